// Round 9
// baseline (234.670 us; speedup 1.0000x reference)
//
#include <hip/hip_runtime.h>
#include <hip/hip_bf16.h>
#include <math.h>

#ifndef M_PI_F
#define M_PI_F 3.14159265358979323846f
#endif

static constexpr int Bb = 2, Tt = 1024, Dd = 1024, Hh = 16, DHh = 64, NFf = 256, Rr = 4096;
static constexpr int Mm = Bb * Tt;
static constexpr int CHK = 64, NCHK = Tt / CHK;  // attention chunking
static constexpr int QS = 3072;                  // fused qkv row stride

enum Epi { EPI_NONE = 0, EPI_RELU, EPI_QKV };

typedef __attribute__((ext_vector_type(8))) short bf16x8;
typedef __attribute__((ext_vector_type(4))) float f32x4;

// ---------------------------------------------------------------------------
// async global->LDS, 16B per lane. LDS dest is wave-uniform base; HW adds
// lane*16. Global address is per-lane.
// ---------------------------------------------------------------------------
__device__ inline void gload16(const short* g, short* l) {
  __builtin_amdgcn_global_load_lds(
      (const __attribute__((address_space(1))) unsigned int*)g,
      (__attribute__((address_space(3))) unsigned int*)l, 16, 0, 0);
}

// ---------------------------------------------------------------------------
// bf16 MFMA GEMM: C[M,N] = epi(A[M,K] @ BT[N,K]^T + bias)
// 128x128 tile, BK=64, 4 waves (2x2), each 64x64 via 4x4 frags of 16x16x32.
// - PIPE-deep K-loop (r7: dbuf; r8: depth 3). PIPE=3 gives the oldest tile's
//   loads TWO compute phases to land (~1200cy > 900cy HBM latency) — used for
//   grids <= 256 blocks (1 block/CU, no implicit wave overlap). PIPE=2
//   (64KB LDS) for larger grids where 2-block/CU co-residency overlaps.
//   Counted vmcnt ladder: in-flight after staging = 8*(buffered tiles);
//   wait (inflight-8) so the CURRENT tile's 8 loads are retired.
//   vmcnt counting relies on the loop body issuing no other VMEM ops.
// - LDS XOR bank-swizzle (rule #21 both-sides involution).
// - Bijective XCD swizzle (m204): XCD gets a contiguous wg2 chunk -> blocks
//   on one XCD share A-panels (L2 reuse).
// - SPLITK: blockIdx.z selects K-slice, writes fp32 partial at Cf + z*M*N.
//   Caller must place partials disjoint from A and BT (r4 had such a race).
// ---------------------------------------------------------------------------
#define GSTAGE(bufsel, kk0)                                           \
  _Pragma("unroll") for (int si = 0; si < 4; ++si) {                  \
    const int s = wid + si * 4;                                       \
    gload16(A + (size_t)(m0 + s * 8 + srow) * ldk + (kk0) + skk,      \
            &lA[(bufsel) * 8192 + s * 512]);                          \
    gload16(BT + (size_t)(n0 + s * 8 + srow) * ldk + (kk0) + skk,     \
            &lB[(bufsel) * 8192 + s * 512]);                          \
  }

template <int EPI, int OUTBF, int SPLITK, int PIPE>
__global__ __launch_bounds__(256) void gemm_mfma(const short* __restrict__ A,
                                                 const short* __restrict__ BT,
                                                 const float* __restrict__ bias,
                                                 float* __restrict__ Cf,
                                                 __hip_bfloat16* __restrict__ Cb,
                                                 int M, int N, int ldk) {
  __shared__ short lA[PIPE * 128 * 64];
  __shared__ short lB[PIPE * 128 * 64];
  const int tid = threadIdx.x;
  const int wid = tid >> 6, lane = tid & 63;

  // XCD-aware bijective block swizzle (grids here always have nwg % 8 == 0)
  const int nwg = gridDim.x * gridDim.y;
  const int wg = blockIdx.y * gridDim.x + blockIdx.x;
  const int qq = nwg >> 3, rr = nwg & 7;
  const int xcd = wg & 7, idx = wg >> 3;
  const int wg2 = (xcd < rr ? xcd * (qq + 1) : rr * (qq + 1) + (xcd - rr) * qq) + idx;
  const int bx = wg2 % gridDim.x, by = wg2 / gridDim.x;

  const int m0 = by * 128, n0 = bx * 128;
  const int wm = (wid >> 1) * 64, wn = (wid & 1) * 64;
  const int srow = lane >> 3;                         // row within 8-row slab
  const int skk = (((lane & 7) ^ (lane >> 3)) << 3);  // swizzled k offset (elems)

  int kstart = 0, klen = ldk;
  if (SPLITK > 1) {
    klen = ldk / SPLITK;
    kstart = blockIdx.z * klen;
    Cf += (size_t)blockIdx.z * M * N;
  }
  const int kend = kstart + klen;

  f32x4 acc[4][4] = {};

  GSTAGE(0, kstart);  // prologue: 8 loads/wave in flight
  if (PIPE >= 3 && kstart + 64 < kend) GSTAGE(1, kstart + 64);  // -> 16
  int cur = 0;
  for (int k0 = kstart; k0 < kend; k0 += 64) {
    if (PIPE == 2) {
      if (k0 + 64 < kend) {
        GSTAGE(cur ^ 1, k0 + 64);                         // 16 in flight
        asm volatile("s_waitcnt vmcnt(8)" ::: "memory");  // oldest 8 done
      } else {
        asm volatile("s_waitcnt vmcnt(0)" ::: "memory");
      }
    } else {
      if (k0 + 128 < kend) {
        int nb = cur + 2;
        if (nb >= 3) nb -= 3;
        GSTAGE(nb, k0 + 128);                              // 24 in flight
        asm volatile("s_waitcnt vmcnt(16)" ::: "memory");  // oldest 8 done
      } else if (k0 + 64 < kend) {
        asm volatile("s_waitcnt vmcnt(8)" ::: "memory");   // 16 in flight
      } else {
        asm volatile("s_waitcnt vmcnt(0)" ::: "memory");
      }
    }
    asm volatile("s_barrier" ::: "memory");
    const short* bA = &lA[cur * 8192];
    const short* bB = &lB[cur * 8192];
#pragma unroll
    for (int kk = 0; kk < 2; ++kk) {
      const int krd = kk * 32 + (lane >> 4) * 8;
      const int rsel = lane & 15;
      const int kswz = krd ^ ((rsel & 7) << 3);  // same involution as store side
      bf16x8 af[4], bfr[4];
#pragma unroll
      for (int i = 0; i < 4; ++i) {
        af[i] = *(const bf16x8*)&bA[(wm + i * 16 + rsel) * 64 + kswz];
        bfr[i] = *(const bf16x8*)&bB[(wn + i * 16 + rsel) * 64 + kswz];
      }
#pragma unroll
      for (int i = 0; i < 4; ++i)
#pragma unroll
        for (int j = 0; j < 4; ++j)
          acc[i][j] = __builtin_amdgcn_mfma_f32_16x16x32_bf16(af[i], bfr[j], acc[i][j], 0, 0, 0);
    }
    // ds_read results are consumed by MFMA (compiler lgkmcnt) before here.
    asm volatile("s_barrier" ::: "memory");  // all waves done reading cur buf
    if (PIPE == 2) {
      cur ^= 1;
    } else {
      cur = (cur + 1 >= 3) ? 0 : cur + 1;
    }
  }

  const int crow = (lane >> 4) * 4;
  const int ccol = lane & 15;
#pragma unroll
  for (int j = 0; j < 4; ++j) {
    const int col = n0 + wn + j * 16 + ccol;
    const float bv = bias ? bias[col] : 0.f;
#pragma unroll
    for (int i = 0; i < 4; ++i) {
#pragma unroll
      for (int r = 0; r < 4; ++r) {
        float v = acc[i][j][r] + bv;
        const int row = m0 + wm + i * 16 + crow + r;
        if (EPI == EPI_QKV) {
          Cf[(size_t)row * QS + col] = (col < 2048) ? fmaxf(v, 0.f) : v;
        } else {
          if (EPI == EPI_RELU) v = fmaxf(v, 0.f);
          const size_t off = (size_t)row * N + col;
          if (OUTBF)
            Cb[off] = __float2bfloat16(v);
          else
            Cf[off] = v;
        }
      }
    }
  }
}

// ---------------------------------------------------------------------------
// amp/phi split-K reduce fused with activations and polar->cartesian:
//   amp = softplus(sum partials[.,c] + b_amp), phi = pi*tanh(sum + b_phi)
//   -> urh = bf16(amp*cos(phi)), uih = bf16(amp*sin(phi))
// part layout: [4][M][512] fp32 (cols 0..255 amp, 256..511 phi).
// ---------------------------------------------------------------------------
__global__ __launch_bounds__(256) void reduce_polar(const float* __restrict__ part,
                                                    const float* __restrict__ b_amp,
                                                    const float* __restrict__ b_phi,
                                                    __hip_bfloat16* __restrict__ outr,
                                                    __hip_bfloat16* __restrict__ outi) {
  const int idx = blockIdx.x * 256 + threadIdx.x;  // [0, M*NF)
  const int row = idx >> 8, c = idx & 255;
  const size_t MN = (size_t)Mm * 512;
  const size_t pa = (size_t)row * 512 + c;
  float a = part[pa] + part[pa + MN] + part[pa + 2 * MN] + part[pa + 3 * MN] + b_amp[c];
  float ph = part[pa + 256] + part[pa + 256 + MN] + part[pa + 256 + 2 * MN] +
             part[pa + 256 + 3 * MN] + b_phi[c];
  a = (a > 0.f) ? (a + log1pf(expf(-a))) : log1pf(expf(a));
  ph = M_PI_F * tanhf(ph);
  float s, co;
  sincosf(ph, &s, &co);
  outr[idx] = __float2bfloat16(a * co);
  outi[idx] = __float2bfloat16(a * s);
}

// ---------------------------------------------------------------------------
// Fused transpose-cast of all 8 weight matrices: W[K,N] f32 -> WT[N,K] bf16.
// ---------------------------------------------------------------------------
struct TCDesc {
  const float* src[8];
  __hip_bfloat16* dst[8];
};

__global__ __launch_bounds__(256) void transpose_cast_all(TCDesc d) {
  constexpr int KS[8] = {1024, 1024, 768, 1024, 1024, 1024, 1024, 4096};
  constexpr int NS[8] = {256, 256, 1024, 1024, 1024, 1024, 4096, 1024};
  constexpr int CUM[9] = {0, 256, 512, 1280, 2304, 3328, 4352, 8448, 12544};
  __shared__ float tile[32][33];
  const int bid = blockIdx.x;
  int w = 0;
#pragma unroll
  for (int i = 0; i < 8; ++i)
    if (bid >= CUM[i + 1]) w = i + 1;
  const int tlocal = bid - CUM[w];
  const int K = KS[w], N = NS[w];
  const int tilesN = N / 32;
  const int bk = (tlocal / tilesN) * 32, bn = (tlocal % tilesN) * 32;
  const float* W = d.src[w];
  __hip_bfloat16* WT = d.dst[w];
  const int tx = threadIdx.x & 31, ty = threadIdx.x >> 5;  // 32x8
#pragma unroll
  for (int r = 0; r < 32; r += 8) tile[ty + r][tx] = W[(size_t)(bk + ty + r) * N + bn + tx];
  __syncthreads();
#pragma unroll
  for (int r = 0; r < 32; r += 8)
    WT[(size_t)(bn + ty + r) * K + bk + tx] = __float2bfloat16(tile[tx][ty + r]);
}

// ---------------------------------------------------------------------------
// x: f32 -> bf16 cast (row-major, layout preserved)
// ---------------------------------------------------------------------------
__global__ __launch_bounds__(256) void cast_x(const float* __restrict__ x,
                                              __hip_bfloat16* __restrict__ xb) {
  const int i = (blockIdx.x * 256 + threadIdx.x) * 4;
  const float4 v = *(const float4*)&x[i];
  xb[i + 0] = __float2bfloat16(v.x);
  xb[i + 1] = __float2bfloat16(v.y);
  xb[i + 2] = __float2bfloat16(v.z);
  xb[i + 3] = __float2bfloat16(v.w);
}

// ---------------------------------------------------------------------------
// Sequential complex resonator recurrence; writes feat bf16 [B,T,3*NF].
// TIME-CHUNK PARALLEL (r6): contraction >= sigmoid(2.0)=0.881/step makes a
// 128-step warm-up from X=0 exact to below bf16 quantization. 64 blocks x
// 64 lanes; register double-buffer (P=16) keeps ~4KB/wave in flight.
// ---------------------------------------------------------------------------
static constexpr int RES_P = 16;
static constexpr int RES_TC = 128;  // chunk length
static constexpr int RES_W = 128;   // warm-up length

#define RES_LOAD(buf_r, buf_i, tg)                                        \
  if ((tg) < cend) {                                                      \
    _Pragma("unroll") for (int i = 0; i < RES_P; ++i) {                   \
      buf_r[i] = __bfloat162float(ur[bbase + (size_t)((tg) + i) * NFf]);  \
      buf_i[i] = __bfloat162float(ui[bbase + (size_t)((tg) + i) * NFf]);  \
    }                                                                     \
  }

#define RES_STEP(buf_r, buf_i, tg)                                      \
  {                                                                      \
    const bool wr_ = (tg) >= cstart;                                     \
    _Pragma("unroll") for (int i = 0; i < RES_P; ++i) {                  \
      const float pr = fmaf(ar, Xr, fmaf(-ai, Xi, buf_r[i]));            \
      const float pim = fmaf(ar, Xi, fmaf(ai, Xr, buf_i[i]));            \
      const float mag = __builtin_amdgcn_sqrtf(fmaf(pr, pr, pim * pim)); \
      const float g = __builtin_amdgcn_rcpf(1.f + __expf(th - mag));     \
      Xr = pr * g;                                                       \
      Xi = pim * g;                                                      \
      if (wr_) {                                                         \
        const size_t fb = ((size_t)b * Tt + (tg) + i) * (3 * NFf);       \
        featb[fb + f] = __float2bfloat16(Xr);                            \
        featb[fb + NFf + f] = __float2bfloat16(Xi);                      \
        featb[fb + 2 * NFf + f] = __float2bfloat16(mag * g);             \
      }                                                                  \
    }                                                                    \
  }

__global__ __launch_bounds__(64) void resonator_scan(const __hip_bfloat16* __restrict__ ur,
                                                     const __hip_bfloat16* __restrict__ ui,
                                                     const float* __restrict__ omega,
                                                     const float* __restrict__ ret_logit,
                                                     const float* __restrict__ theta,
                                                     __hip_bfloat16* __restrict__ featb) {
  const int bid = blockIdx.x;  // 64 blocks: (b:2, fs:4, tc:8)
  const int tc = bid & 7;
  const int fs = (bid >> 3) & 3;
  const int b = bid >> 5;
  const int f = fs * 64 + threadIdx.x;
  const int cstart = tc * RES_TC;
  const int cend = cstart + RES_TC;
  const int tbeg = (cstart >= RES_W) ? cstart - RES_W : 0;

  const float dec = 1.f / (1.f + __expf(-ret_logit[f]));
  float so, co;
  sincosf(omega[f], &so, &co);
  const float ar = dec * co, ai = dec * so;
  const float th = theta[f];
  const size_t bbase = (size_t)b * Tt * NFf + f;
  float Xr = 0.f, Xi = 0.f;
  float Ar[RES_P], Ai[RES_P], Br[RES_P], Bi[RES_P];
  RES_LOAD(Ar, Ai, tbeg);
  for (int t0 = tbeg; t0 < cend; t0 += 2 * RES_P) {
    RES_LOAD(Br, Bi, t0 + RES_P);
    RES_STEP(Ar, Ai, t0);
    RES_LOAD(Ar, Ai, t0 + 2 * RES_P);
    RES_STEP(Br, Bi, t0 + RES_P);
  }
}

// ---------------------------------------------------------------------------
// Attention phase A: per-chunk KV outer-product sums and k-sums.
// q/k/v live in the fused qkv buffer (row stride QS=3072).
// ---------------------------------------------------------------------------
__global__ __launch_bounds__(256) void attn_chunk_kv(const float* __restrict__ k,
                                                     const float* __restrict__ v,
                                                     float* __restrict__ S,
                                                     float* __restrict__ Ksum) {
  __shared__ float Ks[64][68], Vs[64][68];
  const int g = blockIdx.x;
  const int j = g & (NCHK - 1), bh = g >> 4;
  const int b = bh >> 4, h = bh & (Hh - 1);
  const int tid = threadIdx.x;
  const size_t rowbase = (size_t)(b * Tt + j * CHK) * QS + h * DHh;
  for (int l = tid; l < 4096; l += 256) {
    const int s = l >> 6, d = l & 63;
    Ks[s][d] = k[rowbase + (size_t)s * QS + d];
    Vs[s][d] = v[rowbase + (size_t)s * QS + d];
  }
  __syncthreads();
  const int d0 = tid & 63, eb = tid >> 6, e0 = eb * 16;
  float4 acc4[4] = {};
  float ks = 0.f;
  for (int s = 0; s < 64; ++s) {
    const float kd = Ks[s][d0];
    ks += kd;
#pragma unroll
    for (int i = 0; i < 4; ++i) {
      const float4 v4 = *(const float4*)&Vs[s][e0 + 4 * i];
      acc4[i].x = fmaf(kd, v4.x, acc4[i].x);
      acc4[i].y = fmaf(kd, v4.y, acc4[i].y);
      acc4[i].z = fmaf(kd, v4.z, acc4[i].z);
      acc4[i].w = fmaf(kd, v4.w, acc4[i].w);
    }
  }
  float* Sg = S + (size_t)g * 4096 + (size_t)d0 * 64 + e0;
#pragma unroll
  for (int i = 0; i < 4; ++i) *(float4*)&Sg[4 * i] = acc4[i];
  if (eb == 0) Ksum[(size_t)g * 64 + d0] = ks;
}

// ---------------------------------------------------------------------------
// Attention phase B: in-place EXCLUSIVE prefix over the 16 chunks per (b,h).
// ---------------------------------------------------------------------------
__global__ __launch_bounds__(256) void attn_prefix(float* __restrict__ S,
                                                   float* __restrict__ Ksum) {
  const int bh = blockIdx.x;
  const int tid = threadIdx.x;
  for (int r = 0; r < 16; ++r) {
    const int de = r * 256 + tid;
    float run = 0.f;
    size_t p = (size_t)bh * (NCHK * 4096) + de;
    for (int j = 0; j < NCHK; ++j, p += 4096) {
      const float tmp = S[p];
      S[p] = run;
      run += tmp;
    }
  }
  if (tid < 64) {
    float run = 0.f;
    size_t p = (size_t)bh * (NCHK * 64) + tid;
    for (int j = 0; j < NCHK; ++j, p += 64) {
      const float tmp = Ksum[p];
      Ksum[p] = run;
      run += tmp;
    }
  }
}

// ---------------------------------------------------------------------------
// Attention phase C: per-chunk output (q/k/v strided QS; y is [B,T,H,DH]).
// ---------------------------------------------------------------------------
__global__ __launch_bounds__(256) void attn_out(const float* __restrict__ q,
                                                const float* __restrict__ k,
                                                const float* __restrict__ v,
                                                const float* __restrict__ S,
                                                const float* __restrict__ Ksum,
                                                float* __restrict__ y) {
  __shared__ float Qt[64][65];
  __shared__ float KVP[64][68];
  __shared__ float At[64][65];
  const int g = blockIdx.x;
  const int j = g & (NCHK - 1), bh = g >> 4;
  const int b = bh >> 4, h = bh & (Hh - 1);
  const int tid = threadIdx.x;
  const size_t rowbase = (size_t)(b * Tt + j * CHK) * QS + h * DHh;
  const size_t ybase = (((size_t)b * Tt + j * CHK) * Hh + h) * DHh;
  for (int l = tid; l < 4096; l += 256) {
    const int s = l >> 6, d = l & 63;
    Qt[d][s] = q[rowbase + (size_t)s * QS + d];
    KVP[s][d] = k[rowbase + (size_t)s * QS + d];
  }
  __syncthreads();
  const int t = tid >> 2, sg = tid & 3;
  const float* pk = Ksum + (size_t)g * 64;
  // --- stage 1: masked scores + denominator ---
  float adot[16] = {};
  float qpk = 0.f;
  for (int c = 0; c < 16; ++c) {
    const float q0 = Qt[4 * c + 0][t], q1 = Qt[4 * c + 1][t];
    const float q2 = Qt[4 * c + 2][t], q3 = Qt[4 * c + 3][t];
    const float4 pk4 = *(const float4*)&pk[4 * c];
    qpk = fmaf(q0, pk4.x, fmaf(q1, pk4.y, fmaf(q2, pk4.z, fmaf(q3, pk4.w, qpk))));
#pragma unroll
    for (int i = 0; i < 16; ++i) {
      const float4 k4 = *(const float4*)&KVP[sg * 16 + i][4 * c];
      adot[i] = fmaf(q0, k4.x, fmaf(q1, k4.y, fmaf(q2, k4.z, fmaf(q3, k4.w, adot[i]))));
    }
  }
  float rs = 0.f;
#pragma unroll
  for (int i = 0; i < 16; ++i) {
    if (sg * 16 + i > t) adot[i] = 0.f;
    rs += adot[i];
  }
  rs += __shfl_xor(rs, 1);
  rs += __shfl_xor(rs, 2);
  const float den = qpk + rs + 1e-6f;
  __syncthreads();  // all K reads complete
#pragma unroll
  for (int i = 0; i < 16; ++i) At[sg * 16 + i][t] = adot[i];
  for (int l = tid; l < 4096; l += 256) {  // overwrite K with V
    const int s = l >> 6, d = l & 63;
    KVP[s][d] = v[rowbase + (size_t)s * QS + d];
  }
  __syncthreads();
  // --- stage 2a: masked-score @ V ---
  const int e0 = sg * 16;
  float4 num[4] = {};
  for (int s = 0; s <= t; ++s) {
    const float av = At[s][t];
#pragma unroll
    for (int i = 0; i < 4; ++i) {
      const float4 v4 = *(const float4*)&KVP[s][e0 + 4 * i];
      num[i].x = fmaf(av, v4.x, num[i].x);
      num[i].y = fmaf(av, v4.y, num[i].y);
      num[i].z = fmaf(av, v4.z, num[i].z);
      num[i].w = fmaf(av, v4.w, num[i].w);
    }
  }
  __syncthreads();  // all V reads complete
  const float* Pg = S + (size_t)g * 4096;
  for (int l = tid; l < 4096; l += 256) KVP[l >> 6][l & 63] = Pg[l];
  __syncthreads();
  // --- stage 2b: Q @ P ---
  for (int d = 0; d < 64; ++d) {
    const float qd = Qt[d][t];
#pragma unroll
    for (int i = 0; i < 4; ++i) {
      const float4 p4 = *(const float4*)&KVP[d][e0 + 4 * i];
      num[i].x = fmaf(qd, p4.x, num[i].x);
      num[i].y = fmaf(qd, p4.y, num[i].y);
      num[i].z = fmaf(qd, p4.z, num[i].z);
      num[i].w = fmaf(qd, p4.w, num[i].w);
    }
  }
  const float inv = 1.f / den;
  float* yg = y + ybase + (size_t)t * (Hh * DHh) + e0;
#pragma unroll
  for (int i = 0; i < 4; ++i) {
    float4 o;
    o.x = num[i].x * inv;
    o.y = num[i].y * inv;
    o.z = num[i].z * inv;
    o.w = num[i].w * inv;
    *(float4*)&yg[4 * i] = o;
  }
}

// ---------------------------------------------------------------------------
// Per-head layernorm over DH=64, output bf16 [B,T,D].
// ---------------------------------------------------------------------------
__global__ __launch_bounds__(256) void ln_head(const float* __restrict__ y,
                                               const float* __restrict__ w,
                                               const float* __restrict__ bsh,
                                               __hip_bfloat16* __restrict__ out) {
  const int tid = threadIdx.x;
  const int e = tid & 63;
  const int r = blockIdx.x * 4 + (tid >> 6);
  const int h = r & (Hh - 1);
  const float val = y[(size_t)r * DHh + e];
  float s = val;
#pragma unroll
  for (int o = 1; o < 64; o <<= 1) s += __shfl_xor(s, o);
  const float mean = s * (1.f / 64.f);
  const float dv = val - mean;
  float s2 = dv * dv;
#pragma unroll
  for (int o = 1; o < 64; o <<= 1) s2 += __shfl_xor(s2, o);
  const float var = s2 * (1.f / 64.f);
  const float res = dv * rsqrtf(var + 1e-5f) * w[h * DHh + e] + bsh[h * DHh + e];
  out[(size_t)r * DHh + e] = __float2bfloat16(res);
}

// ---------------------------------------------------------------------------
// Fused FFN2-reduce + bias + relu + residual + final layernorm over D=1024.
// ---------------------------------------------------------------------------
__global__ __launch_bounds__(256) void final_ln(const float* __restrict__ x,
                                                const float* __restrict__ part,
                                                const float* __restrict__ b2,
                                                const float* __restrict__ w,
                                                const float* __restrict__ bb,
                                                float* __restrict__ out) {
  __shared__ float r1[4], r2[4];
  const int row = blockIdx.x;
  const int tid = threadIdx.x;
  const size_t off = (size_t)row * Dd + tid * 4;
  const size_t MN = (size_t)Mm * Dd;
  const float4 p0 = *(const float4*)&part[off];
  const float4 p1 = *(const float4*)&part[off + MN];
  const float4 bv = *(const float4*)&b2[tid * 4];
  const float4 xa = *(const float4*)&x[off];
  float z[4];
  z[0] = xa.x + fmaxf(p0.x + p1.x + bv.x, 0.f);
  z[1] = xa.y + fmaxf(p0.y + p1.y + bv.y, 0.f);
  z[2] = xa.z + fmaxf(p0.z + p1.z + bv.z, 0.f);
  z[3] = xa.w + fmaxf(p0.w + p1.w + bv.w, 0.f);
  float s1 = z[0] + z[1] + z[2] + z[3];
  float s2 = z[0] * z[0] + z[1] * z[1] + z[2] * z[2] + z[3] * z[3];
#pragma unroll
  for (int o = 1; o < 64; o <<= 1) {
    s1 += __shfl_xor(s1, o);
    s2 += __shfl_xor(s2, o);
  }
  const int wid = tid >> 6;
  if ((tid & 63) == 0) {
    r1[wid] = s1;
    r2[wid] = s2;
  }
  __syncthreads();
  const float t1 = r1[0] + r1[1] + r1[2] + r1[3];
  const float t2 = r2[0] + r2[1] + r2[2] + r2[3];
  const float mu = t1 * (1.f / Dd);
  const float var = t2 * (1.f / Dd) - mu * mu;
  const float rsv = rsqrtf(var + 1e-5f);
  float4 o4;
  float* op = &o4.x;
#pragma unroll
  for (int jj = 0; jj < 4; ++jj) op[jj] = (z[jj] - mu) * rsv * w[tid * 4 + jj] + bb[tid * 4 + jj];
  *(float4*)&out[off] = o4;
}

// ---------------------------------------------------------------------------
extern "C" void kernel_launch(void* const* d_in, const int* in_sizes, int n_in,
                              void* d_out, int out_size, void* d_ws, size_t ws_size,
                              hipStream_t stream) {
  const float* x = (const float*)d_in[0];
  const float* W_amp = (const float*)d_in[1];
  const float* b_amp = (const float*)d_in[2];
  const float* W_phi = (const float*)d_in[3];
  const float* b_phi = (const float*)d_in[4];
  const float* omega = (const float*)d_in[5];
  const float* ret_logit = (const float*)d_in[6];
  const float* theta = (const float*)d_in[7];
  const float* W_feat = (const float*)d_in[8];
  const float* b_feat = (const float*)d_in[9];
  const float* Wq = (const float*)d_in[10];
  const float* Wk = (const float*)d_in[11];
  const float* Wv = (const float*)d_in[12];
  const float* lnh_w = (const float*)d_in[13];
  const float* lnh_b = (const float*)d_in[14];
  const float* W1 = (const float*)d_in[15];
  const float* b1 = (const float*)d_in[16];
  const float* W2 = (const float*)d_in[17];
  const float* b2 = (const float*)d_in[18];
  const float* ln_w = (const float*)d_in[19];
  const float* ln_b = (const float*)d_in[20];

  // ---- workspace bump allocator (256B aligned) ----
  char* p = (char*)d_ws;
  auto alloc = [&](size_t bytes) {
    char* r = p;
    p += (bytes + 255) & ~(size_t)255;
    return r;
  };
  __hip_bfloat16* xb = (__hip_bfloat16*)alloc((size_t)Mm * Dd * 2);  // later: featb
  __hip_bfloat16* urh = (__hip_bfloat16*)alloc((size_t)Mm * NFf * 2);  // bf16 Re(u)
  __hip_bfloat16* uih = (__hip_bfloat16*)alloc((size_t)Mm * NFf * 2);  // bf16 Im(u)
  __hip_bfloat16* WTamp = (__hip_bfloat16*)alloc((size_t)NFf * Dd * 2);  // +WTphi contiguous
  __hip_bfloat16* WTphi = (__hip_bfloat16*)alloc((size_t)NFf * Dd * 2);
  __hip_bfloat16* WTfeat = (__hip_bfloat16*)alloc((size_t)Dd * 3 * NFf * 2);
  __hip_bfloat16* WTq = (__hip_bfloat16*)alloc((size_t)Dd * Dd * 2);  // +k+v contiguous
  __hip_bfloat16* WTk = (__hip_bfloat16*)alloc((size_t)Dd * Dd * 2);
  __hip_bfloat16* WTv = (__hip_bfloat16*)alloc((size_t)Dd * Dd * 2);
  __hip_bfloat16* WT1 = (__hip_bfloat16*)alloc((size_t)Rr * Dd * 2);
  __hip_bfloat16* WT2 = (__hip_bfloat16*)alloc((size_t)Dd * Rr * 2);
  __hip_bfloat16* hb = (__hip_bfloat16*)alloc((size_t)Mm * Dd * 2);
  float* qkv = (float*)alloc((size_t)Mm * QS * 4);  // 24 MB; amp/phi partials pre-qkv,
                                                    // later yhb + f1b
  float* y = (float*)alloc((size_t)Mm * Dd * 4);    // 8 MB; later partial_ffn2[0]
  float* S = (float*)alloc((size_t)Bb * Hh * NCHK * 4096 * 4);  // 8 MB; later partial_ffn2[1]
  float* Ksum = (float*)alloc((size_t)Bb * Hh * NCHK * 64 * 4);

  __hip_bfloat16* featb = xb;
  const float* q = qkv;
  const float* k = qkv + 1024;
  const float* v = qkv + 2048;
  // amp/phi split-K=4 partials [4][M][512] = 16 MB in the (then-dead) qkv region
  float* pamp = qkv;
  __hip_bfloat16* yhb = (__hip_bfloat16*)qkv;                        // [M,1024] bf16 (4 MB)
  __hip_bfloat16* f1b = (__hip_bfloat16*)(qkv + (size_t)Mm * 1024);  // [M,4096] bf16 (16 MB)
  // FFN2 fp32 partials [2][M][1024] = 16 MB over y(8)+S(8): both dead after
  // ln_head / attn_out, disjoint from f1b and WT2 (r4's overlay raced WT2).
  float* partial = y;
  float* out = (float*)d_out;

  const dim3 blk(256);

  // 0: casts
  cast_x<<<dim3(Mm * Dd / 1024), blk, 0, stream>>>(x, xb);
  TCDesc tc;
  tc.src[0] = W_amp; tc.dst[0] = WTamp;
  tc.src[1] = W_phi; tc.dst[1] = WTphi;
  tc.src[2] = W_feat; tc.dst[2] = WTfeat;
  tc.src[3] = Wq; tc.dst[3] = WTq;
  tc.src[4] = Wk; tc.dst[4] = WTk;
  tc.src[5] = Wv; tc.dst[5] = WTv;
  tc.src[6] = W1; tc.dst[6] = WT1;
  tc.src[7] = W2; tc.dst[7] = WT2;
  transpose_cast_all<<<dim3(12544), blk, 0, stream>>>(tc);

  // 1: fused amp/phi projection, split-K=4 (grid 256, PIPE=3), then
  //    fused reduce + softplus/tanh + polar -> bf16 u
  gemm_mfma<EPI_NONE, 0, 4, 3><<<dim3(512 / 128, Mm / 128, 4), blk, 0, stream>>>(
      (const short*)xb, (const short*)WTamp, nullptr, pamp, nullptr, Mm, 512, Dd);
  reduce_polar<<<dim3(Mm * NFf / 256), blk, 0, stream>>>(pamp, b_amp, b_phi, urh, uih);

  // 2: resonator scan -> feat (bf16); 64 blocks x 64 lanes, time-chunked
  resonator_scan<<<dim3(64), dim3(64), 0, stream>>>(urh, uih, omega, ret_logit, theta, featb);

  // 3: feat projection -> h (bf16); 128 blocks (1/CU) -> PIPE=3
  gemm_mfma<EPI_RELU, 1, 0, 3><<<dim3(Dd / 128, Mm / 128), blk, 0, stream>>>(
      (const short*)featb, (const short*)WTfeat, b_feat, nullptr, hb, Mm, Dd, 3 * NFf);

  // 4: fused q,k,v projection (384 blocks -> PIPE=2 keeps 2-block/CU)
  gemm_mfma<EPI_QKV, 0, 0, 2><<<dim3(QS / 128, Mm / 128), blk, 0, stream>>>(
      (const short*)hb, (const short*)WTq, nullptr, qkv, nullptr, Mm, QS, Dd);

  // 5: chunked causal linear attention
  attn_chunk_kv<<<dim3(Bb * Hh * NCHK), blk, 0, stream>>>(k, v, S, Ksum);
  attn_prefix<<<dim3(Bb * Hh), blk, 0, stream>>>(S, Ksum);
  attn_out<<<dim3(Bb * Hh * NCHK), blk, 0, stream>>>(q, k, v, S, Ksum, y);

  // 6: per-head layernorm -> bf16 (qkv dead; yhb overlays it)
  ln_head<<<dim3(Bb * Tt * Hh / 4), blk, 0, stream>>>(y, lnh_w, lnh_b, yhb);

  // 7: FFN1 -> f1b (bf16); 512 blocks -> PIPE=2 keeps 2-block/CU
  gemm_mfma<EPI_RELU, 1, 0, 2><<<dim3(Rr / 128, Mm / 128), blk, 0, stream>>>(
      (const short*)yhb, (const short*)WT1, b1, nullptr, f1b, Mm, Rr, Dd);

  // 8: FFN2 split-K=2 -> partials over y+S (256 blocks, 1/CU -> PIPE=3)
  gemm_mfma<EPI_NONE, 0, 2, 3><<<dim3(Dd / 128, Mm / 128, 2), blk, 0, stream>>>(
      (const short*)f1b, (const short*)WT2, nullptr, partial, nullptr, Mm, Dd, Rr);

  // 9: fused reduce + bias + relu + residual + final layernorm
  final_ln<<<dim3(Mm), blk, 0, stream>>>(x, partial, b2, ln_w, ln_b, out);
}

// Round 10
// 222.143 us; speedup vs baseline: 1.0564x; 1.0564x over previous
//
#include <hip/hip_runtime.h>
#include <hip/hip_bf16.h>
#include <math.h>

#ifndef M_PI_F
#define M_PI_F 3.14159265358979323846f
#endif

static constexpr int Bb = 2, Tt = 1024, Dd = 1024, Hh = 16, DHh = 64, NFf = 256, Rr = 4096;
static constexpr int Mm = Bb * Tt;
static constexpr int CHK = 64, NCHK = Tt / CHK;  // attention chunking
static constexpr int QS = 3072;                  // fused qkv row stride

enum Epi { EPI_NONE = 0, EPI_RELU, EPI_QKV };

typedef __attribute__((ext_vector_type(8))) short bf16x8;
typedef __attribute__((ext_vector_type(4))) float f32x4;

__device__ inline float bf2f(unsigned short u) {
  union { unsigned int i; float f; } c;
  c.i = (unsigned int)u << 16;
  return c.f;
}

// ---------------------------------------------------------------------------
// async global->LDS, 16B per lane. LDS dest is wave-uniform base; HW adds
// lane*16. Global address is per-lane.
// ---------------------------------------------------------------------------
__device__ inline void gload16(const short* g, short* l) {
  __builtin_amdgcn_global_load_lds(
      (const __attribute__((address_space(1))) unsigned int*)g,
      (__attribute__((address_space(3))) unsigned int*)l, 16, 0, 0);
}

// ---------------------------------------------------------------------------
// bf16 MFMA GEMM: C[M,N] = epi(A[M,K] @ BT[N,K]^T + bias)
// 128x128 tile, BK=64, 4 waves (2x2), each 64x64 via 4x4 frags of 16x16x32.
// - Double-buffered K-loop with counted vmcnt (r7). r9 lesson: at 1 block/CU
//   NO pipeline depth fixes the stall (lockstep barriers expose ds_read+MFMA
//   latency); the working lever is >=2 blocks/CU co-residency (m114 implicit
//   wave overlap) — so PIPE=2 (64KB LDS, 2 blocks/CU possible) everywhere,
//   and grids are sized >256 blocks via split-K where it matters (FFN2).
// - LDS XOR bank-swizzle (rule #21 both-sides involution).
// - Bijective XCD swizzle (m204) for A-panel L2 reuse per XCD.
// - SPLITK: blockIdx.z selects K-slice, writes partial (fp32 via Cf or bf16
//   via Cb per OUTBF) at +z*M*N. Caller must place partials disjoint from
//   A and BT (r4 had such a race).
// ---------------------------------------------------------------------------
#define GSTAGE(bufsel, kk0)                                           \
  _Pragma("unroll") for (int si = 0; si < 4; ++si) {                  \
    const int s = wid + si * 4;                                       \
    gload16(A + (size_t)(m0 + s * 8 + srow) * ldk + (kk0) + skk,      \
            &lA[(bufsel) * 8192 + s * 512]);                          \
    gload16(BT + (size_t)(n0 + s * 8 + srow) * ldk + (kk0) + skk,     \
            &lB[(bufsel) * 8192 + s * 512]);                          \
  }

template <int EPI, int OUTBF, int SPLITK>
__global__ __launch_bounds__(256) void gemm_mfma(const short* __restrict__ A,
                                                 const short* __restrict__ BT,
                                                 const float* __restrict__ bias,
                                                 float* __restrict__ Cf,
                                                 __hip_bfloat16* __restrict__ Cb,
                                                 int M, int N, int ldk) {
  __shared__ short lA[2 * 128 * 64];
  __shared__ short lB[2 * 128 * 64];
  const int tid = threadIdx.x;
  const int wid = tid >> 6, lane = tid & 63;

  // XCD-aware bijective block swizzle (grids here always have nwg % 8 == 0)
  const int nwg = gridDim.x * gridDim.y;
  const int wg = blockIdx.y * gridDim.x + blockIdx.x;
  const int qq = nwg >> 3, rr = nwg & 7;
  const int xcd = wg & 7, idx = wg >> 3;
  const int wg2 = (xcd < rr ? xcd * (qq + 1) : rr * (qq + 1) + (xcd - rr) * qq) + idx;
  const int bx = wg2 % gridDim.x, by = wg2 / gridDim.x;

  const int m0 = by * 128, n0 = bx * 128;
  const int wm = (wid >> 1) * 64, wn = (wid & 1) * 64;
  const int srow = lane >> 3;                         // row within 8-row slab
  const int skk = (((lane & 7) ^ (lane >> 3)) << 3);  // swizzled k offset (elems)

  int kstart = 0, klen = ldk;
  if (SPLITK > 1) {
    klen = ldk / SPLITK;
    kstart = blockIdx.z * klen;
    if (OUTBF)
      Cb += (size_t)blockIdx.z * M * N;
    else
      Cf += (size_t)blockIdx.z * M * N;
  }
  const int kend = kstart + klen;

  f32x4 acc[4][4] = {};

  GSTAGE(0, kstart);  // prologue: 8 loads/wave in flight
  int cur = 0;
  for (int k0 = kstart; k0 < kend; k0 += 64) {
    if (k0 + 64 < kend) {
      GSTAGE(cur ^ 1, k0 + 64);                         // 16 in flight
      asm volatile("s_waitcnt vmcnt(8)" ::: "memory");  // oldest 8 (cur buf) done
    } else {
      asm volatile("s_waitcnt vmcnt(0)" ::: "memory");
    }
    asm volatile("s_barrier" ::: "memory");
    const short* bA = &lA[cur * 8192];
    const short* bB = &lB[cur * 8192];
#pragma unroll
    for (int kk = 0; kk < 2; ++kk) {
      const int krd = kk * 32 + (lane >> 4) * 8;
      const int rsel = lane & 15;
      const int kswz = krd ^ ((rsel & 7) << 3);  // same involution as store side
      bf16x8 af[4], bfr[4];
#pragma unroll
      for (int i = 0; i < 4; ++i) {
        af[i] = *(const bf16x8*)&bA[(wm + i * 16 + rsel) * 64 + kswz];
        bfr[i] = *(const bf16x8*)&bB[(wn + i * 16 + rsel) * 64 + kswz];
      }
#pragma unroll
      for (int i = 0; i < 4; ++i)
#pragma unroll
        for (int j = 0; j < 4; ++j)
          acc[i][j] = __builtin_amdgcn_mfma_f32_16x16x32_bf16(af[i], bfr[j], acc[i][j], 0, 0, 0);
    }
    // ds_read results are consumed by MFMA (compiler lgkmcnt) before here.
    asm volatile("s_barrier" ::: "memory");  // all waves done reading cur buf
    cur ^= 1;
  }

  const int crow = (lane >> 4) * 4;
  const int ccol = lane & 15;
#pragma unroll
  for (int j = 0; j < 4; ++j) {
    const int col = n0 + wn + j * 16 + ccol;
    const float bv = bias ? bias[col] : 0.f;
#pragma unroll
    for (int i = 0; i < 4; ++i) {
#pragma unroll
      for (int r = 0; r < 4; ++r) {
        float v = acc[i][j][r] + bv;
        const int row = m0 + wm + i * 16 + crow + r;
        if (EPI == EPI_QKV) {
          Cf[(size_t)row * QS + col] = (col < 2048) ? fmaxf(v, 0.f) : v;
        } else {
          if (EPI == EPI_RELU) v = fmaxf(v, 0.f);
          const size_t off = (size_t)row * N + col;
          if (OUTBF)
            Cb[off] = __float2bfloat16(v);
          else
            Cf[off] = v;
        }
      }
    }
  }
}

// ---------------------------------------------------------------------------
// amp/phi split-K reduce fused with activations and polar->cartesian:
//   amp = softplus(sum partials[.,c] + b_amp), phi = pi*tanh(sum + b_phi)
//   -> urh = bf16(amp*cos(phi)), uih = bf16(amp*sin(phi))
// part layout: [4][M][512] fp32 (cols 0..255 amp, 256..511 phi).
// ---------------------------------------------------------------------------
__global__ __launch_bounds__(256) void reduce_polar(const float* __restrict__ part,
                                                    const float* __restrict__ b_amp,
                                                    const float* __restrict__ b_phi,
                                                    __hip_bfloat16* __restrict__ outr,
                                                    __hip_bfloat16* __restrict__ outi) {
  const int idx = blockIdx.x * 256 + threadIdx.x;  // [0, M*NF)
  const int row = idx >> 8, c = idx & 255;
  const size_t MN = (size_t)Mm * 512;
  const size_t pa = (size_t)row * 512 + c;
  float a = part[pa] + part[pa + MN] + part[pa + 2 * MN] + part[pa + 3 * MN] + b_amp[c];
  float ph = part[pa + 256] + part[pa + 256 + MN] + part[pa + 256 + 2 * MN] +
             part[pa + 256 + 3 * MN] + b_phi[c];
  a = (a > 0.f) ? (a + log1pf(expf(-a))) : log1pf(expf(a));
  ph = M_PI_F * tanhf(ph);
  float s, co;
  sincosf(ph, &s, &co);
  outr[idx] = __float2bfloat16(a * co);
  outi[idx] = __float2bfloat16(a * s);
}

// ---------------------------------------------------------------------------
// Fused transpose-cast of all 8 weight matrices: W[K,N] f32 -> WT[N,K] bf16.
// ---------------------------------------------------------------------------
struct TCDesc {
  const float* src[8];
  __hip_bfloat16* dst[8];
};

__global__ __launch_bounds__(256) void transpose_cast_all(TCDesc d) {
  constexpr int KS[8] = {1024, 1024, 768, 1024, 1024, 1024, 1024, 4096};
  constexpr int NS[8] = {256, 256, 1024, 1024, 1024, 1024, 4096, 1024};
  constexpr int CUM[9] = {0, 256, 512, 1280, 2304, 3328, 4352, 8448, 12544};
  __shared__ float tile[32][33];
  const int bid = blockIdx.x;
  int w = 0;
#pragma unroll
  for (int i = 0; i < 8; ++i)
    if (bid >= CUM[i + 1]) w = i + 1;
  const int tlocal = bid - CUM[w];
  const int K = KS[w], N = NS[w];
  const int tilesN = N / 32;
  const int bk = (tlocal / tilesN) * 32, bn = (tlocal % tilesN) * 32;
  const float* W = d.src[w];
  __hip_bfloat16* WT = d.dst[w];
  const int tx = threadIdx.x & 31, ty = threadIdx.x >> 5;  // 32x8
#pragma unroll
  for (int r = 0; r < 32; r += 8) tile[ty + r][tx] = W[(size_t)(bk + ty + r) * N + bn + tx];
  __syncthreads();
#pragma unroll
  for (int r = 0; r < 32; r += 8)
    WT[(size_t)(bn + ty + r) * K + bk + tx] = __float2bfloat16(tile[tx][ty + r]);
}

// ---------------------------------------------------------------------------
// x: f32 -> bf16 cast (row-major, layout preserved)
// ---------------------------------------------------------------------------
__global__ __launch_bounds__(256) void cast_x(const float* __restrict__ x,
                                              __hip_bfloat16* __restrict__ xb) {
  const int i = (blockIdx.x * 256 + threadIdx.x) * 4;
  const float4 v = *(const float4*)&x[i];
  xb[i + 0] = __float2bfloat16(v.x);
  xb[i + 1] = __float2bfloat16(v.y);
  xb[i + 2] = __float2bfloat16(v.z);
  xb[i + 3] = __float2bfloat16(v.w);
}

// ---------------------------------------------------------------------------
// Sequential complex resonator recurrence; writes feat bf16 [B,T,3*NF].
// TIME-CHUNK PARALLEL (r6): contraction >= sigmoid(2.0)=0.881/step makes a
// 128-step warm-up from X=0 exact to below bf16 quantization. 64 blocks x
// 64 lanes; register double-buffer (P=16) keeps ~4KB/wave in flight.
// ---------------------------------------------------------------------------
static constexpr int RES_P = 16;
static constexpr int RES_TC = 128;  // chunk length
static constexpr int RES_W = 128;   // warm-up length

#define RES_LOAD(buf_r, buf_i, tg)                                        \
  if ((tg) < cend) {                                                      \
    _Pragma("unroll") for (int i = 0; i < RES_P; ++i) {                   \
      buf_r[i] = __bfloat162float(ur[bbase + (size_t)((tg) + i) * NFf]);  \
      buf_i[i] = __bfloat162float(ui[bbase + (size_t)((tg) + i) * NFf]);  \
    }                                                                     \
  }

#define RES_STEP(buf_r, buf_i, tg)                                      \
  {                                                                      \
    const bool wr_ = (tg) >= cstart;                                     \
    _Pragma("unroll") for (int i = 0; i < RES_P; ++i) {                  \
      const float pr = fmaf(ar, Xr, fmaf(-ai, Xi, buf_r[i]));            \
      const float pim = fmaf(ar, Xi, fmaf(ai, Xr, buf_i[i]));            \
      const float mag = __builtin_amdgcn_sqrtf(fmaf(pr, pr, pim * pim)); \
      const float g = __builtin_amdgcn_rcpf(1.f + __expf(th - mag));     \
      Xr = pr * g;                                                       \
      Xi = pim * g;                                                      \
      if (wr_) {                                                         \
        const size_t fb = ((size_t)b * Tt + (tg) + i) * (3 * NFf);       \
        featb[fb + f] = __float2bfloat16(Xr);                            \
        featb[fb + NFf + f] = __float2bfloat16(Xi);                      \
        featb[fb + 2 * NFf + f] = __float2bfloat16(mag * g);             \
      }                                                                  \
    }                                                                    \
  }

__global__ __launch_bounds__(64) void resonator_scan(const __hip_bfloat16* __restrict__ ur,
                                                     const __hip_bfloat16* __restrict__ ui,
                                                     const float* __restrict__ omega,
                                                     const float* __restrict__ ret_logit,
                                                     const float* __restrict__ theta,
                                                     __hip_bfloat16* __restrict__ featb) {
  const int bid = blockIdx.x;  // 64 blocks: (b:2, fs:4, tc:8)
  const int tc = bid & 7;
  const int fs = (bid >> 3) & 3;
  const int b = bid >> 5;
  const int f = fs * 64 + threadIdx.x;
  const int cstart = tc * RES_TC;
  const int cend = cstart + RES_TC;
  const int tbeg = (cstart >= RES_W) ? cstart - RES_W : 0;

  const float dec = 1.f / (1.f + __expf(-ret_logit[f]));
  float so, co;
  sincosf(omega[f], &so, &co);
  const float ar = dec * co, ai = dec * so;
  const float th = theta[f];
  const size_t bbase = (size_t)b * Tt * NFf + f;
  float Xr = 0.f, Xi = 0.f;
  float Ar[RES_P], Ai[RES_P], Br[RES_P], Bi[RES_P];
  RES_LOAD(Ar, Ai, tbeg);
  for (int t0 = tbeg; t0 < cend; t0 += 2 * RES_P) {
    RES_LOAD(Br, Bi, t0 + RES_P);
    RES_STEP(Ar, Ai, t0);
    RES_LOAD(Ar, Ai, t0 + 2 * RES_P);
    RES_STEP(Br, Bi, t0 + RES_P);
  }
}

// ---------------------------------------------------------------------------
// Attention phase A: per-chunk KV outer-product sums and k-sums.
// q/k/v live in the fused qkv buffer (row stride QS=3072).
// ---------------------------------------------------------------------------
__global__ __launch_bounds__(256) void attn_chunk_kv(const float* __restrict__ k,
                                                     const float* __restrict__ v,
                                                     float* __restrict__ S,
                                                     float* __restrict__ Ksum) {
  __shared__ float Ks[64][68], Vs[64][68];
  const int g = blockIdx.x;
  const int j = g & (NCHK - 1), bh = g >> 4;
  const int b = bh >> 4, h = bh & (Hh - 1);
  const int tid = threadIdx.x;
  const size_t rowbase = (size_t)(b * Tt + j * CHK) * QS + h * DHh;
  for (int l = tid; l < 4096; l += 256) {
    const int s = l >> 6, d = l & 63;
    Ks[s][d] = k[rowbase + (size_t)s * QS + d];
    Vs[s][d] = v[rowbase + (size_t)s * QS + d];
  }
  __syncthreads();
  const int d0 = tid & 63, eb = tid >> 6, e0 = eb * 16;
  float4 acc4[4] = {};
  float ks = 0.f;
  for (int s = 0; s < 64; ++s) {
    const float kd = Ks[s][d0];
    ks += kd;
#pragma unroll
    for (int i = 0; i < 4; ++i) {
      const float4 v4 = *(const float4*)&Vs[s][e0 + 4 * i];
      acc4[i].x = fmaf(kd, v4.x, acc4[i].x);
      acc4[i].y = fmaf(kd, v4.y, acc4[i].y);
      acc4[i].z = fmaf(kd, v4.z, acc4[i].z);
      acc4[i].w = fmaf(kd, v4.w, acc4[i].w);
    }
  }
  float* Sg = S + (size_t)g * 4096 + (size_t)d0 * 64 + e0;
#pragma unroll
  for (int i = 0; i < 4; ++i) *(float4*)&Sg[4 * i] = acc4[i];
  if (eb == 0) Ksum[(size_t)g * 64 + d0] = ks;
}

// ---------------------------------------------------------------------------
// Attention phase B: in-place EXCLUSIVE prefix over the 16 chunks per (b,h).
// ---------------------------------------------------------------------------
__global__ __launch_bounds__(256) void attn_prefix(float* __restrict__ S,
                                                   float* __restrict__ Ksum) {
  const int bh = blockIdx.x;
  const int tid = threadIdx.x;
  for (int r = 0; r < 16; ++r) {
    const int de = r * 256 + tid;
    float run = 0.f;
    size_t p = (size_t)bh * (NCHK * 4096) + de;
    for (int j = 0; j < NCHK; ++j, p += 4096) {
      const float tmp = S[p];
      S[p] = run;
      run += tmp;
    }
  }
  if (tid < 64) {
    float run = 0.f;
    size_t p = (size_t)bh * (NCHK * 64) + tid;
    for (int j = 0; j < NCHK; ++j, p += 64) {
      const float tmp = Ksum[p];
      Ksum[p] = run;
      run += tmp;
    }
  }
}

// ---------------------------------------------------------------------------
// Attention phase C: per-chunk output (q/k/v strided QS; y is [B,T,H,DH]).
// ---------------------------------------------------------------------------
__global__ __launch_bounds__(256) void attn_out(const float* __restrict__ q,
                                                const float* __restrict__ k,
                                                const float* __restrict__ v,
                                                const float* __restrict__ S,
                                                const float* __restrict__ Ksum,
                                                float* __restrict__ y) {
  __shared__ float Qt[64][65];
  __shared__ float KVP[64][68];
  __shared__ float At[64][65];
  const int g = blockIdx.x;
  const int j = g & (NCHK - 1), bh = g >> 4;
  const int b = bh >> 4, h = bh & (Hh - 1);
  const int tid = threadIdx.x;
  const size_t rowbase = (size_t)(b * Tt + j * CHK) * QS + h * DHh;
  const size_t ybase = (((size_t)b * Tt + j * CHK) * Hh + h) * DHh;
  for (int l = tid; l < 4096; l += 256) {
    const int s = l >> 6, d = l & 63;
    Qt[d][s] = q[rowbase + (size_t)s * QS + d];
    KVP[s][d] = k[rowbase + (size_t)s * QS + d];
  }
  __syncthreads();
  const int t = tid >> 2, sg = tid & 3;
  const float* pk = Ksum + (size_t)g * 64;
  // --- stage 1: masked scores + denominator ---
  float adot[16] = {};
  float qpk = 0.f;
  for (int c = 0; c < 16; ++c) {
    const float q0 = Qt[4 * c + 0][t], q1 = Qt[4 * c + 1][t];
    const float q2 = Qt[4 * c + 2][t], q3 = Qt[4 * c + 3][t];
    const float4 pk4 = *(const float4*)&pk[4 * c];
    qpk = fmaf(q0, pk4.x, fmaf(q1, pk4.y, fmaf(q2, pk4.z, fmaf(q3, pk4.w, qpk))));
#pragma unroll
    for (int i = 0; i < 16; ++i) {
      const float4 k4 = *(const float4*)&KVP[sg * 16 + i][4 * c];
      adot[i] = fmaf(q0, k4.x, fmaf(q1, k4.y, fmaf(q2, k4.z, fmaf(q3, k4.w, adot[i]))));
    }
  }
  float rs = 0.f;
#pragma unroll
  for (int i = 0; i < 16; ++i) {
    if (sg * 16 + i > t) adot[i] = 0.f;
    rs += adot[i];
  }
  rs += __shfl_xor(rs, 1);
  rs += __shfl_xor(rs, 2);
  const float den = qpk + rs + 1e-6f;
  __syncthreads();  // all K reads complete
#pragma unroll
  for (int i = 0; i < 16; ++i) At[sg * 16 + i][t] = adot[i];
  for (int l = tid; l < 4096; l += 256) {  // overwrite K with V
    const int s = l >> 6, d = l & 63;
    KVP[s][d] = v[rowbase + (size_t)s * QS + d];
  }
  __syncthreads();
  // --- stage 2a: masked-score @ V ---
  const int e0 = sg * 16;
  float4 num[4] = {};
  for (int s = 0; s <= t; ++s) {
    const float av = At[s][t];
#pragma unroll
    for (int i = 0; i < 4; ++i) {
      const float4 v4 = *(const float4*)&KVP[s][e0 + 4 * i];
      num[i].x = fmaf(av, v4.x, num[i].x);
      num[i].y = fmaf(av, v4.y, num[i].y);
      num[i].z = fmaf(av, v4.z, num[i].z);
      num[i].w = fmaf(av, v4.w, num[i].w);
    }
  }
  __syncthreads();  // all V reads complete
  const float* Pg = S + (size_t)g * 4096;
  for (int l = tid; l < 4096; l += 256) KVP[l >> 6][l & 63] = Pg[l];
  __syncthreads();
  // --- stage 2b: Q @ P ---
  for (int d = 0; d < 64; ++d) {
    const float qd = Qt[d][t];
#pragma unroll
    for (int i = 0; i < 4; ++i) {
      const float4 p4 = *(const float4*)&KVP[d][e0 + 4 * i];
      num[i].x = fmaf(qd, p4.x, num[i].x);
      num[i].y = fmaf(qd, p4.y, num[i].y);
      num[i].z = fmaf(qd, p4.z, num[i].z);
      num[i].w = fmaf(qd, p4.w, num[i].w);
    }
  }
  const float inv = 1.f / den;
  float* yg = y + ybase + (size_t)t * (Hh * DHh) + e0;
#pragma unroll
  for (int i = 0; i < 4; ++i) {
    float4 o;
    o.x = num[i].x * inv;
    o.y = num[i].y * inv;
    o.z = num[i].z * inv;
    o.w = num[i].w * inv;
    *(float4*)&yg[4 * i] = o;
  }
}

// ---------------------------------------------------------------------------
// Per-head layernorm over DH=64, output bf16 [B,T,D].
// ---------------------------------------------------------------------------
__global__ __launch_bounds__(256) void ln_head(const float* __restrict__ y,
                                               const float* __restrict__ w,
                                               const float* __restrict__ bsh,
                                               __hip_bfloat16* __restrict__ out) {
  const int tid = threadIdx.x;
  const int e = tid & 63;
  const int r = blockIdx.x * 4 + (tid >> 6);
  const int h = r & (Hh - 1);
  const float val = y[(size_t)r * DHh + e];
  float s = val;
#pragma unroll
  for (int o = 1; o < 64; o <<= 1) s += __shfl_xor(s, o);
  const float mean = s * (1.f / 64.f);
  const float dv = val - mean;
  float s2 = dv * dv;
#pragma unroll
  for (int o = 1; o < 64; o <<= 1) s2 += __shfl_xor(s2, o);
  const float var = s2 * (1.f / 64.f);
  const float res = dv * rsqrtf(var + 1e-5f) * w[h * DHh + e] + bsh[h * DHh + e];
  out[(size_t)r * DHh + e] = __float2bfloat16(res);
}

// ---------------------------------------------------------------------------
// Fused FFN2-reduce (4 bf16 split-K partials) + bias + relu + residual +
// final layernorm over D=1024.
// ---------------------------------------------------------------------------
__global__ __launch_bounds__(256) void final_ln(const float* __restrict__ x,
                                                const __hip_bfloat16* __restrict__ part,
                                                const float* __restrict__ b2,
                                                const float* __restrict__ w,
                                                const float* __restrict__ bb,
                                                float* __restrict__ out) {
  __shared__ float r1[4], r2[4];
  const int row = blockIdx.x;
  const int tid = threadIdx.x;
  const size_t off = (size_t)row * Dd + tid * 4;
  const size_t MN = (size_t)Mm * Dd;
  float acc4[4] = {0.f, 0.f, 0.f, 0.f};
#pragma unroll
  for (int z = 0; z < 4; ++z) {
    const ushort4 u = *(const ushort4*)&part[off + (size_t)z * MN];
    acc4[0] += bf2f(u.x);
    acc4[1] += bf2f(u.y);
    acc4[2] += bf2f(u.z);
    acc4[3] += bf2f(u.w);
  }
  const float4 bv = *(const float4*)&b2[tid * 4];
  const float4 xa = *(const float4*)&x[off];
  float z[4];
  z[0] = xa.x + fmaxf(acc4[0] + bv.x, 0.f);
  z[1] = xa.y + fmaxf(acc4[1] + bv.y, 0.f);
  z[2] = xa.z + fmaxf(acc4[2] + bv.z, 0.f);
  z[3] = xa.w + fmaxf(acc4[3] + bv.w, 0.f);
  float s1 = z[0] + z[1] + z[2] + z[3];
  float s2 = z[0] * z[0] + z[1] * z[1] + z[2] * z[2] + z[3] * z[3];
#pragma unroll
  for (int o = 1; o < 64; o <<= 1) {
    s1 += __shfl_xor(s1, o);
    s2 += __shfl_xor(s2, o);
  }
  const int wid = tid >> 6;
  if ((tid & 63) == 0) {
    r1[wid] = s1;
    r2[wid] = s2;
  }
  __syncthreads();
  const float t1 = r1[0] + r1[1] + r1[2] + r1[3];
  const float t2 = r2[0] + r2[1] + r2[2] + r2[3];
  const float mu = t1 * (1.f / Dd);
  const float var = t2 * (1.f / Dd) - mu * mu;
  const float rsv = rsqrtf(var + 1e-5f);
  float4 o4;
  float* op = &o4.x;
#pragma unroll
  for (int jj = 0; jj < 4; ++jj) op[jj] = (z[jj] - mu) * rsv * w[tid * 4 + jj] + bb[tid * 4 + jj];
  *(float4*)&out[off] = o4;
}

// ---------------------------------------------------------------------------
extern "C" void kernel_launch(void* const* d_in, const int* in_sizes, int n_in,
                              void* d_out, int out_size, void* d_ws, size_t ws_size,
                              hipStream_t stream) {
  const float* x = (const float*)d_in[0];
  const float* W_amp = (const float*)d_in[1];
  const float* b_amp = (const float*)d_in[2];
  const float* W_phi = (const float*)d_in[3];
  const float* b_phi = (const float*)d_in[4];
  const float* omega = (const float*)d_in[5];
  const float* ret_logit = (const float*)d_in[6];
  const float* theta = (const float*)d_in[7];
  const float* W_feat = (const float*)d_in[8];
  const float* b_feat = (const float*)d_in[9];
  const float* Wq = (const float*)d_in[10];
  const float* Wk = (const float*)d_in[11];
  const float* Wv = (const float*)d_in[12];
  const float* lnh_w = (const float*)d_in[13];
  const float* lnh_b = (const float*)d_in[14];
  const float* W1 = (const float*)d_in[15];
  const float* b1 = (const float*)d_in[16];
  const float* W2 = (const float*)d_in[17];
  const float* b2 = (const float*)d_in[18];
  const float* ln_w = (const float*)d_in[19];
  const float* ln_b = (const float*)d_in[20];

  // ---- workspace bump allocator (256B aligned) ----
  char* p = (char*)d_ws;
  auto alloc = [&](size_t bytes) {
    char* r = p;
    p += (bytes + 255) & ~(size_t)255;
    return r;
  };
  __hip_bfloat16* xb = (__hip_bfloat16*)alloc((size_t)Mm * Dd * 2);  // later: featb
  __hip_bfloat16* urh = (__hip_bfloat16*)alloc((size_t)Mm * NFf * 2);  // bf16 Re(u)
  __hip_bfloat16* uih = (__hip_bfloat16*)alloc((size_t)Mm * NFf * 2);  // bf16 Im(u)
  __hip_bfloat16* WTamp = (__hip_bfloat16*)alloc((size_t)NFf * Dd * 2);  // +WTphi contiguous
  __hip_bfloat16* WTphi = (__hip_bfloat16*)alloc((size_t)NFf * Dd * 2);
  __hip_bfloat16* WTfeat = (__hip_bfloat16*)alloc((size_t)Dd * 3 * NFf * 2);
  __hip_bfloat16* WTq = (__hip_bfloat16*)alloc((size_t)Dd * Dd * 2);  // +k+v contiguous
  __hip_bfloat16* WTk = (__hip_bfloat16*)alloc((size_t)Dd * Dd * 2);
  __hip_bfloat16* WTv = (__hip_bfloat16*)alloc((size_t)Dd * Dd * 2);
  __hip_bfloat16* WT1 = (__hip_bfloat16*)alloc((size_t)Rr * Dd * 2);
  __hip_bfloat16* WT2 = (__hip_bfloat16*)alloc((size_t)Dd * Rr * 2);
  __hip_bfloat16* hb = (__hip_bfloat16*)alloc((size_t)Mm * Dd * 2);
  float* qkv = (float*)alloc((size_t)Mm * QS * 4);  // 24 MB; amp/phi partials pre-qkv,
                                                    // later yhb + f1b
  float* y = (float*)alloc((size_t)Mm * Dd * 4);    // 8 MB; later bf16 partials[0..1]
  float* S = (float*)alloc((size_t)Bb * Hh * NCHK * 4096 * 4);  // 8 MB; later bf16 partials[2..3]
  float* Ksum = (float*)alloc((size_t)Bb * Hh * NCHK * 64 * 4);

  __hip_bfloat16* featb = xb;
  const float* q = qkv;
  const float* k = qkv + 1024;
  const float* v = qkv + 2048;
  // amp/phi split-K=4 partials [4][M][512] fp32 = 16 MB in the (then-dead) qkv region
  float* pamp = qkv;
  __hip_bfloat16* yhb = (__hip_bfloat16*)qkv;                        // [M,1024] bf16 (4 MB)
  __hip_bfloat16* f1b = (__hip_bfloat16*)(qkv + (size_t)Mm * 1024);  // [M,4096] bf16 (16 MB)
  // FFN2 bf16 partials [4][M][1024] = 16 MB over y(8)+S(8): both dead after
  // ln_head / attn_out, disjoint from f1b and WT2 (r4's overlay raced WT2).
  __hip_bfloat16* partial = (__hip_bfloat16*)y;
  float* out = (float*)d_out;

  const dim3 blk(256);

  // 0: casts
  cast_x<<<dim3(Mm * Dd / 1024), blk, 0, stream>>>(x, xb);
  TCDesc tc;
  tc.src[0] = W_amp; tc.dst[0] = WTamp;
  tc.src[1] = W_phi; tc.dst[1] = WTphi;
  tc.src[2] = W_feat; tc.dst[2] = WTfeat;
  tc.src[3] = Wq; tc.dst[3] = WTq;
  tc.src[4] = Wk; tc.dst[4] = WTk;
  tc.src[5] = Wv; tc.dst[5] = WTv;
  tc.src[6] = W1; tc.dst[6] = WT1;
  tc.src[7] = W2; tc.dst[7] = WT2;
  transpose_cast_all<<<dim3(12544), blk, 0, stream>>>(tc);

  // 1: fused amp/phi projection, split-K=4 (256 blocks), then fused
  //    reduce + softplus/tanh + polar -> bf16 u
  gemm_mfma<EPI_NONE, 0, 4><<<dim3(512 / 128, Mm / 128, 4), blk, 0, stream>>>(
      (const short*)xb, (const short*)WTamp, nullptr, pamp, nullptr, Mm, 512, Dd);
  reduce_polar<<<dim3(Mm * NFf / 256), blk, 0, stream>>>(pamp, b_amp, b_phi, urh, uih);

  // 2: resonator scan -> feat (bf16); 64 blocks x 64 lanes, time-chunked
  resonator_scan<<<dim3(64), dim3(64), 0, stream>>>(urh, uih, omega, ret_logit, theta, featb);

  // 3: feat projection -> h (bf16)
  gemm_mfma<EPI_RELU, 1, 0><<<dim3(Dd / 128, Mm / 128), blk, 0, stream>>>(
      (const short*)featb, (const short*)WTfeat, b_feat, nullptr, hb, Mm, Dd, 3 * NFf);

  // 4: fused q,k,v projection (384 blocks, 1.5 blocks/CU)
  gemm_mfma<EPI_QKV, 0, 0><<<dim3(QS / 128, Mm / 128), blk, 0, stream>>>(
      (const short*)hb, (const short*)WTq, nullptr, qkv, nullptr, Mm, QS, Dd);

  // 5: chunked causal linear attention
  attn_chunk_kv<<<dim3(Bb * Hh * NCHK), blk, 0, stream>>>(k, v, S, Ksum);
  attn_prefix<<<dim3(Bb * Hh), blk, 0, stream>>>(S, Ksum);
  attn_out<<<dim3(Bb * Hh * NCHK), blk, 0, stream>>>(q, k, v, S, Ksum, y);

  // 6: per-head layernorm -> bf16 (qkv dead; yhb overlays it)
  ln_head<<<dim3(Bb * Tt * Hh / 4), blk, 0, stream>>>(y, lnh_w, lnh_b, yhb);

  // 7: FFN1 -> f1b (bf16); 512 blocks = 2 blocks/CU
  gemm_mfma<EPI_RELU, 1, 0><<<dim3(Rr / 128, Mm / 128), blk, 0, stream>>>(
      (const short*)yhb, (const short*)WT1, b1, nullptr, f1b, Mm, Rr, Dd);

  // 8: FFN2 split-K=4, bf16 partials -> y+S region; 512 blocks = 2 blocks/CU
  //    (r9 lesson: co-residency, not pipeline depth, is what hides the
  //    2-phase structure's barrier stalls at this shape)
  gemm_mfma<EPI_NONE, 1, 4><<<dim3(Dd / 128, Mm / 128, 4), blk, 0, stream>>>(
      (const short*)f1b, (const short*)WT2, nullptr, nullptr, partial, Mm, Dd, Rr);

  // 9: fused reduce(4x bf16) + bias + relu + residual + final layernorm
  final_ln<<<dim3(Mm), blk, 0, stream>>>(x, partial, b2, ln_w, ln_b, out);
}

// Round 11
// 195.459 us; speedup vs baseline: 1.2006x; 1.1365x over previous
//
#include <hip/hip_runtime.h>
#include <hip/hip_bf16.h>
#include <math.h>

#ifndef M_PI_F
#define M_PI_F 3.14159265358979323846f
#endif

static constexpr int Bb = 2, Tt = 1024, Dd = 1024, Hh = 16, DHh = 64, NFf = 256, Rr = 4096;
static constexpr int Mm = Bb * Tt;
static constexpr int CHK = 64, NCHK = Tt / CHK;  // attention chunking
static constexpr int QS = 3072;                  // fused qkv row stride

enum Epi { EPI_NONE = 0, EPI_RELU, EPI_QKV };

typedef __attribute__((ext_vector_type(8))) short bf16x8;
typedef __attribute__((ext_vector_type(4))) float f32x4;

__device__ inline float bf2f(unsigned short u) {
  union { unsigned int i; float f; } c;
  c.i = (unsigned int)u << 16;
  return c.f;
}

// ---------------------------------------------------------------------------
// async global->LDS, 16B per lane. LDS dest is wave-uniform base; HW adds
// lane*16. Global address is per-lane.
// ---------------------------------------------------------------------------
__device__ inline void gload16(const short* g, short* l) {
  __builtin_amdgcn_global_load_lds(
      (const __attribute__((address_space(1))) unsigned int*)g,
      (__attribute__((address_space(3))) unsigned int*)l, 16, 0, 0);
}

// ---------------------------------------------------------------------------
// bf16 MFMA GEMM: C[M,N] = epi(A[M,K] @ BT[N,K]^T + bias)
// 128x128 tile, BK=64, 4 waves (2x2), each 64x64 via 4x4 frags of 16x16x32.
// - Double-buffered K-loop, counted vmcnt (r7). r9/r10 lesson: >=2 blocks/CU
//   co-residency (m114) is the stall-hiding lever, not pipeline depth.
// - LDS XOR bank-swizzle (rule #21 both-sides involution).
// - Bijective XCD swizzle (m204) for A-panel L2 reuse per XCD.
// - SPLITK: blockIdx.z selects K-slice, writes partial (fp32 Cf / bf16 Cb)
//   at +z*M*N. Caller must keep partials disjoint from A and BT (r4 race).
// ---------------------------------------------------------------------------
#define GSTAGE(bufsel, kk0)                                           \
  _Pragma("unroll") for (int si = 0; si < 4; ++si) {                  \
    const int s = wid + si * 4;                                       \
    gload16(A + (size_t)(m0 + s * 8 + srow) * ldk + (kk0) + skk,      \
            &lA[(bufsel) * 8192 + s * 512]);                          \
    gload16(BT + (size_t)(n0 + s * 8 + srow) * ldk + (kk0) + skk,     \
            &lB[(bufsel) * 8192 + s * 512]);                          \
  }

template <int EPI, int OUTBF, int SPLITK>
__global__ __launch_bounds__(256) void gemm_mfma(const short* __restrict__ A,
                                                 const short* __restrict__ BT,
                                                 const float* __restrict__ bias,
                                                 float* __restrict__ Cf,
                                                 __hip_bfloat16* __restrict__ Cb,
                                                 int M, int N, int ldk) {
  __shared__ short lA[2 * 128 * 64];
  __shared__ short lB[2 * 128 * 64];
  const int tid = threadIdx.x;
  const int wid = tid >> 6, lane = tid & 63;

  // XCD-aware bijective block swizzle (grids here always have nwg % 8 == 0)
  const int nwg = gridDim.x * gridDim.y;
  const int wg = blockIdx.y * gridDim.x + blockIdx.x;
  const int qq = nwg >> 3, rr = nwg & 7;
  const int xcd = wg & 7, idx = wg >> 3;
  const int wg2 = (xcd < rr ? xcd * (qq + 1) : rr * (qq + 1) + (xcd - rr) * qq) + idx;
  const int bx = wg2 % gridDim.x, by = wg2 / gridDim.x;

  const int m0 = by * 128, n0 = bx * 128;
  const int wm = (wid >> 1) * 64, wn = (wid & 1) * 64;
  const int srow = lane >> 3;                         // row within 8-row slab
  const int skk = (((lane & 7) ^ (lane >> 3)) << 3);  // swizzled k offset (elems)

  int kstart = 0, klen = ldk;
  if (SPLITK > 1) {
    klen = ldk / SPLITK;
    kstart = blockIdx.z * klen;
    if (OUTBF)
      Cb += (size_t)blockIdx.z * M * N;
    else
      Cf += (size_t)blockIdx.z * M * N;
  }
  const int kend = kstart + klen;

  f32x4 acc[4][4] = {};

  GSTAGE(0, kstart);  // prologue: 8 loads/wave in flight
  int cur = 0;
  for (int k0 = kstart; k0 < kend; k0 += 64) {
    if (k0 + 64 < kend) {
      GSTAGE(cur ^ 1, k0 + 64);                         // 16 in flight
      asm volatile("s_waitcnt vmcnt(8)" ::: "memory");  // oldest 8 (cur buf) done
    } else {
      asm volatile("s_waitcnt vmcnt(0)" ::: "memory");
    }
    asm volatile("s_barrier" ::: "memory");
    const short* bA = &lA[cur * 8192];
    const short* bB = &lB[cur * 8192];
#pragma unroll
    for (int kk = 0; kk < 2; ++kk) {
      const int krd = kk * 32 + (lane >> 4) * 8;
      const int rsel = lane & 15;
      const int kswz = krd ^ ((rsel & 7) << 3);  // same involution as store side
      bf16x8 af[4], bfr[4];
#pragma unroll
      for (int i = 0; i < 4; ++i) {
        af[i] = *(const bf16x8*)&bA[(wm + i * 16 + rsel) * 64 + kswz];
        bfr[i] = *(const bf16x8*)&bB[(wn + i * 16 + rsel) * 64 + kswz];
      }
#pragma unroll
      for (int i = 0; i < 4; ++i)
#pragma unroll
        for (int j = 0; j < 4; ++j)
          acc[i][j] = __builtin_amdgcn_mfma_f32_16x16x32_bf16(af[i], bfr[j], acc[i][j], 0, 0, 0);
    }
    // ds_read results are consumed by MFMA (compiler lgkmcnt) before here.
    asm volatile("s_barrier" ::: "memory");  // all waves done reading cur buf
    cur ^= 1;
  }

  const int crow = (lane >> 4) * 4;
  const int ccol = lane & 15;
#pragma unroll
  for (int j = 0; j < 4; ++j) {
    const int col = n0 + wn + j * 16 + ccol;
    const float bv = bias ? bias[col] : 0.f;
#pragma unroll
    for (int i = 0; i < 4; ++i) {
#pragma unroll
      for (int r = 0; r < 4; ++r) {
        float v = acc[i][j][r] + bv;
        const int row = m0 + wm + i * 16 + crow + r;
        if (EPI == EPI_QKV) {
          const float vv = (col < 2048) ? fmaxf(v, 0.f) : v;
          Cb[(size_t)row * QS + col] = __float2bfloat16(vv);
        } else {
          if (EPI == EPI_RELU) v = fmaxf(v, 0.f);
          const size_t off = (size_t)row * N + col;
          if (OUTBF)
            Cb[off] = __float2bfloat16(v);
          else
            Cf[off] = v;
        }
      }
    }
  }
}

// ---------------------------------------------------------------------------
// amp/phi split-K reduce (4 bf16 partials) fused with activations and
// polar->cartesian. part layout: [4][M][512] bf16 (cols 0..255 amp, rest phi).
// ---------------------------------------------------------------------------
__global__ __launch_bounds__(256) void reduce_polar(const __hip_bfloat16* __restrict__ part,
                                                    const float* __restrict__ b_amp,
                                                    const float* __restrict__ b_phi,
                                                    __hip_bfloat16* __restrict__ outr,
                                                    __hip_bfloat16* __restrict__ outi) {
  const int idx = blockIdx.x * 256 + threadIdx.x;  // [0, M*NF)
  const int row = idx >> 8, c = idx & 255;
  const size_t MN = (size_t)Mm * 512;
  const size_t pa = (size_t)row * 512 + c;
  const unsigned short* pu = (const unsigned short*)part;
  float a = bf2f(pu[pa]) + bf2f(pu[pa + MN]) + bf2f(pu[pa + 2 * MN]) + bf2f(pu[pa + 3 * MN]) +
            b_amp[c];
  float ph = bf2f(pu[pa + 256]) + bf2f(pu[pa + 256 + MN]) + bf2f(pu[pa + 256 + 2 * MN]) +
             bf2f(pu[pa + 256 + 3 * MN]) + b_phi[c];
  a = (a > 0.f) ? (a + log1pf(expf(-a))) : log1pf(expf(a));
  ph = M_PI_F * tanhf(ph);
  float s, co;
  sincosf(ph, &s, &co);
  outr[idx] = __float2bfloat16(a * co);
  outi[idx] = __float2bfloat16(a * s);
}

// ---------------------------------------------------------------------------
// Fused transpose-cast of all 8 weight matrices (W[K,N] f32 -> WT[N,K] bf16)
// + x f32->bf16 cast (blocks >= 12544).
// ---------------------------------------------------------------------------
struct TCDesc {
  const float* src[8];
  __hip_bfloat16* dst[8];
  const float* x;
  __hip_bfloat16* xb;
};

__global__ __launch_bounds__(256) void transpose_cast_all(TCDesc d) {
  constexpr int KS[8] = {1024, 1024, 768, 1024, 1024, 1024, 1024, 4096};
  constexpr int NS[8] = {256, 256, 1024, 1024, 1024, 1024, 4096, 1024};
  constexpr int CUM[9] = {0, 256, 512, 1280, 2304, 3328, 4352, 8448, 12544};
  const int bid = blockIdx.x;
  if (bid >= 12544) {  // cast_x region: 2048 blocks x 1024 elements
    const int i = ((bid - 12544) * 256 + threadIdx.x) * 4;
    const float4 v = *(const float4*)&d.x[i];
    d.xb[i + 0] = __float2bfloat16(v.x);
    d.xb[i + 1] = __float2bfloat16(v.y);
    d.xb[i + 2] = __float2bfloat16(v.z);
    d.xb[i + 3] = __float2bfloat16(v.w);
    return;
  }
  __shared__ float tile[32][33];
  int w = 0;
#pragma unroll
  for (int i = 0; i < 8; ++i)
    if (bid >= CUM[i + 1]) w = i + 1;
  const int tlocal = bid - CUM[w];
  const int K = KS[w], N = NS[w];
  const int tilesN = N / 32;
  const int bk = (tlocal / tilesN) * 32, bn = (tlocal % tilesN) * 32;
  const float* W = d.src[w];
  __hip_bfloat16* WT = d.dst[w];
  const int tx = threadIdx.x & 31, ty = threadIdx.x >> 5;  // 32x8
#pragma unroll
  for (int r = 0; r < 32; r += 8) tile[ty + r][tx] = W[(size_t)(bk + ty + r) * N + bn + tx];
  __syncthreads();
#pragma unroll
  for (int r = 0; r < 32; r += 8)
    WT[(size_t)(bn + ty + r) * K + bk + tx] = __float2bfloat16(tile[tx][ty + r]);
}

// ---------------------------------------------------------------------------
// Sequential complex resonator recurrence; writes feat bf16 [B,T,3*NF].
// TIME-CHUNK PARALLEL (r6): contraction >= sigmoid(2.0)=0.881/step makes a
// 128-step warm-up from X=0 exact to below bf16 quantization. 64 blocks x
// 64 lanes; register double-buffer (P=16) keeps ~4KB/wave in flight.
// ---------------------------------------------------------------------------
static constexpr int RES_P = 16;
static constexpr int RES_TC = 128;  // chunk length
static constexpr int RES_W = 128;   // warm-up length

#define RES_LOAD(buf_r, buf_i, tg)                                        \
  if ((tg) < cend) {                                                      \
    _Pragma("unroll") for (int i = 0; i < RES_P; ++i) {                   \
      buf_r[i] = __bfloat162float(ur[bbase + (size_t)((tg) + i) * NFf]);  \
      buf_i[i] = __bfloat162float(ui[bbase + (size_t)((tg) + i) * NFf]);  \
    }                                                                     \
  }

#define RES_STEP(buf_r, buf_i, tg)                                      \
  {                                                                      \
    const bool wr_ = (tg) >= cstart;                                     \
    _Pragma("unroll") for (int i = 0; i < RES_P; ++i) {                  \
      const float pr = fmaf(ar, Xr, fmaf(-ai, Xi, buf_r[i]));            \
      const float pim = fmaf(ar, Xi, fmaf(ai, Xr, buf_i[i]));            \
      const float mag = __builtin_amdgcn_sqrtf(fmaf(pr, pr, pim * pim)); \
      const float g = __builtin_amdgcn_rcpf(1.f + __expf(th - mag));     \
      Xr = pr * g;                                                       \
      Xi = pim * g;                                                      \
      if (wr_) {                                                         \
        const size_t fb = ((size_t)b * Tt + (tg) + i) * (3 * NFf);       \
        featb[fb + f] = __float2bfloat16(Xr);                            \
        featb[fb + NFf + f] = __float2bfloat16(Xi);                      \
        featb[fb + 2 * NFf + f] = __float2bfloat16(mag * g);             \
      }                                                                  \
    }                                                                    \
  }

__global__ __launch_bounds__(64) void resonator_scan(const __hip_bfloat16* __restrict__ ur,
                                                     const __hip_bfloat16* __restrict__ ui,
                                                     const float* __restrict__ omega,
                                                     const float* __restrict__ ret_logit,
                                                     const float* __restrict__ theta,
                                                     __hip_bfloat16* __restrict__ featb) {
  const int bid = blockIdx.x;  // 64 blocks: (b:2, fs:4, tc:8)
  const int tc = bid & 7;
  const int fs = (bid >> 3) & 3;
  const int b = bid >> 5;
  const int f = fs * 64 + threadIdx.x;
  const int cstart = tc * RES_TC;
  const int cend = cstart + RES_TC;
  const int tbeg = (cstart >= RES_W) ? cstart - RES_W : 0;

  const float dec = 1.f / (1.f + __expf(-ret_logit[f]));
  float so, co;
  sincosf(omega[f], &so, &co);
  const float ar = dec * co, ai = dec * so;
  const float th = theta[f];
  const size_t bbase = (size_t)b * Tt * NFf + f;
  float Xr = 0.f, Xi = 0.f;
  float Ar[RES_P], Ai[RES_P], Br[RES_P], Bi[RES_P];
  RES_LOAD(Ar, Ai, tbeg);
  for (int t0 = tbeg; t0 < cend; t0 += 2 * RES_P) {
    RES_LOAD(Br, Bi, t0 + RES_P);
    RES_STEP(Ar, Ai, t0);
    RES_LOAD(Ar, Ai, t0 + 2 * RES_P);
    RES_STEP(Br, Bi, t0 + RES_P);
  }
}

// ---------------------------------------------------------------------------
// Attention phase A: per-chunk KV outer-product sums and k-sums (bf16 qkv).
// ---------------------------------------------------------------------------
__global__ __launch_bounds__(256) void attn_chunk_kv(const __hip_bfloat16* __restrict__ k,
                                                     const __hip_bfloat16* __restrict__ v,
                                                     float* __restrict__ S,
                                                     float* __restrict__ Ksum) {
  __shared__ float Ks[64][68], Vs[64][68];
  const int g = blockIdx.x;
  const int j = g & (NCHK - 1), bh = g >> 4;
  const int b = bh >> 4, h = bh & (Hh - 1);
  const int tid = threadIdx.x;
  const size_t rowbase = (size_t)(b * Tt + j * CHK) * QS + h * DHh;
  const unsigned short* ku = (const unsigned short*)k;
  const unsigned short* vu = (const unsigned short*)v;
  for (int l = tid; l < 4096; l += 256) {
    const int s = l >> 6, d = l & 63;
    Ks[s][d] = bf2f(ku[rowbase + (size_t)s * QS + d]);
    Vs[s][d] = bf2f(vu[rowbase + (size_t)s * QS + d]);
  }
  __syncthreads();
  const int d0 = tid & 63, eb = tid >> 6, e0 = eb * 16;
  float4 acc4[4] = {};
  float ks = 0.f;
  for (int s = 0; s < 64; ++s) {
    const float kd = Ks[s][d0];
    ks += kd;
#pragma unroll
    for (int i = 0; i < 4; ++i) {
      const float4 v4 = *(const float4*)&Vs[s][e0 + 4 * i];
      acc4[i].x = fmaf(kd, v4.x, acc4[i].x);
      acc4[i].y = fmaf(kd, v4.y, acc4[i].y);
      acc4[i].z = fmaf(kd, v4.z, acc4[i].z);
      acc4[i].w = fmaf(kd, v4.w, acc4[i].w);
    }
  }
  float* Sg = S + (size_t)g * 4096 + (size_t)d0 * 64 + e0;
#pragma unroll
  for (int i = 0; i < 4; ++i) *(float4*)&Sg[4 * i] = acc4[i];
  if (eb == 0) Ksum[(size_t)g * 64 + d0] = ks;
}

// ---------------------------------------------------------------------------
// Attention phase B: EXCLUSIVE prefix over the 16 chunks per (b,h).
// FULLY PARALLEL (r10 post-mortem: the 32-block version put 16 MB on 32 CUs
// = ~20 us per-CU-BW + chained latency). 131072 S-chains + 2048 Ksum-chains
// are independent: one thread per chain, prefetch all 16 values (independent
// addresses -> one latency), prefix in registers, store. Grid 520 blocks.
// ---------------------------------------------------------------------------
__global__ __launch_bounds__(256) void attn_prefix(float* __restrict__ S,
                                                   float* __restrict__ Ksum) {
  const int bid = blockIdx.x;
  const int tid = threadIdx.x;
  if (bid < 512) {
    const int bh = bid >> 4, r = bid & 15;
    const int de = r * 256 + tid;
    const size_t base = (size_t)bh * (NCHK * 4096) + de;
    float vv[NCHK];
#pragma unroll
    for (int j = 0; j < NCHK; ++j) vv[j] = S[base + (size_t)j * 4096];
    float run = 0.f;
#pragma unroll
    for (int j = 0; j < NCHK; ++j) {
      const float tmp = vv[j];
      S[base + (size_t)j * 4096] = run;
      run += tmp;
    }
  } else {
    const int cid = (bid - 512) * 256 + tid;  // [0, 2048)
    const int bh = cid >> 6, d = cid & 63;
    const size_t base = (size_t)bh * (NCHK * 64) + d;
    float vv[NCHK];
#pragma unroll
    for (int j = 0; j < NCHK; ++j) vv[j] = Ksum[base + (size_t)j * 64];
    float run = 0.f;
#pragma unroll
    for (int j = 0; j < NCHK; ++j) {
      const float tmp = vv[j];
      Ksum[base + (size_t)j * 64] = run;
      run += tmp;
    }
  }
}

// ---------------------------------------------------------------------------
// Attention phase C + fused per-head layernorm. bf16 q/k/v (stride QS);
// output yhb bf16 [B*T, 1024]. Each block computes 64 complete (t, h)-rows,
// so LN-over-DH=64 is done in-kernel: row t is held by 4 sg-lanes x 16 e;
// stats via shfl_xor(1|2).
// ---------------------------------------------------------------------------
__global__ __launch_bounds__(256) void attn_out(const __hip_bfloat16* __restrict__ q,
                                                const __hip_bfloat16* __restrict__ k,
                                                const __hip_bfloat16* __restrict__ v,
                                                const float* __restrict__ S,
                                                const float* __restrict__ Ksum,
                                                const float* __restrict__ lnw,
                                                const float* __restrict__ lnb,
                                                __hip_bfloat16* __restrict__ yhb) {
  __shared__ float Qt[64][65];
  __shared__ float KVP[64][68];
  __shared__ float At[64][65];
  const int g = blockIdx.x;
  const int j = g & (NCHK - 1), bh = g >> 4;
  const int b = bh >> 4, h = bh & (Hh - 1);
  const int tid = threadIdx.x;
  const size_t rowbase = (size_t)(b * Tt + j * CHK) * QS + h * DHh;
  const unsigned short* qu = (const unsigned short*)q;
  const unsigned short* ku = (const unsigned short*)k;
  const unsigned short* vu = (const unsigned short*)v;
  for (int l = tid; l < 4096; l += 256) {
    const int s = l >> 6, d = l & 63;
    Qt[d][s] = bf2f(qu[rowbase + (size_t)s * QS + d]);
    KVP[s][d] = bf2f(ku[rowbase + (size_t)s * QS + d]);
  }
  __syncthreads();
  const int t = tid >> 2, sg = tid & 3;
  const float* pk = Ksum + (size_t)g * 64;
  // --- stage 1: masked scores + denominator ---
  float adot[16] = {};
  float qpk = 0.f;
  for (int c = 0; c < 16; ++c) {
    const float q0 = Qt[4 * c + 0][t], q1 = Qt[4 * c + 1][t];
    const float q2 = Qt[4 * c + 2][t], q3 = Qt[4 * c + 3][t];
    const float4 pk4 = *(const float4*)&pk[4 * c];
    qpk = fmaf(q0, pk4.x, fmaf(q1, pk4.y, fmaf(q2, pk4.z, fmaf(q3, pk4.w, qpk))));
#pragma unroll
    for (int i = 0; i < 16; ++i) {
      const float4 k4 = *(const float4*)&KVP[sg * 16 + i][4 * c];
      adot[i] = fmaf(q0, k4.x, fmaf(q1, k4.y, fmaf(q2, k4.z, fmaf(q3, k4.w, adot[i]))));
    }
  }
  float rs = 0.f;
#pragma unroll
  for (int i = 0; i < 16; ++i) {
    if (sg * 16 + i > t) adot[i] = 0.f;
    rs += adot[i];
  }
  rs += __shfl_xor(rs, 1);
  rs += __shfl_xor(rs, 2);
  const float den = qpk + rs + 1e-6f;
  __syncthreads();  // all K reads complete
#pragma unroll
  for (int i = 0; i < 16; ++i) At[sg * 16 + i][t] = adot[i];
  for (int l = tid; l < 4096; l += 256) {  // overwrite K with V
    const int s = l >> 6, d = l & 63;
    KVP[s][d] = bf2f(vu[rowbase + (size_t)s * QS + d]);
  }
  __syncthreads();
  // --- stage 2a: masked-score @ V ---
  const int e0 = sg * 16;
  float4 num[4] = {};
  for (int s = 0; s <= t; ++s) {
    const float av = At[s][t];
#pragma unroll
    for (int i = 0; i < 4; ++i) {
      const float4 v4 = *(const float4*)&KVP[s][e0 + 4 * i];
      num[i].x = fmaf(av, v4.x, num[i].x);
      num[i].y = fmaf(av, v4.y, num[i].y);
      num[i].z = fmaf(av, v4.z, num[i].z);
      num[i].w = fmaf(av, v4.w, num[i].w);
    }
  }
  __syncthreads();  // all V reads complete
  const float* Pg = S + (size_t)g * 4096;
  for (int l = tid; l < 4096; l += 256) KVP[l >> 6][l & 63] = Pg[l];
  __syncthreads();
  // --- stage 2b: Q @ P ---
  for (int d = 0; d < 64; ++d) {
    const float qd = Qt[d][t];
#pragma unroll
    for (int i = 0; i < 4; ++i) {
      const float4 p4 = *(const float4*)&KVP[d][e0 + 4 * i];
      num[i].x = fmaf(qd, p4.x, num[i].x);
      num[i].y = fmaf(qd, p4.y, num[i].y);
      num[i].z = fmaf(qd, p4.z, num[i].z);
      num[i].w = fmaf(qd, p4.w, num[i].w);
    }
  }
  const float inv = 1.f / den;
  float o[16];
#pragma unroll
  for (int i = 0; i < 4; ++i) {
    o[4 * i + 0] = num[i].x * inv;
    o[4 * i + 1] = num[i].y * inv;
    o[4 * i + 2] = num[i].z * inv;
    o[4 * i + 3] = num[i].w * inv;
  }
  // --- fused per-head LN over the 64-wide row (4 sg-lanes x 16 e) ---
  float s1 = 0.f, s2 = 0.f;
#pragma unroll
  for (int i = 0; i < 16; ++i) {
    s1 += o[i];
    s2 += o[i] * o[i];
  }
  s1 += __shfl_xor(s1, 1);
  s1 += __shfl_xor(s1, 2);
  s2 += __shfl_xor(s2, 1);
  s2 += __shfl_xor(s2, 2);
  const float mean = s1 * (1.f / 64.f);
  const float var = s2 * (1.f / 64.f) - mean * mean;
  const float rsv = rsqrtf(var + 1e-5f);
  const float* wv = lnw + h * DHh + e0;
  const float* bv = lnb + h * DHh + e0;
  unsigned short ob[16];
#pragma unroll
  for (int i = 0; i < 16; ++i) {
    const float r = (o[i] - mean) * rsv * wv[i] + bv[i];
    __hip_bfloat16 hv = __float2bfloat16(r);
    ob[i] = *(unsigned short*)&hv;
  }
  unsigned short* yg =
      (unsigned short*)yhb + (size_t)(b * Tt + j * CHK + t) * Dd + h * DHh + e0;
#pragma unroll
  for (int i = 0; i < 4; ++i) *(ushort4*)&yg[4 * i] = *(ushort4*)&ob[4 * i];
}

// ---------------------------------------------------------------------------
// Fused FFN2-reduce (4 bf16 split-K partials) + bias + relu + residual +
// final layernorm over D=1024.
// ---------------------------------------------------------------------------
__global__ __launch_bounds__(256) void final_ln(const float* __restrict__ x,
                                                const __hip_bfloat16* __restrict__ part,
                                                const float* __restrict__ b2,
                                                const float* __restrict__ w,
                                                const float* __restrict__ bb,
                                                float* __restrict__ out) {
  __shared__ float r1[4], r2[4];
  const int row = blockIdx.x;
  const int tid = threadIdx.x;
  const size_t off = (size_t)row * Dd + tid * 4;
  const size_t MN = (size_t)Mm * Dd;
  float acc4[4] = {0.f, 0.f, 0.f, 0.f};
#pragma unroll
  for (int z = 0; z < 4; ++z) {
    const ushort4 u = *(const ushort4*)&part[off + (size_t)z * MN];
    acc4[0] += bf2f(u.x);
    acc4[1] += bf2f(u.y);
    acc4[2] += bf2f(u.z);
    acc4[3] += bf2f(u.w);
  }
  const float4 bv = *(const float4*)&b2[tid * 4];
  const float4 xa = *(const float4*)&x[off];
  float z[4];
  z[0] = xa.x + fmaxf(acc4[0] + bv.x, 0.f);
  z[1] = xa.y + fmaxf(acc4[1] + bv.y, 0.f);
  z[2] = xa.z + fmaxf(acc4[2] + bv.z, 0.f);
  z[3] = xa.w + fmaxf(acc4[3] + bv.w, 0.f);
  float s1 = z[0] + z[1] + z[2] + z[3];
  float s2 = z[0] * z[0] + z[1] * z[1] + z[2] * z[2] + z[3] * z[3];
#pragma unroll
  for (int o = 1; o < 64; o <<= 1) {
    s1 += __shfl_xor(s1, o);
    s2 += __shfl_xor(s2, o);
  }
  const int wid = tid >> 6;
  if ((tid & 63) == 0) {
    r1[wid] = s1;
    r2[wid] = s2;
  }
  __syncthreads();
  const float t1 = r1[0] + r1[1] + r1[2] + r1[3];
  const float t2 = r2[0] + r2[1] + r2[2] + r2[3];
  const float mu = t1 * (1.f / Dd);
  const float var = t2 * (1.f / Dd) - mu * mu;
  const float rsv = rsqrtf(var + 1e-5f);
  float4 o4;
  float* op = &o4.x;
#pragma unroll
  for (int jj = 0; jj < 4; ++jj) op[jj] = (z[jj] - mu) * rsv * w[tid * 4 + jj] + bb[tid * 4 + jj];
  *(float4*)&out[off] = o4;
}

// ---------------------------------------------------------------------------
extern "C" void kernel_launch(void* const* d_in, const int* in_sizes, int n_in,
                              void* d_out, int out_size, void* d_ws, size_t ws_size,
                              hipStream_t stream) {
  const float* x = (const float*)d_in[0];
  const float* W_amp = (const float*)d_in[1];
  const float* b_amp = (const float*)d_in[2];
  const float* W_phi = (const float*)d_in[3];
  const float* b_phi = (const float*)d_in[4];
  const float* omega = (const float*)d_in[5];
  const float* ret_logit = (const float*)d_in[6];
  const float* theta = (const float*)d_in[7];
  const float* W_feat = (const float*)d_in[8];
  const float* b_feat = (const float*)d_in[9];
  const float* Wq = (const float*)d_in[10];
  const float* Wk = (const float*)d_in[11];
  const float* Wv = (const float*)d_in[12];
  const float* lnh_w = (const float*)d_in[13];
  const float* lnh_b = (const float*)d_in[14];
  const float* W1 = (const float*)d_in[15];
  const float* b1 = (const float*)d_in[16];
  const float* W2 = (const float*)d_in[17];
  const float* b2 = (const float*)d_in[18];
  const float* ln_w = (const float*)d_in[19];
  const float* ln_b = (const float*)d_in[20];

  // ---- workspace bump allocator (256B aligned) ----
  char* p = (char*)d_ws;
  auto alloc = [&](size_t bytes) {
    char* r = p;
    p += (bytes + 255) & ~(size_t)255;
    return r;
  };
  __hip_bfloat16* xb = (__hip_bfloat16*)alloc((size_t)Mm * Dd * 2);   // later: featb
  __hip_bfloat16* urh = (__hip_bfloat16*)alloc((size_t)Mm * NFf * 2);
  __hip_bfloat16* uih = (__hip_bfloat16*)alloc((size_t)Mm * NFf * 2);
  __hip_bfloat16* WTamp = (__hip_bfloat16*)alloc((size_t)NFf * Dd * 2);  // +WTphi contiguous
  __hip_bfloat16* WTphi = (__hip_bfloat16*)alloc((size_t)NFf * Dd * 2);
  __hip_bfloat16* WTfeat = (__hip_bfloat16*)alloc((size_t)Dd * 3 * NFf * 2);
  __hip_bfloat16* WTq = (__hip_bfloat16*)alloc((size_t)Dd * Dd * 2);  // +k+v contiguous
  __hip_bfloat16* WTk = (__hip_bfloat16*)alloc((size_t)Dd * Dd * 2);
  __hip_bfloat16* WTv = (__hip_bfloat16*)alloc((size_t)Dd * Dd * 2);
  __hip_bfloat16* WT1 = (__hip_bfloat16*)alloc((size_t)Rr * Dd * 2);
  __hip_bfloat16* WT2 = (__hip_bfloat16*)alloc((size_t)Dd * Rr * 2);
  __hip_bfloat16* hb = (__hip_bfloat16*)alloc((size_t)Mm * Dd * 2);
  __hip_bfloat16* qkvb = (__hip_bfloat16*)alloc((size_t)Mm * QS * 2);  // 12 MB
  __hip_bfloat16* yhb = (__hip_bfloat16*)alloc((size_t)Mm * Dd * 2);   // 4 MB (contig w/ qkvb)
  float* S = (float*)alloc((size_t)Bb * Hh * NCHK * 4096 * 4);         // 8 MB
  float* Ksum = (float*)alloc((size_t)Bb * Hh * NCHK * 64 * 4);
  __hip_bfloat16* f1b = (__hip_bfloat16*)alloc((size_t)Mm * Rr * 2);   // 16 MB

  __hip_bfloat16* featb = xb;
  const __hip_bfloat16* q = qkvb;
  const __hip_bfloat16* k = qkvb + 1024;
  const __hip_bfloat16* v = qkvb + 2048;
  // amp/phi split-K=4 bf16 partials [4][M][512] = 8 MB in the (then-dead) qkvb region
  __hip_bfloat16* pamp = qkvb;
  // FFN2 bf16 partials [4][M][1024] = 16 MB over qkvb(12)+yhb(4) (contiguous
  // allocations; both dead after FFN1 reads yhb). Disjoint from f1b and WT2.
  __hip_bfloat16* partial = qkvb;
  float* out = (float*)d_out;

  const dim3 blk(256);

  // 0: weight transpose-casts + x cast (single kernel)
  TCDesc tc;
  tc.src[0] = W_amp; tc.dst[0] = WTamp;
  tc.src[1] = W_phi; tc.dst[1] = WTphi;
  tc.src[2] = W_feat; tc.dst[2] = WTfeat;
  tc.src[3] = Wq; tc.dst[3] = WTq;
  tc.src[4] = Wk; tc.dst[4] = WTk;
  tc.src[5] = Wv; tc.dst[5] = WTv;
  tc.src[6] = W1; tc.dst[6] = WT1;
  tc.src[7] = W2; tc.dst[7] = WT2;
  tc.x = x; tc.xb = xb;
  transpose_cast_all<<<dim3(12544 + 2048), blk, 0, stream>>>(tc);

  // 1: fused amp/phi projection, split-K=4 (256 blocks, bf16 partials), then
  //    fused reduce + softplus/tanh + polar -> bf16 u
  gemm_mfma<EPI_NONE, 1, 4><<<dim3(512 / 128, Mm / 128, 4), blk, 0, stream>>>(
      (const short*)xb, (const short*)WTamp, nullptr, nullptr, pamp, Mm, 512, Dd);
  reduce_polar<<<dim3(Mm * NFf / 256), blk, 0, stream>>>(pamp, b_amp, b_phi, urh, uih);

  // 2: resonator scan -> feat (bf16); 64 blocks x 64 lanes, time-chunked
  resonator_scan<<<dim3(64), dim3(64), 0, stream>>>(urh, uih, omega, ret_logit, theta, featb);

  // 3: feat projection -> h (bf16)
  gemm_mfma<EPI_RELU, 1, 0><<<dim3(Dd / 128, Mm / 128), blk, 0, stream>>>(
      (const short*)featb, (const short*)WTfeat, b_feat, nullptr, hb, Mm, Dd, 3 * NFf);

  // 4: fused q,k,v projection -> bf16 qkvb (384 blocks, 1.5 blocks/CU)
  gemm_mfma<EPI_QKV, 1, 0><<<dim3(QS / 128, Mm / 128), blk, 0, stream>>>(
      (const short*)hb, (const short*)WTq, nullptr, nullptr, qkvb, Mm, QS, Dd);

  // 5: chunked causal linear attention (+ fused per-head LN in attn_out)
  attn_chunk_kv<<<dim3(Bb * Hh * NCHK), blk, 0, stream>>>(k, v, S, Ksum);
  attn_prefix<<<dim3(520), blk, 0, stream>>>(S, Ksum);
  attn_out<<<dim3(Bb * Hh * NCHK), blk, 0, stream>>>(q, k, v, S, Ksum, lnh_w, lnh_b, yhb);

  // 6: FFN1 -> f1b (bf16); 512 blocks = 2 blocks/CU
  gemm_mfma<EPI_RELU, 1, 0><<<dim3(Rr / 128, Mm / 128), blk, 0, stream>>>(
      (const short*)yhb, (const short*)WT1, b1, nullptr, f1b, Mm, Rr, Dd);

  // 7: FFN2 split-K=4, bf16 partials -> qkvb+yhb region; 512 blocks = 2/CU
  gemm_mfma<EPI_NONE, 1, 4><<<dim3(Dd / 128, Mm / 128, 4), blk, 0, stream>>>(
      (const short*)f1b, (const short*)WT2, nullptr, nullptr, partial, Mm, Dd, Rr);

  // 8: fused reduce(4x bf16) + bias + relu + residual + final layernorm
  final_ln<<<dim3(Mm), blk, 0, stream>>>(x, partial, b2, ln_w, ln_b, out);
}

// Round 12
// 186.969 us; speedup vs baseline: 1.2551x; 1.0454x over previous
//
#include <hip/hip_runtime.h>
#include <hip/hip_bf16.h>
#include <math.h>

#ifndef M_PI_F
#define M_PI_F 3.14159265358979323846f
#endif

static constexpr int Bb = 2, Tt = 1024, Dd = 1024, Hh = 16, DHh = 64, NFf = 256, Rr = 4096;
static constexpr int Mm = Bb * Tt;
static constexpr int CHK = 64, NCHK = Tt / CHK;  // attention chunking
static constexpr int QS = 3072;                  // fused qkv row stride

enum Epi { EPI_NONE = 0, EPI_RELU, EPI_QKV };

typedef __attribute__((ext_vector_type(8))) short bf16x8;
typedef __attribute__((ext_vector_type(4))) float f32x4;

__device__ inline float bf2f(unsigned short u) {
  union { unsigned int i; float f; } c;
  c.i = (unsigned int)u << 16;
  return c.f;
}

// ---------------------------------------------------------------------------
// async global->LDS, 16B per lane. LDS dest is wave-uniform base; HW adds
// lane*16. Global address is per-lane.
// ---------------------------------------------------------------------------
__device__ inline void gload16(const short* g, short* l) {
  __builtin_amdgcn_global_load_lds(
      (const __attribute__((address_space(1))) unsigned int*)g,
      (__attribute__((address_space(3))) unsigned int*)l, 16, 0, 0);
}

// ---------------------------------------------------------------------------
// bf16 MFMA GEMM: C[M,N] = epi(A[M,K] @ BT[N,K]^T + bias)
// 128x128 tile, BK=64, 4 waves (2x2), each 64x64 via 4x4 frags of 16x16x32.
// - Double-buffered K-loop, counted vmcnt (r7). r9/r10 lesson: >=2 blocks/CU
//   co-residency (m114) is the stall-hiding lever, not pipeline depth; with
//   64KB LDS the cap is 2 blocks/CU, so grids beyond 512 blocks buy nothing.
// - LDS XOR bank-swizzle (rule #21 both-sides involution).
// - Bijective XCD swizzle (m204) for A-panel L2 reuse per XCD.
// - SPLITK: blockIdx.z selects K-slice, writes partial (fp32 Cf / bf16 Cb)
//   at +z*M*N. Partials live in DEDICATED buffers (r4 overlay race lesson).
// ---------------------------------------------------------------------------
#define GSTAGE(bufsel, kk0)                                           \
  _Pragma("unroll") for (int si = 0; si < 4; ++si) {                  \
    const int s = wid + si * 4;                                       \
    gload16(A + (size_t)(m0 + s * 8 + srow) * ldk + (kk0) + skk,      \
            &lA[(bufsel) * 8192 + s * 512]);                          \
    gload16(BT + (size_t)(n0 + s * 8 + srow) * ldk + (kk0) + skk,     \
            &lB[(bufsel) * 8192 + s * 512]);                          \
  }

template <int EPI, int OUTBF, int SPLITK>
__global__ __launch_bounds__(256) void gemm_mfma(const short* __restrict__ A,
                                                 const short* __restrict__ BT,
                                                 const float* __restrict__ bias,
                                                 float* __restrict__ Cf,
                                                 __hip_bfloat16* __restrict__ Cb,
                                                 int M, int N, int ldk) {
  __shared__ short lA[2 * 128 * 64];
  __shared__ short lB[2 * 128 * 64];
  const int tid = threadIdx.x;
  const int wid = tid >> 6, lane = tid & 63;

  // XCD-aware bijective block swizzle (grids here always have nwg % 8 == 0)
  const int nwg = gridDim.x * gridDim.y;
  const int wg = blockIdx.y * gridDim.x + blockIdx.x;
  const int qq = nwg >> 3, rr = nwg & 7;
  const int xcd = wg & 7, idx = wg >> 3;
  const int wg2 = (xcd < rr ? xcd * (qq + 1) : rr * (qq + 1) + (xcd - rr) * qq) + idx;
  const int bx = wg2 % gridDim.x, by = wg2 / gridDim.x;

  const int m0 = by * 128, n0 = bx * 128;
  const int wm = (wid >> 1) * 64, wn = (wid & 1) * 64;
  const int srow = lane >> 3;                         // row within 8-row slab
  const int skk = (((lane & 7) ^ (lane >> 3)) << 3);  // swizzled k offset (elems)

  int kstart = 0, klen = ldk;
  if (SPLITK > 1) {
    klen = ldk / SPLITK;
    kstart = blockIdx.z * klen;
    if (OUTBF)
      Cb += (size_t)blockIdx.z * M * N;
    else
      Cf += (size_t)blockIdx.z * M * N;
  }
  const int kend = kstart + klen;

  f32x4 acc[4][4] = {};

  GSTAGE(0, kstart);  // prologue: 8 loads/wave in flight
  int cur = 0;
  for (int k0 = kstart; k0 < kend; k0 += 64) {
    if (k0 + 64 < kend) {
      GSTAGE(cur ^ 1, k0 + 64);                         // 16 in flight
      asm volatile("s_waitcnt vmcnt(8)" ::: "memory");  // oldest 8 (cur buf) done
    } else {
      asm volatile("s_waitcnt vmcnt(0)" ::: "memory");
    }
    asm volatile("s_barrier" ::: "memory");
    const short* bA = &lA[cur * 8192];
    const short* bB = &lB[cur * 8192];
#pragma unroll
    for (int kk = 0; kk < 2; ++kk) {
      const int krd = kk * 32 + (lane >> 4) * 8;
      const int rsel = lane & 15;
      const int kswz = krd ^ ((rsel & 7) << 3);  // same involution as store side
      bf16x8 af[4], bfr[4];
#pragma unroll
      for (int i = 0; i < 4; ++i) {
        af[i] = *(const bf16x8*)&bA[(wm + i * 16 + rsel) * 64 + kswz];
        bfr[i] = *(const bf16x8*)&bB[(wn + i * 16 + rsel) * 64 + kswz];
      }
#pragma unroll
      for (int i = 0; i < 4; ++i)
#pragma unroll
        for (int j = 0; j < 4; ++j)
          acc[i][j] = __builtin_amdgcn_mfma_f32_16x16x32_bf16(af[i], bfr[j], acc[i][j], 0, 0, 0);
    }
    // ds_read results are consumed by MFMA (compiler lgkmcnt) before here.
    asm volatile("s_barrier" ::: "memory");  // all waves done reading cur buf
    cur ^= 1;
  }

  const int crow = (lane >> 4) * 4;
  const int ccol = lane & 15;
#pragma unroll
  for (int j = 0; j < 4; ++j) {
    const int col = n0 + wn + j * 16 + ccol;
    const float bv = bias ? bias[col] : 0.f;
#pragma unroll
    for (int i = 0; i < 4; ++i) {
#pragma unroll
      for (int r = 0; r < 4; ++r) {
        float v = acc[i][j][r] + bv;
        const int row = m0 + wm + i * 16 + crow + r;
        if (EPI == EPI_QKV) {
          const float vv = (col < 2048) ? fmaxf(v, 0.f) : v;
          Cb[(size_t)row * QS + col] = __float2bfloat16(vv);
        } else {
          if (EPI == EPI_RELU) v = fmaxf(v, 0.f);
          const size_t off = (size_t)row * N + col;
          if (OUTBF)
            Cb[off] = __float2bfloat16(v);
          else
            Cf[off] = v;
        }
      }
    }
  }
}

// ---------------------------------------------------------------------------
// 32x32 transpose-cast tile helper: W[K,N] f32 -> WT[N,K] bf16.
// ---------------------------------------------------------------------------
__device__ __forceinline__ void tc_tile(float (*tile)[33], const float* __restrict__ W,
                                        __hip_bfloat16* __restrict__ WT, int K, int N,
                                        int tlocal) {
  const int tilesN = N / 32;
  const int bk = (tlocal / tilesN) * 32, bn = (tlocal % tilesN) * 32;
  const int tx = threadIdx.x & 31, ty = threadIdx.x >> 5;  // 32x8
#pragma unroll
  for (int r = 0; r < 32; r += 8) tile[ty + r][tx] = W[(size_t)(bk + ty + r) * N + bn + tx];
  __syncthreads();
#pragma unroll
  for (int r = 0; r < 32; r += 8)
    WT[(size_t)(bn + ty + r) * K + bk + tx] = __float2bfloat16(tile[tx][ty + r]);
}

// ---------------------------------------------------------------------------
// Head kernel: W_amp / W_phi transpose-cast + x f32->bf16 cast.
// Blocks: [0,256) amp tiles, [256,512) phi tiles, [512,2560) x cast.
// ---------------------------------------------------------------------------
__global__ __launch_bounds__(256) void tc_first(const float* __restrict__ W_amp,
                                                const float* __restrict__ W_phi,
                                                __hip_bfloat16* __restrict__ WTamp,
                                                __hip_bfloat16* __restrict__ WTphi,
                                                const float* __restrict__ x,
                                                __hip_bfloat16* __restrict__ xb) {
  __shared__ float tile[32][33];
  const int bid = blockIdx.x;
  if (bid >= 512) {
    const int i = ((bid - 512) * 256 + threadIdx.x) * 4;
    const float4 v = *(const float4*)&x[i];
    xb[i + 0] = __float2bfloat16(v.x);
    xb[i + 1] = __float2bfloat16(v.y);
    xb[i + 2] = __float2bfloat16(v.z);
    xb[i + 3] = __float2bfloat16(v.w);
    return;
  }
  if (bid < 256)
    tc_tile(tile, W_amp, WTamp, 1024, 256, bid);
  else
    tc_tile(tile, W_phi, WTphi, 1024, 256, bid - 256);
}

// ---------------------------------------------------------------------------
// amp/phi split-K reduce (4 bf16 partials) fused with activations and
// polar->cartesian. part layout: [4][M][512] bf16 (cols 0..255 amp, rest phi).
// ---------------------------------------------------------------------------
__global__ __launch_bounds__(256) void reduce_polar(const __hip_bfloat16* __restrict__ part,
                                                    const float* __restrict__ b_amp,
                                                    const float* __restrict__ b_phi,
                                                    __hip_bfloat16* __restrict__ outr,
                                                    __hip_bfloat16* __restrict__ outi) {
  const int idx = blockIdx.x * 256 + threadIdx.x;  // [0, M*NF)
  const int row = idx >> 8, c = idx & 255;
  const size_t MN = (size_t)Mm * 512;
  const size_t pa = (size_t)row * 512 + c;
  const unsigned short* pu = (const unsigned short*)part;
  float a = bf2f(pu[pa]) + bf2f(pu[pa + MN]) + bf2f(pu[pa + 2 * MN]) + bf2f(pu[pa + 3 * MN]) +
            b_amp[c];
  float ph = bf2f(pu[pa + 256]) + bf2f(pu[pa + 256 + MN]) + bf2f(pu[pa + 256 + 2 * MN]) +
             bf2f(pu[pa + 256 + 3 * MN]) + b_phi[c];
  a = (a > 0.f) ? (a + log1pf(expf(-a))) : log1pf(expf(a));
  ph = M_PI_F * tanhf(ph);
  float s, co;
  sincosf(ph, &s, &co);
  outr[idx] = __float2bfloat16(a * co);
  outi[idx] = __float2bfloat16(a * s);
}

// ---------------------------------------------------------------------------
// FUSED: resonator scan (blocks 0..63) || transpose-cast of the 6 remaining
// weights (blocks 64..12095). r11 post-mortem: the scan (64 blocks, ~10us of
// latency chains) serialized with the 12k-block transpose although they are
// independent — fusing lets the transpose backfill the other ~190 CUs.
//
// Scan: TIME-CHUNK PARALLEL (r6): contraction >= sigmoid(2.0)=0.881/step
// makes a 128-step warm-up from X=0 exact below bf16 quantization. Register
// double-buffer (P=16) keeps ~4KB/wave in flight (r3/r6 lessons).
// ---------------------------------------------------------------------------
static constexpr int RES_P = 16;
static constexpr int RES_TC = 128;  // chunk length
static constexpr int RES_W = 128;   // warm-up length

#define RES_LOAD(buf_r, buf_i, tg)                                        \
  if ((tg) < cend) {                                                      \
    _Pragma("unroll") for (int i = 0; i < RES_P; ++i) {                   \
      buf_r[i] = __bfloat162float(ur[bbase + (size_t)((tg) + i) * NFf]);  \
      buf_i[i] = __bfloat162float(ui[bbase + (size_t)((tg) + i) * NFf]);  \
    }                                                                     \
  }

#define RES_STEP(buf_r, buf_i, tg)                                      \
  {                                                                      \
    const bool wr_ = (tg) >= cstart;                                     \
    _Pragma("unroll") for (int i = 0; i < RES_P; ++i) {                  \
      const float pr = fmaf(ar, Xr, fmaf(-ai, Xi, buf_r[i]));            \
      const float pim = fmaf(ar, Xi, fmaf(ai, Xr, buf_i[i]));            \
      const float mag = __builtin_amdgcn_sqrtf(fmaf(pr, pr, pim * pim)); \
      const float g = __builtin_amdgcn_rcpf(1.f + __expf(th - mag));     \
      Xr = pr * g;                                                       \
      Xi = pim * g;                                                      \
      if (wr_) {                                                         \
        const size_t fb = ((size_t)b * Tt + (tg) + i) * (3 * NFf);       \
        featb[fb + f] = __float2bfloat16(Xr);                            \
        featb[fb + NFf + f] = __float2bfloat16(Xi);                      \
        featb[fb + 2 * NFf + f] = __float2bfloat16(mag * g);             \
      }                                                                  \
    }                                                                    \
  }

struct STDesc {
  const float* src[6];
  __hip_bfloat16* dst[6];
  const __hip_bfloat16* ur;
  const __hip_bfloat16* ui;
  const float* omega;
  const float* ret_logit;
  const float* theta;
  __hip_bfloat16* featb;
};

__global__ __launch_bounds__(256) void scan_and_tc(STDesc d) {
  __shared__ float tile[32][33];
  const int bid = blockIdx.x;
  if (bid < 64) {
    if (threadIdx.x >= 64) return;  // scan uses 64 lanes; no barriers below
    const int tc = bid & 7;
    const int fs = (bid >> 3) & 3;
    const int b = bid >> 5;
    const int f = fs * 64 + threadIdx.x;
    const int cstart = tc * RES_TC;
    const int cend = cstart + RES_TC;
    const int tbeg = (cstart >= RES_W) ? cstart - RES_W : 0;
    const __hip_bfloat16* ur = d.ur;
    const __hip_bfloat16* ui = d.ui;
    __hip_bfloat16* featb = d.featb;
    const float dec = 1.f / (1.f + __expf(-d.ret_logit[f]));
    float so, co;
    sincosf(d.omega[f], &so, &co);
    const float ar = dec * co, ai = dec * so;
    const float th = d.theta[f];
    const size_t bbase = (size_t)b * Tt * NFf + f;
    float Xr = 0.f, Xi = 0.f;
    float Ar[RES_P], Ai[RES_P], Br[RES_P], Bi[RES_P];
    RES_LOAD(Ar, Ai, tbeg);
    for (int t0 = tbeg; t0 < cend; t0 += 2 * RES_P) {
      RES_LOAD(Br, Bi, t0 + RES_P);
      RES_STEP(Ar, Ai, t0);
      RES_LOAD(Ar, Ai, t0 + 2 * RES_P);
      RES_STEP(Br, Bi, t0 + RES_P);
    }
    return;
  }
  // transpose-cast region: W_feat, Wq, Wk, Wv, W1, W2
  constexpr int KS[6] = {768, 1024, 1024, 1024, 1024, 4096};
  constexpr int NS[6] = {1024, 1024, 1024, 1024, 4096, 1024};
  constexpr int CUM[7] = {0, 768, 1792, 2816, 3840, 7936, 12032};
  const int t = bid - 64;
  int w = 0;
#pragma unroll
  for (int i = 0; i < 6; ++i)
    if (t >= CUM[i + 1]) w = i + 1;
  tc_tile(tile, d.src[w], d.dst[w], KS[w], NS[w], t - CUM[w]);
}

// ---------------------------------------------------------------------------
// Attention phase A: per-chunk KV outer-product sums and k-sums (bf16 qkv).
// ---------------------------------------------------------------------------
__global__ __launch_bounds__(256) void attn_chunk_kv(const __hip_bfloat16* __restrict__ k,
                                                     const __hip_bfloat16* __restrict__ v,
                                                     float* __restrict__ S,
                                                     float* __restrict__ Ksum) {
  __shared__ float Ks[64][68], Vs[64][68];
  const int g = blockIdx.x;
  const int j = g & (NCHK - 1), bh = g >> 4;
  const int b = bh >> 4, h = bh & (Hh - 1);
  const int tid = threadIdx.x;
  const size_t rowbase = (size_t)(b * Tt + j * CHK) * QS + h * DHh;
  const unsigned short* ku = (const unsigned short*)k;
  const unsigned short* vu = (const unsigned short*)v;
  for (int l = tid; l < 4096; l += 256) {
    const int s = l >> 6, d = l & 63;
    Ks[s][d] = bf2f(ku[rowbase + (size_t)s * QS + d]);
    Vs[s][d] = bf2f(vu[rowbase + (size_t)s * QS + d]);
  }
  __syncthreads();
  const int d0 = tid & 63, eb = tid >> 6, e0 = eb * 16;
  float4 acc4[4] = {};
  float ks = 0.f;
  for (int s = 0; s < 64; ++s) {
    const float kd = Ks[s][d0];
    ks += kd;
#pragma unroll
    for (int i = 0; i < 4; ++i) {
      const float4 v4 = *(const float4*)&Vs[s][e0 + 4 * i];
      acc4[i].x = fmaf(kd, v4.x, acc4[i].x);
      acc4[i].y = fmaf(kd, v4.y, acc4[i].y);
      acc4[i].z = fmaf(kd, v4.z, acc4[i].z);
      acc4[i].w = fmaf(kd, v4.w, acc4[i].w);
    }
  }
  float* Sg = S + (size_t)g * 4096 + (size_t)d0 * 64 + e0;
#pragma unroll
  for (int i = 0; i < 4; ++i) *(float4*)&Sg[4 * i] = acc4[i];
  if (eb == 0) Ksum[(size_t)g * 64 + d0] = ks;
}

// ---------------------------------------------------------------------------
// Attention phase B: EXCLUSIVE prefix over the 16 chunks per (b,h).
// FULLY PARALLEL (r10): one thread per chain, prefetch all 16 values
// (independent addresses -> one latency), prefix in registers, store.
// ---------------------------------------------------------------------------
__global__ __launch_bounds__(256) void attn_prefix(float* __restrict__ S,
                                                   float* __restrict__ Ksum) {
  const int bid = blockIdx.x;
  const int tid = threadIdx.x;
  if (bid < 512) {
    const int bh = bid >> 4, r = bid & 15;
    const int de = r * 256 + tid;
    const size_t base = (size_t)bh * (NCHK * 4096) + de;
    float vv[NCHK];
#pragma unroll
    for (int j = 0; j < NCHK; ++j) vv[j] = S[base + (size_t)j * 4096];
    float run = 0.f;
#pragma unroll
    for (int j = 0; j < NCHK; ++j) {
      const float tmp = vv[j];
      S[base + (size_t)j * 4096] = run;
      run += tmp;
    }
  } else {
    const int cid = (bid - 512) * 256 + tid;  // [0, 2048)
    const int bh = cid >> 6, d = cid & 63;
    const size_t base = (size_t)bh * (NCHK * 64) + d;
    float vv[NCHK];
#pragma unroll
    for (int j = 0; j < NCHK; ++j) vv[j] = Ksum[base + (size_t)j * 64];
    float run = 0.f;
#pragma unroll
    for (int j = 0; j < NCHK; ++j) {
      const float tmp = vv[j];
      Ksum[base + (size_t)j * 64] = run;
      run += tmp;
    }
  }
}

// ---------------------------------------------------------------------------
// Attention phase C + fused per-head layernorm. bf16 q/k/v (stride QS);
// output yhb bf16 [B*T, 1024]. Row t held by 4 sg-lanes x 16 e; LN stats
// via shfl_xor(1|2).
// ---------------------------------------------------------------------------
__global__ __launch_bounds__(256) void attn_out(const __hip_bfloat16* __restrict__ q,
                                                const __hip_bfloat16* __restrict__ k,
                                                const __hip_bfloat16* __restrict__ v,
                                                const float* __restrict__ S,
                                                const float* __restrict__ Ksum,
                                                const float* __restrict__ lnw,
                                                const float* __restrict__ lnb,
                                                __hip_bfloat16* __restrict__ yhb) {
  __shared__ float Qt[64][65];
  __shared__ float KVP[64][68];
  __shared__ float At[64][65];
  const int g = blockIdx.x;
  const int j = g & (NCHK - 1), bh = g >> 4;
  const int b = bh >> 4, h = bh & (Hh - 1);
  const int tid = threadIdx.x;
  const size_t rowbase = (size_t)(b * Tt + j * CHK) * QS + h * DHh;
  const unsigned short* qu = (const unsigned short*)q;
  const unsigned short* ku = (const unsigned short*)k;
  const unsigned short* vu = (const unsigned short*)v;
  for (int l = tid; l < 4096; l += 256) {
    const int s = l >> 6, d = l & 63;
    Qt[d][s] = bf2f(qu[rowbase + (size_t)s * QS + d]);
    KVP[s][d] = bf2f(ku[rowbase + (size_t)s * QS + d]);
  }
  __syncthreads();
  const int t = tid >> 2, sg = tid & 3;
  const float* pk = Ksum + (size_t)g * 64;
  // --- stage 1: masked scores + denominator ---
  float adot[16] = {};
  float qpk = 0.f;
  for (int c = 0; c < 16; ++c) {
    const float q0 = Qt[4 * c + 0][t], q1 = Qt[4 * c + 1][t];
    const float q2 = Qt[4 * c + 2][t], q3 = Qt[4 * c + 3][t];
    const float4 pk4 = *(const float4*)&pk[4 * c];
    qpk = fmaf(q0, pk4.x, fmaf(q1, pk4.y, fmaf(q2, pk4.z, fmaf(q3, pk4.w, qpk))));
#pragma unroll
    for (int i = 0; i < 16; ++i) {
      const float4 k4 = *(const float4*)&KVP[sg * 16 + i][4 * c];
      adot[i] = fmaf(q0, k4.x, fmaf(q1, k4.y, fmaf(q2, k4.z, fmaf(q3, k4.w, adot[i]))));
    }
  }
  float rs = 0.f;
#pragma unroll
  for (int i = 0; i < 16; ++i) {
    if (sg * 16 + i > t) adot[i] = 0.f;
    rs += adot[i];
  }
  rs += __shfl_xor(rs, 1);
  rs += __shfl_xor(rs, 2);
  const float den = qpk + rs + 1e-6f;
  __syncthreads();  // all K reads complete
#pragma unroll
  for (int i = 0; i < 16; ++i) At[sg * 16 + i][t] = adot[i];
  for (int l = tid; l < 4096; l += 256) {  // overwrite K with V
    const int s = l >> 6, d = l & 63;
    KVP[s][d] = bf2f(vu[rowbase + (size_t)s * QS + d]);
  }
  __syncthreads();
  // --- stage 2a: masked-score @ V ---
  const int e0 = sg * 16;
  float4 num[4] = {};
  for (int s = 0; s <= t; ++s) {
    const float av = At[s][t];
#pragma unroll
    for (int i = 0; i < 4; ++i) {
      const float4 v4 = *(const float4*)&KVP[s][e0 + 4 * i];
      num[i].x = fmaf(av, v4.x, num[i].x);
      num[i].y = fmaf(av, v4.y, num[i].y);
      num[i].z = fmaf(av, v4.z, num[i].z);
      num[i].w = fmaf(av, v4.w, num[i].w);
    }
  }
  __syncthreads();  // all V reads complete
  const float* Pg = S + (size_t)g * 4096;
  for (int l = tid; l < 4096; l += 256) KVP[l >> 6][l & 63] = Pg[l];
  __syncthreads();
  // --- stage 2b: Q @ P ---
  for (int d = 0; d < 64; ++d) {
    const float qd = Qt[d][t];
#pragma unroll
    for (int i = 0; i < 4; ++i) {
      const float4 p4 = *(const float4*)&KVP[d][e0 + 4 * i];
      num[i].x = fmaf(qd, p4.x, num[i].x);
      num[i].y = fmaf(qd, p4.y, num[i].y);
      num[i].z = fmaf(qd, p4.z, num[i].z);
      num[i].w = fmaf(qd, p4.w, num[i].w);
    }
  }
  const float inv = 1.f / den;
  float o[16];
#pragma unroll
  for (int i = 0; i < 4; ++i) {
    o[4 * i + 0] = num[i].x * inv;
    o[4 * i + 1] = num[i].y * inv;
    o[4 * i + 2] = num[i].z * inv;
    o[4 * i + 3] = num[i].w * inv;
  }
  // --- fused per-head LN over the 64-wide row (4 sg-lanes x 16 e) ---
  float s1 = 0.f, s2 = 0.f;
#pragma unroll
  for (int i = 0; i < 16; ++i) {
    s1 += o[i];
    s2 += o[i] * o[i];
  }
  s1 += __shfl_xor(s1, 1);
  s1 += __shfl_xor(s1, 2);
  s2 += __shfl_xor(s2, 1);
  s2 += __shfl_xor(s2, 2);
  const float mean = s1 * (1.f / 64.f);
  const float var = s2 * (1.f / 64.f) - mean * mean;
  const float rsv = rsqrtf(var + 1e-5f);
  const float* wv = lnw + h * DHh + e0;
  const float* bv = lnb + h * DHh + e0;
  unsigned short ob[16];
#pragma unroll
  for (int i = 0; i < 16; ++i) {
    const float r = (o[i] - mean) * rsv * wv[i] + bv[i];
    __hip_bfloat16 hv = __float2bfloat16(r);
    ob[i] = *(unsigned short*)&hv;
  }
  unsigned short* yg =
      (unsigned short*)yhb + (size_t)(b * Tt + j * CHK + t) * Dd + h * DHh + e0;
#pragma unroll
  for (int i = 0; i < 4; ++i) *(ushort4*)&yg[4 * i] = *(ushort4*)&ob[4 * i];
}

// ---------------------------------------------------------------------------
// Fused FFN2-reduce (4 bf16 split-K partials) + bias + relu + residual +
// final layernorm over D=1024.
// ---------------------------------------------------------------------------
__global__ __launch_bounds__(256) void final_ln(const float* __restrict__ x,
                                                const __hip_bfloat16* __restrict__ part,
                                                const float* __restrict__ b2,
                                                const float* __restrict__ w,
                                                const float* __restrict__ bb,
                                                float* __restrict__ out) {
  __shared__ float r1[4], r2[4];
  const int row = blockIdx.x;
  const int tid = threadIdx.x;
  const size_t off = (size_t)row * Dd + tid * 4;
  const size_t MN = (size_t)Mm * Dd;
  float acc4[4] = {0.f, 0.f, 0.f, 0.f};
#pragma unroll
  for (int z = 0; z < 4; ++z) {
    const ushort4 u = *(const ushort4*)&part[off + (size_t)z * MN];
    acc4[0] += bf2f(u.x);
    acc4[1] += bf2f(u.y);
    acc4[2] += bf2f(u.z);
    acc4[3] += bf2f(u.w);
  }
  const float4 bv = *(const float4*)&b2[tid * 4];
  const float4 xa = *(const float4*)&x[off];
  float z[4];
  z[0] = xa.x + fmaxf(acc4[0] + bv.x, 0.f);
  z[1] = xa.y + fmaxf(acc4[1] + bv.y, 0.f);
  z[2] = xa.z + fmaxf(acc4[2] + bv.z, 0.f);
  z[3] = xa.w + fmaxf(acc4[3] + bv.w, 0.f);
  float s1 = z[0] + z[1] + z[2] + z[3];
  float s2 = z[0] * z[0] + z[1] * z[1] + z[2] * z[2] + z[3] * z[3];
#pragma unroll
  for (int o = 1; o < 64; o <<= 1) {
    s1 += __shfl_xor(s1, o);
    s2 += __shfl_xor(s2, o);
  }
  const int wid = tid >> 6;
  if ((tid & 63) == 0) {
    r1[wid] = s1;
    r2[wid] = s2;
  }
  __syncthreads();
  const float t1 = r1[0] + r1[1] + r1[2] + r1[3];
  const float t2 = r2[0] + r2[1] + r2[2] + r2[3];
  const float mu = t1 * (1.f / Dd);
  const float var = t2 * (1.f / Dd) - mu * mu;
  const float rsv = rsqrtf(var + 1e-5f);
  float4 o4;
  float* op = &o4.x;
#pragma unroll
  for (int jj = 0; jj < 4; ++jj) op[jj] = (z[jj] - mu) * rsv * w[tid * 4 + jj] + bb[tid * 4 + jj];
  *(float4*)&out[off] = o4;
}

// ---------------------------------------------------------------------------
extern "C" void kernel_launch(void* const* d_in, const int* in_sizes, int n_in,
                              void* d_out, int out_size, void* d_ws, size_t ws_size,
                              hipStream_t stream) {
  const float* x = (const float*)d_in[0];
  const float* W_amp = (const float*)d_in[1];
  const float* b_amp = (const float*)d_in[2];
  const float* W_phi = (const float*)d_in[3];
  const float* b_phi = (const float*)d_in[4];
  const float* omega = (const float*)d_in[5];
  const float* ret_logit = (const float*)d_in[6];
  const float* theta = (const float*)d_in[7];
  const float* W_feat = (const float*)d_in[8];
  const float* b_feat = (const float*)d_in[9];
  const float* Wq = (const float*)d_in[10];
  const float* Wk = (const float*)d_in[11];
  const float* Wv = (const float*)d_in[12];
  const float* lnh_w = (const float*)d_in[13];
  const float* lnh_b = (const float*)d_in[14];
  const float* W1 = (const float*)d_in[15];
  const float* b1 = (const float*)d_in[16];
  const float* W2 = (const float*)d_in[17];
  const float* b2 = (const float*)d_in[18];
  const float* ln_w = (const float*)d_in[19];
  const float* ln_b = (const float*)d_in[20];

  // ---- workspace bump allocator (256B aligned); dedicated buffers, ~115 MB
  // of the ~268 MB workspace (fill size observed r8-r11). ----
  char* p = (char*)d_ws;
  auto alloc = [&](size_t bytes) {
    char* r = p;
    p += (bytes + 255) & ~(size_t)255;
    return r;
  };
  __hip_bfloat16* xb = (__hip_bfloat16*)alloc((size_t)Mm * Dd * 2);   // later: featb
  __hip_bfloat16* urh = (__hip_bfloat16*)alloc((size_t)Mm * NFf * 2);
  __hip_bfloat16* uih = (__hip_bfloat16*)alloc((size_t)Mm * NFf * 2);
  __hip_bfloat16* WTamp = (__hip_bfloat16*)alloc((size_t)NFf * Dd * 2);  // +WTphi contiguous
  __hip_bfloat16* WTphi = (__hip_bfloat16*)alloc((size_t)NFf * Dd * 2);
  __hip_bfloat16* WTfeat = (__hip_bfloat16*)alloc((size_t)Dd * 3 * NFf * 2);
  __hip_bfloat16* WTq = (__hip_bfloat16*)alloc((size_t)Dd * Dd * 2);  // +k+v contiguous
  __hip_bfloat16* WTk = (__hip_bfloat16*)alloc((size_t)Dd * Dd * 2);
  __hip_bfloat16* WTv = (__hip_bfloat16*)alloc((size_t)Dd * Dd * 2);
  __hip_bfloat16* WT1 = (__hip_bfloat16*)alloc((size_t)Rr * Dd * 2);
  __hip_bfloat16* WT2 = (__hip_bfloat16*)alloc((size_t)Dd * Rr * 2);
  __hip_bfloat16* hb = (__hip_bfloat16*)alloc((size_t)Mm * Dd * 2);
  __hip_bfloat16* qkvb = (__hip_bfloat16*)alloc((size_t)Mm * QS * 2);  // 12 MB
  __hip_bfloat16* yhb = (__hip_bfloat16*)alloc((size_t)Mm * Dd * 2);   // 4 MB
  float* S = (float*)alloc((size_t)Bb * Hh * NCHK * 4096 * 4);         // 8 MB
  float* Ksum = (float*)alloc((size_t)Bb * Hh * NCHK * 64 * 4);
  __hip_bfloat16* f1b = (__hip_bfloat16*)alloc((size_t)Mm * Rr * 2);   // 16 MB
  __hip_bfloat16* pamp = (__hip_bfloat16*)alloc((size_t)4 * Mm * 512 * 2);   // 8 MB dedicated
  __hip_bfloat16* pffn2 = (__hip_bfloat16*)alloc((size_t)4 * Mm * Dd * 2);   // 16 MB dedicated

  __hip_bfloat16* featb = xb;  // xb dead after ampphi GEMM (stream-ordered)
  const __hip_bfloat16* q = qkvb;
  const __hip_bfloat16* k = qkvb + 1024;
  const __hip_bfloat16* v = qkvb + 2048;
  float* out = (float*)d_out;

  const dim3 blk(256);

  // 0: amp/phi weight transposes + x cast (what the first GEMM needs)
  tc_first<<<dim3(2560), blk, 0, stream>>>(W_amp, W_phi, WTamp, WTphi, x, xb);

  // 1: fused amp/phi projection, split-K=4 (256 blocks, bf16 partials), then
  //    fused reduce + softplus/tanh + polar -> bf16 u
  gemm_mfma<EPI_NONE, 1, 4><<<dim3(512 / 128, Mm / 128, 4), blk, 0, stream>>>(
      (const short*)xb, (const short*)WTamp, nullptr, nullptr, pamp, Mm, 512, Dd);
  reduce_polar<<<dim3(Mm * NFf / 256), blk, 0, stream>>>(pamp, b_amp, b_phi, urh, uih);

  // 2: FUSED resonator scan (64 blocks) || remaining weight transposes
  //    (12032 blocks) — independent work backfills the machine (r11 lesson).
  STDesc st;
  st.src[0] = W_feat; st.dst[0] = WTfeat;
  st.src[1] = Wq; st.dst[1] = WTq;
  st.src[2] = Wk; st.dst[2] = WTk;
  st.src[3] = Wv; st.dst[3] = WTv;
  st.src[4] = W1; st.dst[4] = WT1;
  st.src[5] = W2; st.dst[5] = WT2;
  st.ur = urh; st.ui = uih;
  st.omega = omega; st.ret_logit = ret_logit; st.theta = theta;
  st.featb = featb;
  scan_and_tc<<<dim3(64 + 12032), blk, 0, stream>>>(st);

  // 3: feat projection -> h (bf16)
  gemm_mfma<EPI_RELU, 1, 0><<<dim3(Dd / 128, Mm / 128), blk, 0, stream>>>(
      (const short*)featb, (const short*)WTfeat, b_feat, nullptr, hb, Mm, Dd, 3 * NFf);

  // 4: fused q,k,v projection -> bf16 qkvb (384 blocks, 1.5 blocks/CU)
  gemm_mfma<EPI_QKV, 1, 0><<<dim3(QS / 128, Mm / 128), blk, 0, stream>>>(
      (const short*)hb, (const short*)WTq, nullptr, nullptr, qkvb, Mm, QS, Dd);

  // 5: chunked causal linear attention (+ fused per-head LN in attn_out)
  attn_chunk_kv<<<dim3(Bb * Hh * NCHK), blk, 0, stream>>>(k, v, S, Ksum);
  attn_prefix<<<dim3(520), blk, 0, stream>>>(S, Ksum);
  attn_out<<<dim3(Bb * Hh * NCHK), blk, 0, stream>>>(q, k, v, S, Ksum, lnh_w, lnh_b, yhb);

  // 6: FFN1 -> f1b (bf16); 512 blocks = 2 blocks/CU (LDS-capped max)
  gemm_mfma<EPI_RELU, 1, 0><<<dim3(Rr / 128, Mm / 128), blk, 0, stream>>>(
      (const short*)yhb, (const short*)WT1, b1, nullptr, f1b, Mm, Rr, Dd);

  // 7: FFN2 split-K=4, bf16 partials -> pffn2; 512 blocks = 2 blocks/CU
  gemm_mfma<EPI_NONE, 1, 4><<<dim3(Dd / 128, Mm / 128, 4), blk, 0, stream>>>(
      (const short*)f1b, (const short*)WT2, nullptr, nullptr, pffn2, Mm, Dd, Rr);

  // 8: fused reduce(4x bf16) + bias + relu + residual + final layernorm
  final_ln<<<dim3(Mm), blk, 0, stream>>>(x, pffn2, b2, ln_w, ln_b, out);
}

// Round 14
// 174.443 us; speedup vs baseline: 1.3453x; 1.0718x over previous
//
#include <hip/hip_runtime.h>
#include <hip/hip_bf16.h>
#include <math.h>

#ifndef M_PI_F
#define M_PI_F 3.14159265358979323846f
#endif

static constexpr int Bb = 2, Tt = 1024, Dd = 1024, Hh = 16, DHh = 64, NFf = 256, Rr = 4096;
static constexpr int Mm = Bb * Tt;
static constexpr int CHK = 64, NCHK = Tt / CHK;  // attention chunking
static constexpr int QS = 3072;                  // fused qkv row stride

enum Epi { EPI_NONE = 0, EPI_RELU, EPI_QKV };

typedef __attribute__((ext_vector_type(8))) short bf16x8;
typedef __attribute__((ext_vector_type(4))) float f32x4;

__device__ inline float bf2f(unsigned short u) {
  union { unsigned int i; float f; } c;
  c.i = (unsigned int)u << 16;
  return c.f;
}

// ---------------------------------------------------------------------------
// async global->LDS, 16B per lane. LDS dest is wave-uniform base; HW adds
// lane*16. Global address is per-lane.
// ---------------------------------------------------------------------------
__device__ inline void gload16(const short* g, short* l) {
  __builtin_amdgcn_global_load_lds(
      (const __attribute__((address_space(1))) unsigned int*)g,
      (__attribute__((address_space(3))) unsigned int*)l, 16, 0, 0);
}

// ---------------------------------------------------------------------------
// bf16 MFMA GEMM: C[M,N] = epi(A[M,K] @ BT[N,K]^T + bias)
// 128x128 tile, BK=64, 4 waves (2x2), each 64x64 via 4x4 frags of 16x16x32.
// - Double-buffered K-loop, counted vmcnt (r7). r9/r10 lesson: >=2 blocks/CU
//   co-residency (m114) is the stall-hiding lever, not pipeline depth; with
//   64KB LDS the cap is 2 blocks/CU, so grids beyond 512 blocks buy nothing.
// - LDS XOR bank-swizzle (rule #21 both-sides involution).
// - Bijective XCD swizzle (m204) for A-panel L2 reuse per XCD.
// - SPLITK: blockIdx.z selects K-slice, writes partial (fp32 Cf / bf16 Cb)
//   at +z*M*N. Partials live in DEDICATED buffers (r4 overlay race lesson).
// ---------------------------------------------------------------------------
#define GSTAGE(bufsel, kk0)                                           \
  _Pragma("unroll") for (int si = 0; si < 4; ++si) {                  \
    const int s = wid + si * 4;                                       \
    gload16(A + (size_t)(m0 + s * 8 + srow) * ldk + (kk0) + skk,      \
            &lA[(bufsel) * 8192 + s * 512]);                          \
    gload16(BT + (size_t)(n0 + s * 8 + srow) * ldk + (kk0) + skk,     \
            &lB[(bufsel) * 8192 + s * 512]);                          \
  }

template <int EPI, int OUTBF, int SPLITK>
__global__ __launch_bounds__(256) void gemm_mfma(const short* __restrict__ A,
                                                 const short* __restrict__ BT,
                                                 const float* __restrict__ bias,
                                                 float* __restrict__ Cf,
                                                 __hip_bfloat16* __restrict__ Cb,
                                                 int M, int N, int ldk) {
  __shared__ short lA[2 * 128 * 64];
  __shared__ short lB[2 * 128 * 64];
  const int tid = threadIdx.x;
  const int wid = tid >> 6, lane = tid & 63;

  // XCD-aware bijective block swizzle (grids here always have nwg % 8 == 0)
  const int nwg = gridDim.x * gridDim.y;
  const int wg = blockIdx.y * gridDim.x + blockIdx.x;
  const int qq = nwg >> 3, rr = nwg & 7;
  const int xcd = wg & 7, idx = wg >> 3;
  const int wg2 = (xcd < rr ? xcd * (qq + 1) : rr * (qq + 1) + (xcd - rr) * qq) + idx;
  const int bx = wg2 % gridDim.x, by = wg2 / gridDim.x;

  const int m0 = by * 128, n0 = bx * 128;
  const int wm = (wid >> 1) * 64, wn = (wid & 1) * 64;
  const int srow = lane >> 3;                         // row within 8-row slab
  const int skk = (((lane & 7) ^ (lane >> 3)) << 3);  // swizzled k offset (elems)

  int kstart = 0, klen = ldk;
  if (SPLITK > 1) {
    klen = ldk / SPLITK;
    kstart = blockIdx.z * klen;
    if (OUTBF)
      Cb += (size_t)blockIdx.z * M * N;
    else
      Cf += (size_t)blockIdx.z * M * N;
  }
  const int kend = kstart + klen;

  f32x4 acc[4][4] = {};

  GSTAGE(0, kstart);  // prologue: 8 loads/wave in flight
  int cur = 0;
  for (int k0 = kstart; k0 < kend; k0 += 64) {
    if (k0 + 64 < kend) {
      GSTAGE(cur ^ 1, k0 + 64);                         // 16 in flight
      asm volatile("s_waitcnt vmcnt(8)" ::: "memory");  // oldest 8 (cur buf) done
    } else {
      asm volatile("s_waitcnt vmcnt(0)" ::: "memory");
    }
    asm volatile("s_barrier" ::: "memory");
    const short* bA = &lA[cur * 8192];
    const short* bB = &lB[cur * 8192];
#pragma unroll
    for (int kk = 0; kk < 2; ++kk) {
      const int krd = kk * 32 + (lane >> 4) * 8;
      const int rsel = lane & 15;
      const int kswz = krd ^ ((rsel & 7) << 3);  // same involution as store side
      bf16x8 af[4], bfr[4];
#pragma unroll
      for (int i = 0; i < 4; ++i) {
        af[i] = *(const bf16x8*)&bA[(wm + i * 16 + rsel) * 64 + kswz];
        bfr[i] = *(const bf16x8*)&bB[(wn + i * 16 + rsel) * 64 + kswz];
      }
#pragma unroll
      for (int i = 0; i < 4; ++i)
#pragma unroll
        for (int j = 0; j < 4; ++j)
          acc[i][j] = __builtin_amdgcn_mfma_f32_16x16x32_bf16(af[i], bfr[j], acc[i][j], 0, 0, 0);
    }
    // ds_read results are consumed by MFMA (compiler lgkmcnt) before here.
    asm volatile("s_barrier" ::: "memory");  // all waves done reading cur buf
    cur ^= 1;
  }

  const int crow = (lane >> 4) * 4;
  const int ccol = lane & 15;
#pragma unroll
  for (int j = 0; j < 4; ++j) {
    const int col = n0 + wn + j * 16 + ccol;
    const float bv = bias ? bias[col] : 0.f;
#pragma unroll
    for (int i = 0; i < 4; ++i) {
#pragma unroll
      for (int r = 0; r < 4; ++r) {
        float v = acc[i][j][r] + bv;
        const int row = m0 + wm + i * 16 + crow + r;
        if (EPI == EPI_QKV) {
          const float vv = (col < 2048) ? fmaxf(v, 0.f) : v;
          Cb[(size_t)row * QS + col] = __float2bfloat16(vv);
        } else {
          if (EPI == EPI_RELU) v = fmaxf(v, 0.f);
          const size_t off = (size_t)row * N + col;
          if (OUTBF)
            Cb[off] = __float2bfloat16(v);
          else
            Cf[off] = v;
        }
      }
    }
  }
}

// ---------------------------------------------------------------------------
// 32x32 transpose-cast tile helper: W[K,N] f32 -> WT[N,K] bf16.
// ---------------------------------------------------------------------------
__device__ __forceinline__ void tc_tile(float (*tile)[33], const float* __restrict__ W,
                                        __hip_bfloat16* __restrict__ WT, int K, int N,
                                        int tlocal) {
  const int tilesN = N / 32;
  const int bk = (tlocal / tilesN) * 32, bn = (tlocal % tilesN) * 32;
  const int tx = threadIdx.x & 31, ty = threadIdx.x >> 5;  // 32x8
#pragma unroll
  for (int r = 0; r < 32; r += 8) tile[ty + r][tx] = W[(size_t)(bk + ty + r) * N + bn + tx];
  __syncthreads();
#pragma unroll
  for (int r = 0; r < 32; r += 8)
    WT[(size_t)(bn + ty + r) * K + bk + tx] = __float2bfloat16(tile[tx][ty + r]);
}

// ---------------------------------------------------------------------------
// Head kernel: W_amp / W_phi transpose-cast + x f32->bf16 cast.
// ---------------------------------------------------------------------------
__global__ __launch_bounds__(256) void tc_first(const float* __restrict__ W_amp,
                                                const float* __restrict__ W_phi,
                                                __hip_bfloat16* __restrict__ WTamp,
                                                __hip_bfloat16* __restrict__ WTphi,
                                                const float* __restrict__ x,
                                                __hip_bfloat16* __restrict__ xb) {
  __shared__ float tile[32][33];
  const int bid = blockIdx.x;
  if (bid >= 512) {
    const int i = ((bid - 512) * 256 + threadIdx.x) * 4;
    const float4 v = *(const float4*)&x[i];
    xb[i + 0] = __float2bfloat16(v.x);
    xb[i + 1] = __float2bfloat16(v.y);
    xb[i + 2] = __float2bfloat16(v.z);
    xb[i + 3] = __float2bfloat16(v.w);
    return;
  }
  if (bid < 256)
    tc_tile(tile, W_amp, WTamp, 1024, 256, bid);
  else
    tc_tile(tile, W_phi, WTphi, 1024, 256, bid - 256);
}

// ---------------------------------------------------------------------------
// amp/phi split-K reduce (4 bf16 partials) fused with activations and
// polar->cartesian. part layout: [4][M][512] bf16 (cols 0..255 amp, rest phi).
// ---------------------------------------------------------------------------
__global__ __launch_bounds__(256) void reduce_polar(const __hip_bfloat16* __restrict__ part,
                                                    const float* __restrict__ b_amp,
                                                    const float* __restrict__ b_phi,
                                                    __hip_bfloat16* __restrict__ outr,
                                                    __hip_bfloat16* __restrict__ outi) {
  const int idx = blockIdx.x * 256 + threadIdx.x;  // [0, M*NF)
  const int row = idx >> 8, c = idx & 255;
  const size_t MN = (size_t)Mm * 512;
  const size_t pa = (size_t)row * 512 + c;
  const unsigned short* pu = (const unsigned short*)part;
  float a = bf2f(pu[pa]) + bf2f(pu[pa + MN]) + bf2f(pu[pa + 2 * MN]) + bf2f(pu[pa + 3 * MN]) +
            b_amp[c];
  float ph = bf2f(pu[pa + 256]) + bf2f(pu[pa + 256 + MN]) + bf2f(pu[pa + 256 + 2 * MN]) +
             bf2f(pu[pa + 256 + 3 * MN]) + b_phi[c];
  a = (a > 0.f) ? (a + log1pf(expf(-a))) : log1pf(expf(a));
  ph = M_PI_F * tanhf(ph);
  float s, co;
  sincosf(ph, &s, &co);
  outr[idx] = __float2bfloat16(a * co);
  outi[idx] = __float2bfloat16(a * s);
}

// ---------------------------------------------------------------------------
// FUSED: resonator scan (blocks 0..63) || transpose-cast of the 6 remaining
// weights (blocks 64..12095) — independent work backfills the machine (r11).
// Scan: TIME-CHUNK PARALLEL (r6): contraction >= sigmoid(2.0)=0.881/step
// makes a 128-step warm-up from X=0 exact below bf16 quantization.
// ---------------------------------------------------------------------------
static constexpr int RES_P = 16;
static constexpr int RES_TC = 128;  // chunk length
static constexpr int RES_W = 128;   // warm-up length

#define RES_LOAD(buf_r, buf_i, tg)                                        \
  if ((tg) < cend) {                                                      \
    _Pragma("unroll") for (int i = 0; i < RES_P; ++i) {                   \
      buf_r[i] = __bfloat162float(ur[bbase + (size_t)((tg) + i) * NFf]);  \
      buf_i[i] = __bfloat162float(ui[bbase + (size_t)((tg) + i) * NFf]);  \
    }                                                                     \
  }

#define RES_STEP(buf_r, buf_i, tg)                                      \
  {                                                                      \
    const bool wr_ = (tg) >= cstart;                                     \
    _Pragma("unroll") for (int i = 0; i < RES_P; ++i) {                  \
      const float pr = fmaf(ar, Xr, fmaf(-ai, Xi, buf_r[i]));            \
      const float pim = fmaf(ar, Xi, fmaf(ai, Xr, buf_i[i]));            \
      const float mag = __builtin_amdgcn_sqrtf(fmaf(pr, pr, pim * pim)); \
      const float g = __builtin_amdgcn_rcpf(1.f + __expf(th - mag));     \
      Xr = pr * g;                                                       \
      Xi = pim * g;                                                      \
      if (wr_) {                                                         \
        const size_t fb = ((size_t)b * Tt + (tg) + i) * (3 * NFf);       \
        featb[fb + f] = __float2bfloat16(Xr);                            \
        featb[fb + NFf + f] = __float2bfloat16(Xi);                      \
        featb[fb + 2 * NFf + f] = __float2bfloat16(mag * g);             \
      }                                                                  \
    }                                                                    \
  }

struct STDesc {
  const float* src[6];
  __hip_bfloat16* dst[6];
  const __hip_bfloat16* ur;
  const __hip_bfloat16* ui;
  const float* omega;
  const float* ret_logit;
  const float* theta;
  __hip_bfloat16* featb;
};

__global__ __launch_bounds__(256) void scan_and_tc(STDesc d) {
  __shared__ float tile[32][33];
  const int bid = blockIdx.x;
  if (bid < 64) {
    if (threadIdx.x >= 64) return;  // scan uses 64 lanes; no barriers below
    const int tc = bid & 7;
    const int fs = (bid >> 3) & 3;
    const int b = bid >> 5;
    const int f = fs * 64 + threadIdx.x;
    const int cstart = tc * RES_TC;
    const int cend = cstart + RES_TC;
    const int tbeg = (cstart >= RES_W) ? cstart - RES_W : 0;
    const __hip_bfloat16* ur = d.ur;
    const __hip_bfloat16* ui = d.ui;
    __hip_bfloat16* featb = d.featb;
    const float dec = 1.f / (1.f + __expf(-d.ret_logit[f]));
    float so, co;
    sincosf(d.omega[f], &so, &co);
    const float ar = dec * co, ai = dec * so;
    const float th = d.theta[f];
    const size_t bbase = (size_t)b * Tt * NFf + f;
    float Xr = 0.f, Xi = 0.f;
    float Ar[RES_P], Ai[RES_P], Br[RES_P], Bi[RES_P];
    RES_LOAD(Ar, Ai, tbeg);
    for (int t0 = tbeg; t0 < cend; t0 += 2 * RES_P) {
      RES_LOAD(Br, Bi, t0 + RES_P);
      RES_STEP(Ar, Ai, t0);
      RES_LOAD(Ar, Ai, t0 + 2 * RES_P);
      RES_STEP(Br, Bi, t0 + RES_P);
    }
    return;
  }
  // transpose-cast region: W_feat, Wq, Wk, Wv, W1, W2
  constexpr int KS[6] = {768, 1024, 1024, 1024, 1024, 4096};
  constexpr int NS[6] = {1024, 1024, 1024, 1024, 4096, 1024};
  constexpr int CUM[7] = {0, 768, 1792, 2816, 3840, 7936, 12032};
  const int t = bid - 64;
  int w = 0;
#pragma unroll
  for (int i = 0; i < 6; ++i)
    if (t >= CUM[i + 1]) w = i + 1;
  tc_tile(tile, d.src[w], d.dst[w], KS[w], NS[w], t - CUM[w]);
}

// ---------------------------------------------------------------------------
// Attention phase A: per-chunk KV outer-product sums and k-sums (bf16 qkv).
// ---------------------------------------------------------------------------
__global__ __launch_bounds__(256) void attn_chunk_kv(const __hip_bfloat16* __restrict__ k,
                                                     const __hip_bfloat16* __restrict__ v,
                                                     float* __restrict__ S,
                                                     float* __restrict__ Ksum) {
  __shared__ float Ks[64][68], Vs[64][68];
  const int g = blockIdx.x;
  const int j = g & (NCHK - 1), bh = g >> 4;
  const int b = bh >> 4, h = bh & (Hh - 1);
  const int tid = threadIdx.x;
  const size_t rowbase = (size_t)(b * Tt + j * CHK) * QS + h * DHh;
  const unsigned short* ku = (const unsigned short*)k;
  const unsigned short* vu = (const unsigned short*)v;
  for (int l = tid; l < 4096; l += 256) {
    const int s = l >> 6, d = l & 63;
    Ks[s][d] = bf2f(ku[rowbase + (size_t)s * QS + d]);
    Vs[s][d] = bf2f(vu[rowbase + (size_t)s * QS + d]);
  }
  __syncthreads();
  const int d0 = tid & 63, eb = tid >> 6, e0 = eb * 16;
  float4 acc4[4] = {};
  float ks = 0.f;
  for (int s = 0; s < 64; ++s) {
    const float kd = Ks[s][d0];
    ks += kd;
#pragma unroll
    for (int i = 0; i < 4; ++i) {
      const float4 v4 = *(const float4*)&Vs[s][e0 + 4 * i];
      acc4[i].x = fmaf(kd, v4.x, acc4[i].x);
      acc4[i].y = fmaf(kd, v4.y, acc4[i].y);
      acc4[i].z = fmaf(kd, v4.z, acc4[i].z);
      acc4[i].w = fmaf(kd, v4.w, acc4[i].w);
    }
  }
  float* Sg = S + (size_t)g * 4096 + (size_t)d0 * 64 + e0;
#pragma unroll
  for (int i = 0; i < 4; ++i) *(float4*)&Sg[4 * i] = acc4[i];
  if (eb == 0) Ksum[(size_t)g * 64 + d0] = ks;
}

// ---------------------------------------------------------------------------
// Attention phase B: EXCLUSIVE prefix over the 16 chunks per (b,h).
// FULLY PARALLEL (r10): one thread per chain, prefetch all 16 values,
// prefix in registers, store.
// ---------------------------------------------------------------------------
__global__ __launch_bounds__(256) void attn_prefix(float* __restrict__ S,
                                                   float* __restrict__ Ksum) {
  const int bid = blockIdx.x;
  const int tid = threadIdx.x;
  if (bid < 512) {
    const int bh = bid >> 4, r = bid & 15;
    const int de = r * 256 + tid;
    const size_t base = (size_t)bh * (NCHK * 4096) + de;
    float vv[NCHK];
#pragma unroll
    for (int j = 0; j < NCHK; ++j) vv[j] = S[base + (size_t)j * 4096];
    float run = 0.f;
#pragma unroll
    for (int j = 0; j < NCHK; ++j) {
      const float tmp = vv[j];
      S[base + (size_t)j * 4096] = run;
      run += tmp;
    }
  } else {
    const int cid = (bid - 512) * 256 + tid;  // [0, 2048)
    const int bh = cid >> 6, d = cid & 63;
    const size_t base = (size_t)bh * (NCHK * 64) + d;
    float vv[NCHK];
#pragma unroll
    for (int j = 0; j < NCHK; ++j) vv[j] = Ksum[base + (size_t)j * 64];
    float run = 0.f;
#pragma unroll
    for (int j = 0; j < NCHK; ++j) {
      const float tmp = vv[j];
      Ksum[base + (size_t)j * 64] = run;
      run += tmp;
    }
  }
}

// ---------------------------------------------------------------------------
// Attention phase C + fused per-head layernorm.
// LDS layout (r12/r13):
//  - KVP holds K/V/P with XOR BLOCK-SWIZZLE: logical float4-block blk of row
//    s stored at blk ^ ((s>>4)&3). Stage-1's 4-way same-bank reads (rows 16
//    apart, one column, stride 68*16 % 32 == 0) become conflict-free.
//  - READ side: stored position p holds LOGICAL block p^x, so reading
//    address block (i^x) yields logical block i -> accumulate num[i].
//    (r13 bug: accumulated num[i^x] = double-applied XOR -> wrong output.)
//  - Q stored ROW-major [t][68]: stage-1 reads are one ds_read_b128 per c.
// ---------------------------------------------------------------------------
__global__ __launch_bounds__(256) void attn_out(const __hip_bfloat16* __restrict__ q,
                                                const __hip_bfloat16* __restrict__ k,
                                                const __hip_bfloat16* __restrict__ v,
                                                const float* __restrict__ S,
                                                const float* __restrict__ Ksum,
                                                const float* __restrict__ lnw,
                                                const float* __restrict__ lnb,
                                                __hip_bfloat16* __restrict__ yhb) {
  __shared__ float Qs[64][68];
  __shared__ float KVP[64][68];
  __shared__ float At[64][65];
  const int g = blockIdx.x;
  const int j = g & (NCHK - 1), bh = g >> 4;
  const int b = bh >> 4, h = bh & (Hh - 1);
  const int tid = threadIdx.x;
  const size_t rowbase = (size_t)(b * Tt + j * CHK) * QS + h * DHh;
  const unsigned short* qu = (const unsigned short*)q;
  const unsigned short* ku = (const unsigned short*)k;
  const unsigned short* vu = (const unsigned short*)v;
  // swizzled column: logical (s, d) stored at block (d>>2) ^ ((s>>4)&3)
#define KSWZ(s, d) ((((d) >> 2) ^ (((s) >> 4) & 3)) * 4 + ((d) & 3))
  for (int l = tid; l < 4096; l += 256) {
    const int s = l >> 6, d = l & 63;
    Qs[s][d] = bf2f(qu[rowbase + (size_t)s * QS + d]);
    KVP[s][KSWZ(s, d)] = bf2f(ku[rowbase + (size_t)s * QS + d]);
  }
  __syncthreads();
  const int t = tid >> 2, sg = tid & 3;
  const float* pk = Ksum + (size_t)g * 64;
  // --- stage 1: masked scores + denominator ---
  float adot[16] = {};
  float qpk = 0.f;
  for (int c = 0; c < 16; ++c) {
    const float4 q4 = *(const float4*)&Qs[t][4 * c];
    const float4 pk4 = *(const float4*)&pk[4 * c];
    qpk = fmaf(q4.x, pk4.x, fmaf(q4.y, pk4.y, fmaf(q4.z, pk4.z, fmaf(q4.w, pk4.w, qpk))));
#pragma unroll
    for (int i = 0; i < 16; ++i) {
      // logical K[sg*16+i][4c..]; row>>4 == sg -> stored at block c^sg
      const float4 k4 = *(const float4*)&KVP[sg * 16 + i][4 * (c ^ sg)];
      adot[i] = fmaf(q4.x, k4.x, fmaf(q4.y, k4.y, fmaf(q4.z, k4.z, fmaf(q4.w, k4.w, adot[i]))));
    }
  }
  float rs = 0.f;
#pragma unroll
  for (int i = 0; i < 16; ++i) {
    if (sg * 16 + i > t) adot[i] = 0.f;
    rs += adot[i];
  }
  rs += __shfl_xor(rs, 1);
  rs += __shfl_xor(rs, 2);
  const float den = qpk + rs + 1e-6f;
  __syncthreads();  // all K reads complete
#pragma unroll
  for (int i = 0; i < 16; ++i) At[sg * 16 + i][t] = adot[i];
  for (int l = tid; l < 4096; l += 256) {  // overwrite K with V (same swizzle)
    const int s = l >> 6, d = l & 63;
    KVP[s][KSWZ(s, d)] = bf2f(vu[rowbase + (size_t)s * QS + d]);
  }
  __syncthreads();
  // --- stage 2a: masked-score @ V ---
  const int e0 = sg * 16;
  float4 num[4] = {};
  for (int s = 0; s <= t; ++s) {
    const float av = At[s][t];
    const int x = (s >> 4) & 3;
#pragma unroll
    for (int i = 0; i < 4; ++i) {
      // read address block 4sg+(i^x); it stores logical block 4sg+i -> num[i]
      const float4 v4 = *(const float4*)&KVP[s][e0 + 4 * (i ^ x)];
      num[i].x = fmaf(av, v4.x, num[i].x);
      num[i].y = fmaf(av, v4.y, num[i].y);
      num[i].z = fmaf(av, v4.z, num[i].z);
      num[i].w = fmaf(av, v4.w, num[i].w);
    }
  }
  __syncthreads();  // all V reads complete
  const float* Pg = S + (size_t)g * 4096;
  for (int l = tid; l < 4096; l += 256) KVP[l >> 6][KSWZ(l >> 6, l & 63)] = Pg[l];
  __syncthreads();
  // --- stage 2b: Q @ P ---
  for (int d = 0; d < 64; ++d) {
    const float qd = Qs[t][d];
    const int x = (d >> 4) & 3;
#pragma unroll
    for (int i = 0; i < 4; ++i) {
      // same logic: address block 4sg+(i^x) holds logical block 4sg+i
      const float4 p4 = *(const float4*)&KVP[d][e0 + 4 * (i ^ x)];
      num[i].x = fmaf(qd, p4.x, num[i].x);
      num[i].y = fmaf(qd, p4.y, num[i].y);
      num[i].z = fmaf(qd, p4.z, num[i].z);
      num[i].w = fmaf(qd, p4.w, num[i].w);
    }
  }
#undef KSWZ
  const float inv = 1.f / den;
  float o[16];
#pragma unroll
  for (int i = 0; i < 4; ++i) {
    o[4 * i + 0] = num[i].x * inv;
    o[4 * i + 1] = num[i].y * inv;
    o[4 * i + 2] = num[i].z * inv;
    o[4 * i + 3] = num[i].w * inv;
  }
  // --- fused per-head LN over the 64-wide row (4 sg-lanes x 16 e) ---
  float s1 = 0.f, s2 = 0.f;
#pragma unroll
  for (int i = 0; i < 16; ++i) {
    s1 += o[i];
    s2 += o[i] * o[i];
  }
  s1 += __shfl_xor(s1, 1);
  s1 += __shfl_xor(s1, 2);
  s2 += __shfl_xor(s2, 1);
  s2 += __shfl_xor(s2, 2);
  const float mean = s1 * (1.f / 64.f);
  const float var = s2 * (1.f / 64.f) - mean * mean;
  const float rsv = rsqrtf(var + 1e-5f);
  const float* wv = lnw + h * DHh + e0;
  const float* bv = lnb + h * DHh + e0;
  unsigned short ob[16];
#pragma unroll
  for (int i = 0; i < 16; ++i) {
    const float r = (o[i] - mean) * rsv * wv[i] + bv[i];
    __hip_bfloat16 hv = __float2bfloat16(r);
    ob[i] = *(unsigned short*)&hv;
  }
  unsigned short* yg =
      (unsigned short*)yhb + (size_t)(b * Tt + j * CHK + t) * Dd + h * DHh + e0;
#pragma unroll
  for (int i = 0; i < 4; ++i) *(ushort4*)&yg[4 * i] = *(ushort4*)&ob[4 * i];
}

// ---------------------------------------------------------------------------
// Fused FFN2-reduce (4 bf16 split-K partials) + bias + relu + residual +
// final layernorm over D=1024.
// ---------------------------------------------------------------------------
__global__ __launch_bounds__(256) void final_ln(const float* __restrict__ x,
                                                const __hip_bfloat16* __restrict__ part,
                                                const float* __restrict__ b2,
                                                const float* __restrict__ w,
                                                const float* __restrict__ bb,
                                                float* __restrict__ out) {
  __shared__ float r1[4], r2[4];
  const int row = blockIdx.x;
  const int tid = threadIdx.x;
  const size_t off = (size_t)row * Dd + tid * 4;
  const size_t MN = (size_t)Mm * Dd;
  float acc4[4] = {0.f, 0.f, 0.f, 0.f};
#pragma unroll
  for (int z = 0; z < 4; ++z) {
    const ushort4 u = *(const ushort4*)&part[off + (size_t)z * MN];
    acc4[0] += bf2f(u.x);
    acc4[1] += bf2f(u.y);
    acc4[2] += bf2f(u.z);
    acc4[3] += bf2f(u.w);
  }
  const float4 bv = *(const float4*)&b2[tid * 4];
  const float4 xa = *(const float4*)&x[off];
  float z[4];
  z[0] = xa.x + fmaxf(acc4[0] + bv.x, 0.f);
  z[1] = xa.y + fmaxf(acc4[1] + bv.y, 0.f);
  z[2] = xa.z + fmaxf(acc4[2] + bv.z, 0.f);
  z[3] = xa.w + fmaxf(acc4[3] + bv.w, 0.f);
  float s1 = z[0] + z[1] + z[2] + z[3];
  float s2 = z[0] * z[0] + z[1] * z[1] + z[2] * z[2] + z[3] * z[3];
#pragma unroll
  for (int o = 1; o < 64; o <<= 1) {
    s1 += __shfl_xor(s1, o);
    s2 += __shfl_xor(s2, o);
  }
  const int wid = tid >> 6;
  if ((tid & 63) == 0) {
    r1[wid] = s1;
    r2[wid] = s2;
  }
  __syncthreads();
  const float t1 = r1[0] + r1[1] + r1[2] + r1[3];
  const float t2 = r2[0] + r2[1] + r2[2] + r2[3];
  const float mu = t1 * (1.f / Dd);
  const float var = t2 * (1.f / Dd) - mu * mu;
  const float rsv = rsqrtf(var + 1e-5f);
  float4 o4;
  float* op = &o4.x;
#pragma unroll
  for (int jj = 0; jj < 4; ++jj) op[jj] = (z[jj] - mu) * rsv * w[tid * 4 + jj] + bb[tid * 4 + jj];
  *(float4*)&out[off] = o4;
}

// ---------------------------------------------------------------------------
extern "C" void kernel_launch(void* const* d_in, const int* in_sizes, int n_in,
                              void* d_out, int out_size, void* d_ws, size_t ws_size,
                              hipStream_t stream) {
  const float* x = (const float*)d_in[0];
  const float* W_amp = (const float*)d_in[1];
  const float* b_amp = (const float*)d_in[2];
  const float* W_phi = (const float*)d_in[3];
  const float* b_phi = (const float*)d_in[4];
  const float* omega = (const float*)d_in[5];
  const float* ret_logit = (const float*)d_in[6];
  const float* theta = (const float*)d_in[7];
  const float* W_feat = (const float*)d_in[8];
  const float* b_feat = (const float*)d_in[9];
  const float* Wq = (const float*)d_in[10];
  const float* Wk = (const float*)d_in[11];
  const float* Wv = (const float*)d_in[12];
  const float* lnh_w = (const float*)d_in[13];
  const float* lnh_b = (const float*)d_in[14];
  const float* W1 = (const float*)d_in[15];
  const float* b1 = (const float*)d_in[16];
  const float* W2 = (const float*)d_in[17];
  const float* b2 = (const float*)d_in[18];
  const float* ln_w = (const float*)d_in[19];
  const float* ln_b = (const float*)d_in[20];

  // ---- workspace bump allocator (256B aligned); dedicated buffers ----
  char* p = (char*)d_ws;
  auto alloc = [&](size_t bytes) {
    char* r = p;
    p += (bytes + 255) & ~(size_t)255;
    return r;
  };
  __hip_bfloat16* xb = (__hip_bfloat16*)alloc((size_t)Mm * Dd * 2);   // later: featb
  __hip_bfloat16* urh = (__hip_bfloat16*)alloc((size_t)Mm * NFf * 2);
  __hip_bfloat16* uih = (__hip_bfloat16*)alloc((size_t)Mm * NFf * 2);
  __hip_bfloat16* WTamp = (__hip_bfloat16*)alloc((size_t)NFf * Dd * 2);  // +WTphi contiguous
  __hip_bfloat16* WTphi = (__hip_bfloat16*)alloc((size_t)NFf * Dd * 2);
  __hip_bfloat16* WTfeat = (__hip_bfloat16*)alloc((size_t)Dd * 3 * NFf * 2);
  __hip_bfloat16* WTq = (__hip_bfloat16*)alloc((size_t)Dd * Dd * 2);  // +k+v contiguous
  __hip_bfloat16* WTk = (__hip_bfloat16*)alloc((size_t)Dd * Dd * 2);
  __hip_bfloat16* WTv = (__hip_bfloat16*)alloc((size_t)Dd * Dd * 2);
  __hip_bfloat16* WT1 = (__hip_bfloat16*)alloc((size_t)Rr * Dd * 2);
  __hip_bfloat16* WT2 = (__hip_bfloat16*)alloc((size_t)Dd * Rr * 2);
  __hip_bfloat16* hb = (__hip_bfloat16*)alloc((size_t)Mm * Dd * 2);
  __hip_bfloat16* qkvb = (__hip_bfloat16*)alloc((size_t)Mm * QS * 2);  // 12 MB
  __hip_bfloat16* yhb = (__hip_bfloat16*)alloc((size_t)Mm * Dd * 2);   // 4 MB
  float* S = (float*)alloc((size_t)Bb * Hh * NCHK * 4096 * 4);         // 8 MB
  float* Ksum = (float*)alloc((size_t)Bb * Hh * NCHK * 64 * 4);
  __hip_bfloat16* f1b = (__hip_bfloat16*)alloc((size_t)Mm * Rr * 2);   // 16 MB
  __hip_bfloat16* pamp = (__hip_bfloat16*)alloc((size_t)4 * Mm * 512 * 2);   // 8 MB dedicated
  __hip_bfloat16* pffn2 = (__hip_bfloat16*)alloc((size_t)4 * Mm * Dd * 2);   // 16 MB dedicated

  __hip_bfloat16* featb = xb;  // xb dead after ampphi GEMM (stream-ordered)
  const __hip_bfloat16* q = qkvb;
  const __hip_bfloat16* k = qkvb + 1024;
  const __hip_bfloat16* v = qkvb + 2048;
  float* out = (float*)d_out;

  const dim3 blk(256);

  // 0: amp/phi weight transposes + x cast (what the first GEMM needs)
  tc_first<<<dim3(2560), blk, 0, stream>>>(W_amp, W_phi, WTamp, WTphi, x, xb);

  // 1: fused amp/phi projection, split-K=4 (256 blocks, bf16 partials), then
  //    fused reduce + softplus/tanh + polar -> bf16 u
  gemm_mfma<EPI_NONE, 1, 4><<<dim3(512 / 128, Mm / 128, 4), blk, 0, stream>>>(
      (const short*)xb, (const short*)WTamp, nullptr, nullptr, pamp, Mm, 512, Dd);
  reduce_polar<<<dim3(Mm * NFf / 256), blk, 0, stream>>>(pamp, b_amp, b_phi, urh, uih);

  // 2: FUSED resonator scan (64 blocks) || remaining weight transposes
  STDesc st;
  st.src[0] = W_feat; st.dst[0] = WTfeat;
  st.src[1] = Wq; st.dst[1] = WTq;
  st.src[2] = Wk; st.dst[2] = WTk;
  st.src[3] = Wv; st.dst[3] = WTv;
  st.src[4] = W1; st.dst[4] = WT1;
  st.src[5] = W2; st.dst[5] = WT2;
  st.ur = urh; st.ui = uih;
  st.omega = omega; st.ret_logit = ret_logit; st.theta = theta;
  st.featb = featb;
  scan_and_tc<<<dim3(64 + 12032), blk, 0, stream>>>(st);

  // 3: feat projection -> h (bf16)
  gemm_mfma<EPI_RELU, 1, 0><<<dim3(Dd / 128, Mm / 128), blk, 0, stream>>>(
      (const short*)featb, (const short*)WTfeat, b_feat, nullptr, hb, Mm, Dd, 3 * NFf);

  // 4: fused q,k,v projection -> bf16 qkvb (384 blocks, 1.5 blocks/CU)
  gemm_mfma<EPI_QKV, 1, 0><<<dim3(QS / 128, Mm / 128), blk, 0, stream>>>(
      (const short*)hb, (const short*)WTq, nullptr, nullptr, qkvb, Mm, QS, Dd);

  // 5: chunked causal linear attention (+ fused per-head LN in attn_out)
  attn_chunk_kv<<<dim3(Bb * Hh * NCHK), blk, 0, stream>>>(k, v, S, Ksum);
  attn_prefix<<<dim3(520), blk, 0, stream>>>(S, Ksum);
  attn_out<<<dim3(Bb * Hh * NCHK), blk, 0, stream>>>(q, k, v, S, Ksum, lnh_w, lnh_b, yhb);

  // 6: FFN1 -> f1b (bf16); 512 blocks = 2 blocks/CU (LDS-capped max)
  gemm_mfma<EPI_RELU, 1, 0><<<dim3(Rr / 128, Mm / 128), blk, 0, stream>>>(
      (const short*)yhb, (const short*)WT1, b1, nullptr, f1b, Mm, Rr, Dd);

  // 7: FFN2 split-K=4, bf16 partials -> pffn2; 512 blocks = 2 blocks/CU
  gemm_mfma<EPI_NONE, 1, 4><<<dim3(Dd / 128, Mm / 128, 4), blk, 0, stream>>>(
      (const short*)f1b, (const short*)WT2, nullptr, nullptr, pffn2, Mm, Dd, Rr);

  // 8: fused reduce(4x bf16) + bias + relu + residual + final layernorm
  final_ln<<<dim3(Mm), blk, 0, stream>>>(x, pffn2, b2, ln_w, ln_b, out);
}

// Round 15
// 171.398 us; speedup vs baseline: 1.3692x; 1.0178x over previous
//
#include <hip/hip_runtime.h>
#include <hip/hip_bf16.h>
#include <math.h>

#ifndef M_PI_F
#define M_PI_F 3.14159265358979323846f
#endif

static constexpr int Bb = 2, Tt = 1024, Dd = 1024, Hh = 16, DHh = 64, NFf = 256, Rr = 4096;
static constexpr int Mm = Bb * Tt;
static constexpr int CHK = 64, NCHK = Tt / CHK;  // attention chunking
static constexpr int QS = 3072;                  // fused qkv row stride

enum Epi { EPI_NONE = 0, EPI_RELU, EPI_QKV };

typedef __attribute__((ext_vector_type(8))) short bf16x8;
typedef __attribute__((ext_vector_type(4))) float f32x4;

__device__ inline float bf2f(unsigned short u) {
  union { unsigned int i; float f; } c;
  c.i = (unsigned int)u << 16;
  return c.f;
}

// ---------------------------------------------------------------------------
// async global->LDS, 16B per lane. LDS dest is wave-uniform base; HW adds
// lane*16. Global address is per-lane.
// ---------------------------------------------------------------------------
__device__ inline void gload16(const short* g, short* l) {
  __builtin_amdgcn_global_load_lds(
      (const __attribute__((address_space(1))) unsigned int*)g,
      (__attribute__((address_space(3))) unsigned int*)l, 16, 0, 0);
}

// ---------------------------------------------------------------------------
// bf16 MFMA GEMM: C[M,N] = epi(A[M,K] @ BT[N,K]^T + bias)
// 128x128 tile, BK=64, 4 waves (2x2), each 64x64 via 4x4 frags of 16x16x32.
// - Double-buffered K-loop, counted vmcnt (r7). r9/r10 lesson: >=2 blocks/CU
//   co-residency (m114) is the stall-hiding lever, not pipeline depth; with
//   64KB LDS the cap is 2 blocks/CU, so grids beyond 512 blocks buy nothing.
// - LDS XOR bank-swizzle (rule #21 both-sides involution).
// - Bijective XCD swizzle (m204) for A-panel L2 reuse per XCD.
// - SPLITK: blockIdx.z selects K-slice, writes partial (fp32 Cf / bf16 Cb)
//   at +z*M*N. Partials live in DEDICATED buffers (r4 overlay race lesson).
// ---------------------------------------------------------------------------
#define GSTAGE(bufsel, kk0)                                           \
  _Pragma("unroll") for (int si = 0; si < 4; ++si) {                  \
    const int s = wid + si * 4;                                       \
    gload16(A + (size_t)(m0 + s * 8 + srow) * ldk + (kk0) + skk,      \
            &lA[(bufsel) * 8192 + s * 512]);                          \
    gload16(BT + (size_t)(n0 + s * 8 + srow) * ldk + (kk0) + skk,     \
            &lB[(bufsel) * 8192 + s * 512]);                          \
  }

template <int EPI, int OUTBF, int SPLITK>
__global__ __launch_bounds__(256) void gemm_mfma(const short* __restrict__ A,
                                                 const short* __restrict__ BT,
                                                 const float* __restrict__ bias,
                                                 float* __restrict__ Cf,
                                                 __hip_bfloat16* __restrict__ Cb,
                                                 int M, int N, int ldk) {
  __shared__ short lA[2 * 128 * 64];
  __shared__ short lB[2 * 128 * 64];
  const int tid = threadIdx.x;
  const int wid = tid >> 6, lane = tid & 63;

  // XCD-aware bijective block swizzle (grids here always have nwg % 8 == 0)
  const int nwg = gridDim.x * gridDim.y;
  const int wg = blockIdx.y * gridDim.x + blockIdx.x;
  const int qq = nwg >> 3, rr = nwg & 7;
  const int xcd = wg & 7, idx = wg >> 3;
  const int wg2 = (xcd < rr ? xcd * (qq + 1) : rr * (qq + 1) + (xcd - rr) * qq) + idx;
  const int bx = wg2 % gridDim.x, by = wg2 / gridDim.x;

  const int m0 = by * 128, n0 = bx * 128;
  const int wm = (wid >> 1) * 64, wn = (wid & 1) * 64;
  const int srow = lane >> 3;                         // row within 8-row slab
  const int skk = (((lane & 7) ^ (lane >> 3)) << 3);  // swizzled k offset (elems)

  int kstart = 0, klen = ldk;
  if (SPLITK > 1) {
    klen = ldk / SPLITK;
    kstart = blockIdx.z * klen;
    if (OUTBF)
      Cb += (size_t)blockIdx.z * M * N;
    else
      Cf += (size_t)blockIdx.z * M * N;
  }
  const int kend = kstart + klen;

  f32x4 acc[4][4] = {};

  GSTAGE(0, kstart);  // prologue: 8 loads/wave in flight
  int cur = 0;
  for (int k0 = kstart; k0 < kend; k0 += 64) {
    if (k0 + 64 < kend) {
      GSTAGE(cur ^ 1, k0 + 64);                         // 16 in flight
      asm volatile("s_waitcnt vmcnt(8)" ::: "memory");  // oldest 8 (cur buf) done
    } else {
      asm volatile("s_waitcnt vmcnt(0)" ::: "memory");
    }
    asm volatile("s_barrier" ::: "memory");
    const short* bA = &lA[cur * 8192];
    const short* bB = &lB[cur * 8192];
#pragma unroll
    for (int kk = 0; kk < 2; ++kk) {
      const int krd = kk * 32 + (lane >> 4) * 8;
      const int rsel = lane & 15;
      const int kswz = krd ^ ((rsel & 7) << 3);  // same involution as store side
      bf16x8 af[4], bfr[4];
#pragma unroll
      for (int i = 0; i < 4; ++i) {
        af[i] = *(const bf16x8*)&bA[(wm + i * 16 + rsel) * 64 + kswz];
        bfr[i] = *(const bf16x8*)&bB[(wn + i * 16 + rsel) * 64 + kswz];
      }
#pragma unroll
      for (int i = 0; i < 4; ++i)
#pragma unroll
        for (int j = 0; j < 4; ++j)
          acc[i][j] = __builtin_amdgcn_mfma_f32_16x16x32_bf16(af[i], bfr[j], acc[i][j], 0, 0, 0);
    }
    // ds_read results are consumed by MFMA (compiler lgkmcnt) before here.
    asm volatile("s_barrier" ::: "memory");  // all waves done reading cur buf
    cur ^= 1;
  }

  const int crow = (lane >> 4) * 4;
  const int ccol = lane & 15;
#pragma unroll
  for (int j = 0; j < 4; ++j) {
    const int col = n0 + wn + j * 16 + ccol;
    const float bv = bias ? bias[col] : 0.f;
#pragma unroll
    for (int i = 0; i < 4; ++i) {
#pragma unroll
      for (int r = 0; r < 4; ++r) {
        float v = acc[i][j][r] + bv;
        const int row = m0 + wm + i * 16 + crow + r;
        if (EPI == EPI_QKV) {
          const float vv = (col < 2048) ? fmaxf(v, 0.f) : v;
          Cb[(size_t)row * QS + col] = __float2bfloat16(vv);
        } else {
          if (EPI == EPI_RELU) v = fmaxf(v, 0.f);
          const size_t off = (size_t)row * N + col;
          if (OUTBF)
            Cb[off] = __float2bfloat16(v);
          else
            Cf[off] = v;
        }
      }
    }
  }
}

// ---------------------------------------------------------------------------
// 32x32 transpose-cast tile helper: W[K,N] f32 -> WT[N,K] bf16.
// ---------------------------------------------------------------------------
__device__ __forceinline__ void tc_tile(float (*tile)[33], const float* __restrict__ W,
                                        __hip_bfloat16* __restrict__ WT, int K, int N,
                                        int tlocal) {
  const int tilesN = N / 32;
  const int bk = (tlocal / tilesN) * 32, bn = (tlocal % tilesN) * 32;
  const int tx = threadIdx.x & 31, ty = threadIdx.x >> 5;  // 32x8
#pragma unroll
  for (int r = 0; r < 32; r += 8) tile[ty + r][tx] = W[(size_t)(bk + ty + r) * N + bn + tx];
  __syncthreads();
#pragma unroll
  for (int r = 0; r < 32; r += 8)
    WT[(size_t)(bn + ty + r) * K + bk + tx] = __float2bfloat16(tile[tx][ty + r]);
}

// ---------------------------------------------------------------------------
// Head kernel: W_amp / W_phi transpose-cast + x f32->bf16 cast.
// ---------------------------------------------------------------------------
__global__ __launch_bounds__(256) void tc_first(const float* __restrict__ W_amp,
                                                const float* __restrict__ W_phi,
                                                __hip_bfloat16* __restrict__ WTamp,
                                                __hip_bfloat16* __restrict__ WTphi,
                                                const float* __restrict__ x,
                                                __hip_bfloat16* __restrict__ xb) {
  __shared__ float tile[32][33];
  const int bid = blockIdx.x;
  if (bid >= 512) {
    const int i = ((bid - 512) * 256 + threadIdx.x) * 4;
    const float4 v = *(const float4*)&x[i];
    xb[i + 0] = __float2bfloat16(v.x);
    xb[i + 1] = __float2bfloat16(v.y);
    xb[i + 2] = __float2bfloat16(v.z);
    xb[i + 3] = __float2bfloat16(v.w);
    return;
  }
  if (bid < 256)
    tc_tile(tile, W_amp, WTamp, 1024, 256, bid);
  else
    tc_tile(tile, W_phi, WTphi, 1024, 256, bid - 256);
}

// ---------------------------------------------------------------------------
// amp/phi split-K reduce (4 bf16 partials) fused with activations and
// polar->cartesian. part layout: [4][M][512] bf16 (cols 0..255 amp, rest phi).
// ---------------------------------------------------------------------------
__global__ __launch_bounds__(256) void reduce_polar(const __hip_bfloat16* __restrict__ part,
                                                    const float* __restrict__ b_amp,
                                                    const float* __restrict__ b_phi,
                                                    __hip_bfloat16* __restrict__ outr,
                                                    __hip_bfloat16* __restrict__ outi) {
  const int idx = blockIdx.x * 256 + threadIdx.x;  // [0, M*NF)
  const int row = idx >> 8, c = idx & 255;
  const size_t MN = (size_t)Mm * 512;
  const size_t pa = (size_t)row * 512 + c;
  const unsigned short* pu = (const unsigned short*)part;
  float a = bf2f(pu[pa]) + bf2f(pu[pa + MN]) + bf2f(pu[pa + 2 * MN]) + bf2f(pu[pa + 3 * MN]) +
            b_amp[c];
  float ph = bf2f(pu[pa + 256]) + bf2f(pu[pa + 256 + MN]) + bf2f(pu[pa + 256 + 2 * MN]) +
             bf2f(pu[pa + 256 + 3 * MN]) + b_phi[c];
  a = (a > 0.f) ? (a + log1pf(expf(-a))) : log1pf(expf(a));
  ph = M_PI_F * tanhf(ph);
  float s, co;
  sincosf(ph, &s, &co);
  outr[idx] = __float2bfloat16(a * co);
  outi[idx] = __float2bfloat16(a * s);
}

// ---------------------------------------------------------------------------
// FUSED: resonator scan (blocks 0..63) || transpose-cast of the 6 remaining
// weights (blocks 64..12095) — independent work backfills the machine (r11).
// Scan: TIME-CHUNK PARALLEL (r6): contraction >= sigmoid(2.0)=0.881/step
// makes a 128-step warm-up from X=0 exact below bf16 quantization.
// ---------------------------------------------------------------------------
static constexpr int RES_P = 16;
static constexpr int RES_TC = 128;  // chunk length
static constexpr int RES_W = 128;   // warm-up length

#define RES_LOAD(buf_r, buf_i, tg)                                        \
  if ((tg) < cend) {                                                      \
    _Pragma("unroll") for (int i = 0; i < RES_P; ++i) {                   \
      buf_r[i] = __bfloat162float(ur[bbase + (size_t)((tg) + i) * NFf]);  \
      buf_i[i] = __bfloat162float(ui[bbase + (size_t)((tg) + i) * NFf]);  \
    }                                                                     \
  }

#define RES_STEP(buf_r, buf_i, tg)                                      \
  {                                                                      \
    const bool wr_ = (tg) >= cstart;                                     \
    _Pragma("unroll") for (int i = 0; i < RES_P; ++i) {                  \
      const float pr = fmaf(ar, Xr, fmaf(-ai, Xi, buf_r[i]));            \
      const float pim = fmaf(ar, Xi, fmaf(ai, Xr, buf_i[i]));            \
      const float mag = __builtin_amdgcn_sqrtf(fmaf(pr, pr, pim * pim)); \
      const float g = __builtin_amdgcn_rcpf(1.f + __expf(th - mag));     \
      Xr = pr * g;                                                       \
      Xi = pim * g;                                                      \
      if (wr_) {                                                         \
        const size_t fb = ((size_t)b * Tt + (tg) + i) * (3 * NFf);       \
        featb[fb + f] = __float2bfloat16(Xr);                            \
        featb[fb + NFf + f] = __float2bfloat16(Xi);                      \
        featb[fb + 2 * NFf + f] = __float2bfloat16(mag * g);             \
      }                                                                  \
    }                                                                    \
  }

struct STDesc {
  const float* src[6];
  __hip_bfloat16* dst[6];
  const __hip_bfloat16* ur;
  const __hip_bfloat16* ui;
  const float* omega;
  const float* ret_logit;
  const float* theta;
  __hip_bfloat16* featb;
};

__global__ __launch_bounds__(256) void scan_and_tc(STDesc d) {
  __shared__ float tile[32][33];
  const int bid = blockIdx.x;
  if (bid < 64) {
    if (threadIdx.x >= 64) return;  // scan uses 64 lanes; no barriers below
    const int tc = bid & 7;
    const int fs = (bid >> 3) & 3;
    const int b = bid >> 5;
    const int f = fs * 64 + threadIdx.x;
    const int cstart = tc * RES_TC;
    const int cend = cstart + RES_TC;
    const int tbeg = (cstart >= RES_W) ? cstart - RES_W : 0;
    const __hip_bfloat16* ur = d.ur;
    const __hip_bfloat16* ui = d.ui;
    __hip_bfloat16* featb = d.featb;
    const float dec = 1.f / (1.f + __expf(-d.ret_logit[f]));
    float so, co;
    sincosf(d.omega[f], &so, &co);
    const float ar = dec * co, ai = dec * so;
    const float th = d.theta[f];
    const size_t bbase = (size_t)b * Tt * NFf + f;
    float Xr = 0.f, Xi = 0.f;
    float Ar[RES_P], Ai[RES_P], Br[RES_P], Bi[RES_P];
    RES_LOAD(Ar, Ai, tbeg);
    for (int t0 = tbeg; t0 < cend; t0 += 2 * RES_P) {
      RES_LOAD(Br, Bi, t0 + RES_P);
      RES_STEP(Ar, Ai, t0);
      RES_LOAD(Ar, Ai, t0 + 2 * RES_P);
      RES_STEP(Br, Bi, t0 + RES_P);
    }
    return;
  }
  // transpose-cast region: W_feat, Wq, Wk, Wv, W1, W2
  constexpr int KS[6] = {768, 1024, 1024, 1024, 1024, 4096};
  constexpr int NS[6] = {1024, 1024, 1024, 1024, 4096, 1024};
  constexpr int CUM[7] = {0, 768, 1792, 2816, 3840, 7936, 12032};
  const int t = bid - 64;
  int w = 0;
#pragma unroll
  for (int i = 0; i < 6; ++i)
    if (t >= CUM[i + 1]) w = i + 1;
  tc_tile(tile, d.src[w], d.dst[w], KS[w], NS[w], t - CUM[w]);
}

// ---------------------------------------------------------------------------
// Attention phase A: per-chunk KV outer-product sums (bf16 S out — r14) and
// fp32 k-sums.
// ---------------------------------------------------------------------------
__global__ __launch_bounds__(256) void attn_chunk_kv(const __hip_bfloat16* __restrict__ k,
                                                     const __hip_bfloat16* __restrict__ v,
                                                     __hip_bfloat16* __restrict__ S,
                                                     float* __restrict__ Ksum) {
  __shared__ float Ks[64][68], Vs[64][68];
  const int g = blockIdx.x;
  const int j = g & (NCHK - 1), bh = g >> 4;
  const int b = bh >> 4, h = bh & (Hh - 1);
  const int tid = threadIdx.x;
  const size_t rowbase = (size_t)(b * Tt + j * CHK) * QS + h * DHh;
  const unsigned short* ku = (const unsigned short*)k;
  const unsigned short* vu = (const unsigned short*)v;
  for (int l = tid; l < 4096; l += 256) {
    const int s = l >> 6, d = l & 63;
    Ks[s][d] = bf2f(ku[rowbase + (size_t)s * QS + d]);
    Vs[s][d] = bf2f(vu[rowbase + (size_t)s * QS + d]);
  }
  __syncthreads();
  const int d0 = tid & 63, eb = tid >> 6, e0 = eb * 16;
  float4 acc4[4] = {};
  float ks = 0.f;
  for (int s = 0; s < 64; ++s) {
    const float kd = Ks[s][d0];
    ks += kd;
#pragma unroll
    for (int i = 0; i < 4; ++i) {
      const float4 v4 = *(const float4*)&Vs[s][e0 + 4 * i];
      acc4[i].x = fmaf(kd, v4.x, acc4[i].x);
      acc4[i].y = fmaf(kd, v4.y, acc4[i].y);
      acc4[i].z = fmaf(kd, v4.z, acc4[i].z);
      acc4[i].w = fmaf(kd, v4.w, acc4[i].w);
    }
  }
  unsigned short* Sg = (unsigned short*)S + (size_t)g * 4096 + (size_t)d0 * 64 + e0;
#pragma unroll
  for (int i = 0; i < 4; ++i) {
    ushort4 o;
    __hip_bfloat16 h0 = __float2bfloat16(acc4[i].x);
    __hip_bfloat16 h1 = __float2bfloat16(acc4[i].y);
    __hip_bfloat16 h2 = __float2bfloat16(acc4[i].z);
    __hip_bfloat16 h3 = __float2bfloat16(acc4[i].w);
    o.x = *(unsigned short*)&h0;
    o.y = *(unsigned short*)&h1;
    o.z = *(unsigned short*)&h2;
    o.w = *(unsigned short*)&h3;
    *(ushort4*)&Sg[4 * i] = o;
  }
  if (eb == 0) Ksum[(size_t)g * 64 + d0] = ks;
}

// ---------------------------------------------------------------------------
// Attention phase B: EXCLUSIVE prefix over the 16 chunks per (b,h).
// FULLY PARALLEL (r10): one thread per chain, prefetch all 16 values,
// fp32 running sum, bf16 storage (r14).
// ---------------------------------------------------------------------------
__global__ __launch_bounds__(256) void attn_prefix(__hip_bfloat16* __restrict__ S,
                                                   float* __restrict__ Ksum) {
  const int bid = blockIdx.x;
  const int tid = threadIdx.x;
  if (bid < 512) {
    const int bh = bid >> 4, r = bid & 15;
    const int de = r * 256 + tid;
    unsigned short* Su = (unsigned short*)S;
    const size_t base = (size_t)bh * (NCHK * 4096) + de;
    float vv[NCHK];
#pragma unroll
    for (int j = 0; j < NCHK; ++j) vv[j] = bf2f(Su[base + (size_t)j * 4096]);
    float run = 0.f;
#pragma unroll
    for (int j = 0; j < NCHK; ++j) {
      const float tmp = vv[j];
      __hip_bfloat16 hv = __float2bfloat16(run);
      Su[base + (size_t)j * 4096] = *(unsigned short*)&hv;
      run += tmp;
    }
  } else {
    const int cid = (bid - 512) * 256 + tid;  // [0, 2048)
    const int bh = cid >> 6, d = cid & 63;
    const size_t base = (size_t)bh * (NCHK * 64) + d;
    float vv[NCHK];
#pragma unroll
    for (int j = 0; j < NCHK; ++j) vv[j] = Ksum[base + (size_t)j * 64];
    float run = 0.f;
#pragma unroll
    for (int j = 0; j < NCHK; ++j) {
      const float tmp = vv[j];
      Ksum[base + (size_t)j * 64] = run;
      run += tmp;
    }
  }
}

// ---------------------------------------------------------------------------
// Attention phase C + fused per-head layernorm.
// r14: stage-1 QK^T now via MFMA (16x16x32 bf16) with fragments read DIRECTLY
// from global q/k (same lane convention as gemm_mfma: A-row/B-col = lane&15,
// k = (lane>>4)*8; C: col=lane&15, row=(lane>>4)*4+r). Wave w owns score rows
// [16w,16w+16). Mask + per-wave den partials from C-frags; cross-wave den via
// denp[4][64]. K is never staged to LDS. Same math as the fma version (bf16
// inputs, fp32 accumulate) -> bit-comparable.
// KVP (V, then P) keeps the r12/r13 XOR block-swizzle; Q row-major in LDS.
// ---------------------------------------------------------------------------
__global__ __launch_bounds__(256) void attn_out(const __hip_bfloat16* __restrict__ q,
                                                const __hip_bfloat16* __restrict__ k,
                                                const __hip_bfloat16* __restrict__ v,
                                                const __hip_bfloat16* __restrict__ S,
                                                const float* __restrict__ Ksum,
                                                const float* __restrict__ lnw,
                                                const float* __restrict__ lnb,
                                                __hip_bfloat16* __restrict__ yhb) {
  __shared__ float Qs[64][68];
  __shared__ float KVP[64][68];
  __shared__ float At[64][66];
  __shared__ float denp[4][64];
  const int g = blockIdx.x;
  const int j = g & (NCHK - 1), bh = g >> 4;
  const int b = bh >> 4, h = bh & (Hh - 1);
  const int tid = threadIdx.x;
  const size_t rowbase = (size_t)(b * Tt + j * CHK) * QS + h * DHh;
  const unsigned short* qu = (const unsigned short*)q;
  const unsigned short* ku = (const unsigned short*)k;
  const unsigned short* vu = (const unsigned short*)v;
  // swizzled column: logical (s, d) stored at block (d>>2) ^ ((s>>4)&3)
#define KSWZ(s, d) ((((d) >> 2) ^ (((s) >> 4) & 3)) * 4 + ((d) & 3))
  // entry: stage Q (row-major) and V (swizzled) into LDS
  for (int l = tid; l < 4096; l += 256) {
    const int s = l >> 6, d = l & 63;
    Qs[s][d] = bf2f(qu[rowbase + (size_t)s * QS + d]);
    KVP[s][KSWZ(s, d)] = bf2f(vu[rowbase + (size_t)s * QS + d]);
  }
  // --- stage 1: QK^T via MFMA, fragments direct from global (no LDS dep) ---
  {
    const int w4 = tid >> 6, ln = tid & 63;
    const int fr = ln & 15;  // A-row / B-col within a 16-tile
    const int kh = ln >> 4;  // k-subgroup: elements kh*8..kh*8+7
    const unsigned short* kr = ku + rowbase + (size_t)(w4 * 16 + fr) * QS + kh * 8;
    const bf16x8 a0 = *(const bf16x8*)&kr[0];
    const bf16x8 a1 = *(const bf16x8*)&kr[32];
    f32x4 accQK[4] = {};
#pragma unroll
    for (int tt = 0; tt < 4; ++tt) {
      const unsigned short* qr = qu + rowbase + (size_t)(tt * 16 + fr) * QS + kh * 8;
      const bf16x8 b0 = *(const bf16x8*)&qr[0];
      const bf16x8 b1 = *(const bf16x8*)&qr[32];
      accQK[tt] = __builtin_amdgcn_mfma_f32_16x16x32_bf16(a0, b0, accQK[tt], 0, 0, 0);
      accQK[tt] = __builtin_amdgcn_mfma_f32_16x16x32_bf16(a1, b1, accQK[tt], 0, 0, 0);
    }
    // mask (keep s <= t), write At, per-wave den partials
#pragma unroll
    for (int tt = 0; tt < 4; ++tt) {
      const int t = tt * 16 + fr;
      float dp = 0.f;
#pragma unroll
      for (int r = 0; r < 4; ++r) {
        const int s = w4 * 16 + kh * 4 + r;
        const float val = (s <= t) ? accQK[tt][r] : 0.f;
        At[s][t] = val;
        dp += val;
      }
      dp += __shfl_xor(dp, 16);
      dp += __shfl_xor(dp, 32);
      if (ln < 16) denp[w4][t] = dp;
    }
  }
  __syncthreads();
  const int t = tid >> 2, sg = tid & 3;
  const float* pk = Ksum + (size_t)g * 64;
  float qpk = 0.f;
#pragma unroll
  for (int c = 0; c < 16; ++c) {
    const float4 q4 = *(const float4*)&Qs[t][4 * c];
    const float4 pk4 = *(const float4*)&pk[4 * c];
    qpk = fmaf(q4.x, pk4.x, fmaf(q4.y, pk4.y, fmaf(q4.z, pk4.z, fmaf(q4.w, pk4.w, qpk))));
  }
  const float den = denp[0][t] + denp[1][t] + denp[2][t] + denp[3][t] + qpk + 1e-6f;
  // --- stage 2a: masked-score @ V ---
  const int e0 = sg * 16;
  float4 num[4] = {};
  for (int s = 0; s <= t; ++s) {
    const float av = At[s][t];
    const int x = (s >> 4) & 3;
#pragma unroll
    for (int i = 0; i < 4; ++i) {
      // address block 4sg+(i^x) stores logical block 4sg+i -> num[i]
      const float4 v4 = *(const float4*)&KVP[s][e0 + 4 * (i ^ x)];
      num[i].x = fmaf(av, v4.x, num[i].x);
      num[i].y = fmaf(av, v4.y, num[i].y);
      num[i].z = fmaf(av, v4.z, num[i].z);
      num[i].w = fmaf(av, v4.w, num[i].w);
    }
  }
  __syncthreads();  // all V reads complete
  const unsigned short* Pg = (const unsigned short*)S + (size_t)g * 4096;
  for (int l = tid; l < 4096; l += 256) KVP[l >> 6][KSWZ(l >> 6, l & 63)] = bf2f(Pg[l]);
  __syncthreads();
  // --- stage 2b: Q @ P ---
  for (int d = 0; d < 64; ++d) {
    const float qd = Qs[t][d];
    const int x = (d >> 4) & 3;
#pragma unroll
    for (int i = 0; i < 4; ++i) {
      const float4 p4 = *(const float4*)&KVP[d][e0 + 4 * (i ^ x)];
      num[i].x = fmaf(qd, p4.x, num[i].x);
      num[i].y = fmaf(qd, p4.y, num[i].y);
      num[i].z = fmaf(qd, p4.z, num[i].z);
      num[i].w = fmaf(qd, p4.w, num[i].w);
    }
  }
#undef KSWZ
  const float inv = 1.f / den;
  float o[16];
#pragma unroll
  for (int i = 0; i < 4; ++i) {
    o[4 * i + 0] = num[i].x * inv;
    o[4 * i + 1] = num[i].y * inv;
    o[4 * i + 2] = num[i].z * inv;
    o[4 * i + 3] = num[i].w * inv;
  }
  // --- fused per-head LN over the 64-wide row (4 sg-lanes x 16 e) ---
  float s1 = 0.f, s2 = 0.f;
#pragma unroll
  for (int i = 0; i < 16; ++i) {
    s1 += o[i];
    s2 += o[i] * o[i];
  }
  s1 += __shfl_xor(s1, 1);
  s1 += __shfl_xor(s1, 2);
  s2 += __shfl_xor(s2, 1);
  s2 += __shfl_xor(s2, 2);
  const float mean = s1 * (1.f / 64.f);
  const float var = s2 * (1.f / 64.f) - mean * mean;
  const float rsv = rsqrtf(var + 1e-5f);
  const float* wv = lnw + h * DHh + e0;
  const float* bv = lnb + h * DHh + e0;
  unsigned short ob[16];
#pragma unroll
  for (int i = 0; i < 16; ++i) {
    const float r = (o[i] - mean) * rsv * wv[i] + bv[i];
    __hip_bfloat16 hv = __float2bfloat16(r);
    ob[i] = *(unsigned short*)&hv;
  }
  unsigned short* yg =
      (unsigned short*)yhb + (size_t)(b * Tt + j * CHK + t) * Dd + h * DHh + e0;
#pragma unroll
  for (int i = 0; i < 4; ++i) *(ushort4*)&yg[4 * i] = *(ushort4*)&ob[4 * i];
}

// ---------------------------------------------------------------------------
// Fused FFN2-reduce (4 bf16 split-K partials) + bias + relu + residual +
// final layernorm over D=1024.
// ---------------------------------------------------------------------------
__global__ __launch_bounds__(256) void final_ln(const float* __restrict__ x,
                                                const __hip_bfloat16* __restrict__ part,
                                                const float* __restrict__ b2,
                                                const float* __restrict__ w,
                                                const float* __restrict__ bb,
                                                float* __restrict__ out) {
  __shared__ float r1[4], r2[4];
  const int row = blockIdx.x;
  const int tid = threadIdx.x;
  const size_t off = (size_t)row * Dd + tid * 4;
  const size_t MN = (size_t)Mm * Dd;
  float acc4[4] = {0.f, 0.f, 0.f, 0.f};
#pragma unroll
  for (int z = 0; z < 4; ++z) {
    const ushort4 u = *(const ushort4*)&part[off + (size_t)z * MN];
    acc4[0] += bf2f(u.x);
    acc4[1] += bf2f(u.y);
    acc4[2] += bf2f(u.z);
    acc4[3] += bf2f(u.w);
  }
  const float4 bv = *(const float4*)&b2[tid * 4];
  const float4 xa = *(const float4*)&x[off];
  float z[4];
  z[0] = xa.x + fmaxf(acc4[0] + bv.x, 0.f);
  z[1] = xa.y + fmaxf(acc4[1] + bv.y, 0.f);
  z[2] = xa.z + fmaxf(acc4[2] + bv.z, 0.f);
  z[3] = xa.w + fmaxf(acc4[3] + bv.w, 0.f);
  float s1 = z[0] + z[1] + z[2] + z[3];
  float s2 = z[0] * z[0] + z[1] * z[1] + z[2] * z[2] + z[3] * z[3];
#pragma unroll
  for (int o = 1; o < 64; o <<= 1) {
    s1 += __shfl_xor(s1, o);
    s2 += __shfl_xor(s2, o);
  }
  const int wid = tid >> 6;
  if ((tid & 63) == 0) {
    r1[wid] = s1;
    r2[wid] = s2;
  }
  __syncthreads();
  const float t1 = r1[0] + r1[1] + r1[2] + r1[3];
  const float t2 = r2[0] + r2[1] + r2[2] + r2[3];
  const float mu = t1 * (1.f / Dd);
  const float var = t2 * (1.f / Dd) - mu * mu;
  const float rsv = rsqrtf(var + 1e-5f);
  float4 o4;
  float* op = &o4.x;
#pragma unroll
  for (int jj = 0; jj < 4; ++jj) op[jj] = (z[jj] - mu) * rsv * w[tid * 4 + jj] + bb[tid * 4 + jj];
  *(float4*)&out[off] = o4;
}

// ---------------------------------------------------------------------------
extern "C" void kernel_launch(void* const* d_in, const int* in_sizes, int n_in,
                              void* d_out, int out_size, void* d_ws, size_t ws_size,
                              hipStream_t stream) {
  const float* x = (const float*)d_in[0];
  const float* W_amp = (const float*)d_in[1];
  const float* b_amp = (const float*)d_in[2];
  const float* W_phi = (const float*)d_in[3];
  const float* b_phi = (const float*)d_in[4];
  const float* omega = (const float*)d_in[5];
  const float* ret_logit = (const float*)d_in[6];
  const float* theta = (const float*)d_in[7];
  const float* W_feat = (const float*)d_in[8];
  const float* b_feat = (const float*)d_in[9];
  const float* Wq = (const float*)d_in[10];
  const float* Wk = (const float*)d_in[11];
  const float* Wv = (const float*)d_in[12];
  const float* lnh_w = (const float*)d_in[13];
  const float* lnh_b = (const float*)d_in[14];
  const float* W1 = (const float*)d_in[15];
  const float* b1 = (const float*)d_in[16];
  const float* W2 = (const float*)d_in[17];
  const float* b2 = (const float*)d_in[18];
  const float* ln_w = (const float*)d_in[19];
  const float* ln_b = (const float*)d_in[20];

  // ---- workspace bump allocator (256B aligned); dedicated buffers ----
  char* p = (char*)d_ws;
  auto alloc = [&](size_t bytes) {
    char* r = p;
    p += (bytes + 255) & ~(size_t)255;
    return r;
  };
  __hip_bfloat16* xb = (__hip_bfloat16*)alloc((size_t)Mm * Dd * 2);   // later: featb
  __hip_bfloat16* urh = (__hip_bfloat16*)alloc((size_t)Mm * NFf * 2);
  __hip_bfloat16* uih = (__hip_bfloat16*)alloc((size_t)Mm * NFf * 2);
  __hip_bfloat16* WTamp = (__hip_bfloat16*)alloc((size_t)NFf * Dd * 2);  // +WTphi contiguous
  __hip_bfloat16* WTphi = (__hip_bfloat16*)alloc((size_t)NFf * Dd * 2);
  __hip_bfloat16* WTfeat = (__hip_bfloat16*)alloc((size_t)Dd * 3 * NFf * 2);
  __hip_bfloat16* WTq = (__hip_bfloat16*)alloc((size_t)Dd * Dd * 2);  // +k+v contiguous
  __hip_bfloat16* WTk = (__hip_bfloat16*)alloc((size_t)Dd * Dd * 2);
  __hip_bfloat16* WTv = (__hip_bfloat16*)alloc((size_t)Dd * Dd * 2);
  __hip_bfloat16* WT1 = (__hip_bfloat16*)alloc((size_t)Rr * Dd * 2);
  __hip_bfloat16* WT2 = (__hip_bfloat16*)alloc((size_t)Dd * Rr * 2);
  __hip_bfloat16* hb = (__hip_bfloat16*)alloc((size_t)Mm * Dd * 2);
  __hip_bfloat16* qkvb = (__hip_bfloat16*)alloc((size_t)Mm * QS * 2);  // 12 MB
  __hip_bfloat16* yhb = (__hip_bfloat16*)alloc((size_t)Mm * Dd * 2);   // 4 MB
  __hip_bfloat16* S = (__hip_bfloat16*)alloc((size_t)Bb * Hh * NCHK * 4096 * 2);  // 4 MB bf16
  float* Ksum = (float*)alloc((size_t)Bb * Hh * NCHK * 64 * 4);
  __hip_bfloat16* f1b = (__hip_bfloat16*)alloc((size_t)Mm * Rr * 2);   // 16 MB
  __hip_bfloat16* pamp = (__hip_bfloat16*)alloc((size_t)4 * Mm * 512 * 2);   // 8 MB dedicated
  __hip_bfloat16* pffn2 = (__hip_bfloat16*)alloc((size_t)4 * Mm * Dd * 2);   // 16 MB dedicated

  __hip_bfloat16* featb = xb;  // xb dead after ampphi GEMM (stream-ordered)
  const __hip_bfloat16* q = qkvb;
  const __hip_bfloat16* k = qkvb + 1024;
  const __hip_bfloat16* v = qkvb + 2048;
  float* out = (float*)d_out;

  const dim3 blk(256);

  // 0: amp/phi weight transposes + x cast (what the first GEMM needs)
  tc_first<<<dim3(2560), blk, 0, stream>>>(W_amp, W_phi, WTamp, WTphi, x, xb);

  // 1: fused amp/phi projection, split-K=4 (256 blocks, bf16 partials), then
  //    fused reduce + softplus/tanh + polar -> bf16 u
  gemm_mfma<EPI_NONE, 1, 4><<<dim3(512 / 128, Mm / 128, 4), blk, 0, stream>>>(
      (const short*)xb, (const short*)WTamp, nullptr, nullptr, pamp, Mm, 512, Dd);
  reduce_polar<<<dim3(Mm * NFf / 256), blk, 0, stream>>>(pamp, b_amp, b_phi, urh, uih);

  // 2: FUSED resonator scan (64 blocks) || remaining weight transposes
  STDesc st;
  st.src[0] = W_feat; st.dst[0] = WTfeat;
  st.src[1] = Wq; st.dst[1] = WTq;
  st.src[2] = Wk; st.dst[2] = WTk;
  st.src[3] = Wv; st.dst[3] = WTv;
  st.src[4] = W1; st.dst[4] = WT1;
  st.src[5] = W2; st.dst[5] = WT2;
  st.ur = urh; st.ui = uih;
  st.omega = omega; st.ret_logit = ret_logit; st.theta = theta;
  st.featb = featb;
  scan_and_tc<<<dim3(64 + 12032), blk, 0, stream>>>(st);

  // 3: feat projection -> h (bf16)
  gemm_mfma<EPI_RELU, 1, 0><<<dim3(Dd / 128, Mm / 128), blk, 0, stream>>>(
      (const short*)featb, (const short*)WTfeat, b_feat, nullptr, hb, Mm, Dd, 3 * NFf);

  // 4: fused q,k,v projection -> bf16 qkvb (384 blocks, 1.5 blocks/CU)
  gemm_mfma<EPI_QKV, 1, 0><<<dim3(QS / 128, Mm / 128), blk, 0, stream>>>(
      (const short*)hb, (const short*)WTq, nullptr, nullptr, qkvb, Mm, QS, Dd);

  // 5: chunked causal linear attention (+ fused per-head LN in attn_out)
  attn_chunk_kv<<<dim3(Bb * Hh * NCHK), blk, 0, stream>>>(k, v, S, Ksum);
  attn_prefix<<<dim3(520), blk, 0, stream>>>(S, Ksum);
  attn_out<<<dim3(Bb * Hh * NCHK), blk, 0, stream>>>(q, k, v, S, Ksum, lnh_w, lnh_b, yhb);

  // 6: FFN1 -> f1b (bf16); 512 blocks = 2 blocks/CU (LDS-capped max)
  gemm_mfma<EPI_RELU, 1, 0><<<dim3(Rr / 128, Mm / 128), blk, 0, stream>>>(
      (const short*)yhb, (const short*)WT1, b1, nullptr, f1b, Mm, Rr, Dd);

  // 7: FFN2 split-K=4, bf16 partials -> pffn2; 512 blocks = 2 blocks/CU
  gemm_mfma<EPI_NONE, 1, 4><<<dim3(Dd / 128, Mm / 128, 4), blk, 0, stream>>>(
      (const short*)f1b, (const short*)WT2, nullptr, nullptr, pffn2, Mm, Dd, Rr);

  // 8: fused reduce(4x bf16) + bias + relu + residual + final layernorm
  final_ln<<<dim3(Mm), blk, 0, stream>>>(x, pffn2, b2, ln_w, ln_b, out);
}

// Round 17
// 159.510 us; speedup vs baseline: 1.4712x; 1.0745x over previous
//
#include <hip/hip_runtime.h>
#include <hip/hip_bf16.h>
#include <math.h>

#ifndef M_PI_F
#define M_PI_F 3.14159265358979323846f
#endif

static constexpr int Bb = 2, Tt = 1024, Dd = 1024, Hh = 16, DHh = 64, NFf = 256, Rr = 4096;
static constexpr int Mm = Bb * Tt;
static constexpr int CHK = 64, NCHK = Tt / CHK;  // attention chunking
static constexpr int QS = 3072;                  // fused qkv row stride

enum Epi { EPI_NONE = 0, EPI_RELU, EPI_QKV };

typedef __attribute__((ext_vector_type(8))) short bf16x8;
typedef __attribute__((ext_vector_type(4))) float f32x4;

__device__ inline float bf2f(unsigned short u) {
  union { unsigned int i; float f; } c;
  c.i = (unsigned int)u << 16;
  return c.f;
}

__device__ inline unsigned short f2bf(float f) {
  __hip_bfloat16 h = __float2bfloat16(f);
  return *(unsigned short*)&h;
}

// ---------------------------------------------------------------------------
// async global->LDS, 16B per lane. LDS dest is wave-uniform base; HW adds
// lane*16. Global address is per-lane.
// ---------------------------------------------------------------------------
__device__ inline void gload16(const short* g, short* l) {
  __builtin_amdgcn_global_load_lds(
      (const __attribute__((address_space(1))) unsigned int*)g,
      (__attribute__((address_space(3))) unsigned int*)l, 16, 0, 0);
}

// ---------------------------------------------------------------------------
// bf16 MFMA GEMM: C[M,N] = epi(A[M,K] @ BT[N,K]^T + bias)
// 128x128 tile, BK=64, 4 waves (2x2), each 64x64 via 4x4 frags of 16x16x32.
// - Double-buffered K-loop, counted vmcnt (r7). r9/r10 lesson: >=2 blocks/CU
//   co-residency (m114) is the stall-hiding lever, not pipeline depth.
// - LDS XOR bank-swizzle (rule #21 both-sides involution).
// - Bijective XCD swizzle (m204) for A-panel L2 reuse per XCD.
// - SPLITK: partial (fp32 Cf / bf16 Cb) at +z*M*N into DEDICATED buffers.
// ---------------------------------------------------------------------------
#define GSTAGE(bufsel, kk0)                                           \
  _Pragma("unroll") for (int si = 0; si < 4; ++si) {                  \
    const int s = wid + si * 4;                                       \
    gload16(A + (size_t)(m0 + s * 8 + srow) * ldk + (kk0) + skk,      \
            &lA[(bufsel) * 8192 + s * 512]);                          \
    gload16(BT + (size_t)(n0 + s * 8 + srow) * ldk + (kk0) + skk,     \
            &lB[(bufsel) * 8192 + s * 512]);                          \
  }

template <int EPI, int OUTBF, int SPLITK>
__global__ __launch_bounds__(256) void gemm_mfma(const short* __restrict__ A,
                                                 const short* __restrict__ BT,
                                                 const float* __restrict__ bias,
                                                 float* __restrict__ Cf,
                                                 __hip_bfloat16* __restrict__ Cb,
                                                 int M, int N, int ldk) {
  __shared__ short lA[2 * 128 * 64];
  __shared__ short lB[2 * 128 * 64];
  const int tid = threadIdx.x;
  const int wid = tid >> 6, lane = tid & 63;

  // XCD-aware bijective block swizzle (grids here always have nwg % 8 == 0)
  const int nwg = gridDim.x * gridDim.y;
  const int wg = blockIdx.y * gridDim.x + blockIdx.x;
  const int qq = nwg >> 3, rr = nwg & 7;
  const int xcd = wg & 7, idx = wg >> 3;
  const int wg2 = (xcd < rr ? xcd * (qq + 1) : rr * (qq + 1) + (xcd - rr) * qq) + idx;
  const int bx = wg2 % gridDim.x, by = wg2 / gridDim.x;

  const int m0 = by * 128, n0 = bx * 128;
  const int wm = (wid >> 1) * 64, wn = (wid & 1) * 64;
  const int srow = lane >> 3;                         // row within 8-row slab
  const int skk = (((lane & 7) ^ (lane >> 3)) << 3);  // swizzled k offset (elems)

  int kstart = 0, klen = ldk;
  if (SPLITK > 1) {
    klen = ldk / SPLITK;
    kstart = blockIdx.z * klen;
    if (OUTBF)
      Cb += (size_t)blockIdx.z * M * N;
    else
      Cf += (size_t)blockIdx.z * M * N;
  }
  const int kend = kstart + klen;

  f32x4 acc[4][4] = {};

  GSTAGE(0, kstart);  // prologue: 8 loads/wave in flight
  int cur = 0;
  for (int k0 = kstart; k0 < kend; k0 += 64) {
    if (k0 + 64 < kend) {
      GSTAGE(cur ^ 1, k0 + 64);                         // 16 in flight
      asm volatile("s_waitcnt vmcnt(8)" ::: "memory");  // oldest 8 (cur buf) done
    } else {
      asm volatile("s_waitcnt vmcnt(0)" ::: "memory");
    }
    asm volatile("s_barrier" ::: "memory");
    const short* bA = &lA[cur * 8192];
    const short* bB = &lB[cur * 8192];
#pragma unroll
    for (int kk = 0; kk < 2; ++kk) {
      const int krd = kk * 32 + (lane >> 4) * 8;
      const int rsel = lane & 15;
      const int kswz = krd ^ ((rsel & 7) << 3);  // same involution as store side
      bf16x8 af[4], bfr[4];
#pragma unroll
      for (int i = 0; i < 4; ++i) {
        af[i] = *(const bf16x8*)&bA[(wm + i * 16 + rsel) * 64 + kswz];
        bfr[i] = *(const bf16x8*)&bB[(wn + i * 16 + rsel) * 64 + kswz];
      }
#pragma unroll
      for (int i = 0; i < 4; ++i)
#pragma unroll
        for (int j = 0; j < 4; ++j)
          acc[i][j] = __builtin_amdgcn_mfma_f32_16x16x32_bf16(af[i], bfr[j], acc[i][j], 0, 0, 0);
    }
    // ds_read results are consumed by MFMA (compiler lgkmcnt) before here.
    asm volatile("s_barrier" ::: "memory");  // all waves done reading cur buf
    cur ^= 1;
  }

  const int crow = (lane >> 4) * 4;
  const int ccol = lane & 15;
#pragma unroll
  for (int j = 0; j < 4; ++j) {
    const int col = n0 + wn + j * 16 + ccol;
    const float bv = bias ? bias[col] : 0.f;
#pragma unroll
    for (int i = 0; i < 4; ++i) {
#pragma unroll
      for (int r = 0; r < 4; ++r) {
        float v = acc[i][j][r] + bv;
        const int row = m0 + wm + i * 16 + crow + r;
        if (EPI == EPI_QKV) {
          const float vv = (col < 2048) ? fmaxf(v, 0.f) : v;
          Cb[(size_t)row * QS + col] = __float2bfloat16(vv);
        } else {
          if (EPI == EPI_RELU) v = fmaxf(v, 0.f);
          const size_t off = (size_t)row * N + col;
          if (OUTBF)
            Cb[off] = __float2bfloat16(v);
          else
            Cf[off] = v;
        }
      }
    }
  }
}

// ---------------------------------------------------------------------------
// 32x32 transpose-cast tile helper: W[K,N] f32 -> WT[N,K] bf16.
// ---------------------------------------------------------------------------
__device__ __forceinline__ void tc_tile(float (*tile)[33], const float* __restrict__ W,
                                        __hip_bfloat16* __restrict__ WT, int K, int N,
                                        int tlocal) {
  const int tilesN = N / 32;
  const int bk = (tlocal / tilesN) * 32, bn = (tlocal % tilesN) * 32;
  const int tx = threadIdx.x & 31, ty = threadIdx.x >> 5;  // 32x8
#pragma unroll
  for (int r = 0; r < 32; r += 8) tile[ty + r][tx] = W[(size_t)(bk + ty + r) * N + bn + tx];
  __syncthreads();
#pragma unroll
  for (int r = 0; r < 32; r += 8)
    WT[(size_t)(bn + ty + r) * K + bk + tx] = __float2bfloat16(tile[tx][ty + r]);
}

// ---------------------------------------------------------------------------
// Head kernel: W_amp / W_phi transpose-cast + x f32->bf16 cast.
// ---------------------------------------------------------------------------
__global__ __launch_bounds__(256) void tc_first(const float* __restrict__ W_amp,
                                                const float* __restrict__ W_phi,
                                                __hip_bfloat16* __restrict__ WTamp,
                                                __hip_bfloat16* __restrict__ WTphi,
                                                const float* __restrict__ x,
                                                __hip_bfloat16* __restrict__ xb) {
  __shared__ float tile[32][33];
  const int bid = blockIdx.x;
  if (bid >= 512) {
    const int i = ((bid - 512) * 256 + threadIdx.x) * 4;
    const float4 v = *(const float4*)&x[i];
    xb[i + 0] = __float2bfloat16(v.x);
    xb[i + 1] = __float2bfloat16(v.y);
    xb[i + 2] = __float2bfloat16(v.z);
    xb[i + 3] = __float2bfloat16(v.w);
    return;
  }
  if (bid < 256)
    tc_tile(tile, W_amp, WTamp, 1024, 256, bid);
  else
    tc_tile(tile, W_phi, WTphi, 1024, 256, bid - 256);
}

// ---------------------------------------------------------------------------
// amp/phi split-K reduce (4 bf16 partials) fused with activations and
// polar->cartesian. part layout: [4][M][512] bf16 (cols 0..255 amp, rest phi).
// ---------------------------------------------------------------------------
__global__ __launch_bounds__(256) void reduce_polar(const __hip_bfloat16* __restrict__ part,
                                                    const float* __restrict__ b_amp,
                                                    const float* __restrict__ b_phi,
                                                    __hip_bfloat16* __restrict__ outr,
                                                    __hip_bfloat16* __restrict__ outi) {
  const int idx = blockIdx.x * 256 + threadIdx.x;  // [0, M*NF)
  const int row = idx >> 8, c = idx & 255;
  const size_t MN = (size_t)Mm * 512;
  const size_t pa = (size_t)row * 512 + c;
  const unsigned short* pu = (const unsigned short*)part;
  float a = bf2f(pu[pa]) + bf2f(pu[pa + MN]) + bf2f(pu[pa + 2 * MN]) + bf2f(pu[pa + 3 * MN]) +
            b_amp[c];
  float ph = bf2f(pu[pa + 256]) + bf2f(pu[pa + 256 + MN]) + bf2f(pu[pa + 256 + 2 * MN]) +
             bf2f(pu[pa + 256 + 3 * MN]) + b_phi[c];
  a = (a > 0.f) ? (a + log1pf(expf(-a))) : log1pf(expf(a));
  ph = M_PI_F * tanhf(ph);
  float s, co;
  sincosf(ph, &s, &co);
  outr[idx] = __float2bfloat16(a * co);
  outi[idx] = __float2bfloat16(a * s);
}

// ---------------------------------------------------------------------------
// FUSED: resonator scan (blocks 0..63) || transpose-cast of the 6 remaining
// weights (blocks 64..12095) — independent work backfills the machine (r11).
// Scan: TIME-CHUNK PARALLEL (r6): contraction >= sigmoid(2.0)=0.881/step
// makes a 128-step warm-up from X=0 exact below bf16 quantization.
// ---------------------------------------------------------------------------
static constexpr int RES_P = 16;
static constexpr int RES_TC = 128;  // chunk length
static constexpr int RES_W = 128;   // warm-up length

#define RES_LOAD(buf_r, buf_i, tg)                                        \
  if ((tg) < cend) {                                                      \
    _Pragma("unroll") for (int i = 0; i < RES_P; ++i) {                   \
      buf_r[i] = __bfloat162float(ur[bbase + (size_t)((tg) + i) * NFf]);  \
      buf_i[i] = __bfloat162float(ui[bbase + (size_t)((tg) + i) * NFf]);  \
    }                                                                     \
  }

#define RES_STEP(buf_r, buf_i, tg)                                      \
  {                                                                      \
    const bool wr_ = (tg) >= cstart;                                     \
    _Pragma("unroll") for (int i = 0; i < RES_P; ++i) {                  \
      const float pr = fmaf(ar, Xr, fmaf(-ai, Xi, buf_r[i]));            \
      const float pim = fmaf(ar, Xi, fmaf(ai, Xr, buf_i[i]));            \
      const float mag = __builtin_amdgcn_sqrtf(fmaf(pr, pr, pim * pim)); \
      const float g = __builtin_amdgcn_rcpf(1.f + __expf(th - mag));     \
      Xr = pr * g;                                                       \
      Xi = pim * g;                                                      \
      if (wr_) {                                                         \
        const size_t fb = ((size_t)b * Tt + (tg) + i) * (3 * NFf);       \
        featb[fb + f] = __float2bfloat16(Xr);                            \
        featb[fb + NFf + f] = __float2bfloat16(Xi);                      \
        featb[fb + 2 * NFf + f] = __float2bfloat16(mag * g);             \
      }                                                                  \
    }                                                                    \
  }

struct STDesc {
  const float* src[6];
  __hip_bfloat16* dst[6];
  const __hip_bfloat16* ur;
  const __hip_bfloat16* ui;
  const float* omega;
  const float* ret_logit;
  const float* theta;
  __hip_bfloat16* featb;
};

__global__ __launch_bounds__(256) void scan_and_tc(STDesc d) {
  __shared__ float tile[32][33];
  const int bid = blockIdx.x;
  if (bid < 64) {
    if (threadIdx.x >= 64) return;  // scan uses 64 lanes; no barriers below
    const int tc = bid & 7;
    const int fs = (bid >> 3) & 3;
    const int b = bid >> 5;
    const int f = fs * 64 + threadIdx.x;
    const int cstart = tc * RES_TC;
    const int cend = cstart + RES_TC;
    const int tbeg = (cstart >= RES_W) ? cstart - RES_W : 0;
    const __hip_bfloat16* ur = d.ur;
    const __hip_bfloat16* ui = d.ui;
    __hip_bfloat16* featb = d.featb;
    const float dec = 1.f / (1.f + __expf(-d.ret_logit[f]));
    float so, co;
    sincosf(d.omega[f], &so, &co);
    const float ar = dec * co, ai = dec * so;
    const float th = d.theta[f];
    const size_t bbase = (size_t)b * Tt * NFf + f;
    float Xr = 0.f, Xi = 0.f;
    float Ar[RES_P], Ai[RES_P], Br[RES_P], Bi[RES_P];
    RES_LOAD(Ar, Ai, tbeg);
    for (int t0 = tbeg; t0 < cend; t0 += 2 * RES_P) {
      RES_LOAD(Br, Bi, t0 + RES_P);
      RES_STEP(Ar, Ai, t0);
      RES_LOAD(Ar, Ai, t0 + 2 * RES_P);
      RES_STEP(Br, Bi, t0 + RES_P);
    }
    return;
  }
  // transpose-cast region: W_feat, Wq, Wk, Wv, W1, W2
  constexpr int KS[6] = {768, 1024, 1024, 1024, 1024, 4096};
  constexpr int NS[6] = {1024, 1024, 1024, 1024, 4096, 1024};
  constexpr int CUM[7] = {0, 768, 1792, 2816, 3840, 7936, 12032};
  const int t = bid - 64;
  int w = 0;
#pragma unroll
  for (int i = 0; i < 6; ++i)
    if (t >= CUM[i + 1]) w = i + 1;
  tc_tile(tile, d.src[w], d.dst[w], KS[w], NS[w], t - CUM[w]);
}

// ---------------------------------------------------------------------------
// Attention phase A: per-chunk KV outer-product sums (bf16 S out) and fp32
// k-sums.
// ---------------------------------------------------------------------------
__global__ __launch_bounds__(256) void attn_chunk_kv(const __hip_bfloat16* __restrict__ k,
                                                     const __hip_bfloat16* __restrict__ v,
                                                     __hip_bfloat16* __restrict__ S,
                                                     float* __restrict__ Ksum) {
  __shared__ float Ks[64][68], Vs[64][68];
  const int g = blockIdx.x;
  const int j = g & (NCHK - 1), bh = g >> 4;
  const int b = bh >> 4, h = bh & (Hh - 1);
  const int tid = threadIdx.x;
  const size_t rowbase = (size_t)(b * Tt + j * CHK) * QS + h * DHh;
  const unsigned short* ku = (const unsigned short*)k;
  const unsigned short* vu = (const unsigned short*)v;
  for (int l = tid; l < 4096; l += 256) {
    const int s = l >> 6, d = l & 63;
    Ks[s][d] = bf2f(ku[rowbase + (size_t)s * QS + d]);
    Vs[s][d] = bf2f(vu[rowbase + (size_t)s * QS + d]);
  }
  __syncthreads();
  const int d0 = tid & 63, eb = tid >> 6, e0 = eb * 16;
  float4 acc4[4] = {};
  float ks = 0.f;
  for (int s = 0; s < 64; ++s) {
    const float kd = Ks[s][d0];
    ks += kd;
#pragma unroll
    for (int i = 0; i < 4; ++i) {
      const float4 v4 = *(const float4*)&Vs[s][e0 + 4 * i];
      acc4[i].x = fmaf(kd, v4.x, acc4[i].x);
      acc4[i].y = fmaf(kd, v4.y, acc4[i].y);
      acc4[i].z = fmaf(kd, v4.z, acc4[i].z);
      acc4[i].w = fmaf(kd, v4.w, acc4[i].w);
    }
  }
  unsigned short* Sg = (unsigned short*)S + (size_t)g * 4096 + (size_t)d0 * 64 + e0;
#pragma unroll
  for (int i = 0; i < 4; ++i) {
    ushort4 o;
    o.x = f2bf(acc4[i].x);
    o.y = f2bf(acc4[i].y);
    o.z = f2bf(acc4[i].z);
    o.w = f2bf(acc4[i].w);
    *(ushort4*)&Sg[4 * i] = o;
  }
  if (eb == 0) Ksum[(size_t)g * 64 + d0] = ks;
}

// ---------------------------------------------------------------------------
// Attention phase B: EXCLUSIVE prefix over the 16 chunks per (b,h).
// FULLY PARALLEL (r10): one thread per chain; fp32 running sum, bf16 storage.
// ---------------------------------------------------------------------------
__global__ __launch_bounds__(256) void attn_prefix(__hip_bfloat16* __restrict__ S,
                                                   float* __restrict__ Ksum) {
  const int bid = blockIdx.x;
  const int tid = threadIdx.x;
  if (bid < 512) {
    const int bh = bid >> 4, r = bid & 15;
    const int de = r * 256 + tid;
    unsigned short* Su = (unsigned short*)S;
    const size_t base = (size_t)bh * (NCHK * 4096) + de;
    float vv[NCHK];
#pragma unroll
    for (int j = 0; j < NCHK; ++j) vv[j] = bf2f(Su[base + (size_t)j * 4096]);
    float run = 0.f;
#pragma unroll
    for (int j = 0; j < NCHK; ++j) {
      const float tmp = vv[j];
      Su[base + (size_t)j * 4096] = f2bf(run);
      run += tmp;
    }
  } else {
    const int cid = (bid - 512) * 256 + tid;  // [0, 2048)
    const int bh = cid >> 6, d = cid & 63;
    const size_t base = (size_t)bh * (NCHK * 64) + d;
    float vv[NCHK];
#pragma unroll
    for (int j = 0; j < NCHK; ++j) vv[j] = Ksum[base + (size_t)j * 64];
    float run = 0.f;
#pragma unroll
    for (int j = 0; j < NCHK; ++j) {
      const float tmp = vv[j];
      Ksum[base + (size_t)j * 64] = run;
      run += tmp;
    }
  }
}

// ---------------------------------------------------------------------------
// Attention phase C + fused per-head layernorm — FULLY MFMA (r16/r17).
// Stage 1 (QK^T): frags direct from global; writes masked scores as
// DOUBLE-BF16 (hi + lo) At[t][s] — r17 fix: single-bf16 At cost 0.4% rel on
// the dominant intra-chunk numerator and failed absmax (0.154 > 0.114).
// hi/lo recovers ~16 mantissa bits: At@V = hi@V + lo@V (fp32 MFMA accum).
// Stage 2: num[t][e] = At @ V + Q @ P via MFMA (V, P staged transposed).
// Same operand convention as gemm_mfma (first operand -> C rows, second ->
// C cols; A-row/B-col = lane&15, k = (lane>>4)*8; C row = (lane>>4)*4+r).
// LN epilogue: row t spans 16 consecutive lanes -> shfl_xor 1/2/4/8.
// ---------------------------------------------------------------------------
__global__ __launch_bounds__(256) void attn_out(const __hip_bfloat16* __restrict__ q,
                                                const __hip_bfloat16* __restrict__ k,
                                                const __hip_bfloat16* __restrict__ v,
                                                const __hip_bfloat16* __restrict__ S,
                                                const float* __restrict__ Ksum,
                                                const float* __restrict__ lnw,
                                                const float* __restrict__ lnb,
                                                __hip_bfloat16* __restrict__ yhb) {
  __shared__ unsigned short Atb[64][72];  // masked scores hi [t][s] bf16
  __shared__ unsigned short Atl[64][72];  // masked scores lo [t][s] bf16
  __shared__ unsigned short Vt[64][72];   // V^T [e][s] bf16
  __shared__ unsigned short Pt[64][72];   // P^T [e][d] bf16
  __shared__ float denp[4][64];
  __shared__ float dens[64];
  const int g = blockIdx.x;
  const int j = g & (NCHK - 1), bh = g >> 4;
  const int b = bh >> 4, h = bh & (Hh - 1);
  const int tid = threadIdx.x;
  const size_t rowbase = (size_t)(b * Tt + j * CHK) * QS + h * DHh;
  const unsigned short* qu = (const unsigned short*)q;
  const unsigned short* ku = (const unsigned short*)k;
  const unsigned short* vu = (const unsigned short*)v;
  const unsigned short* Pg = (const unsigned short*)S + (size_t)g * 4096;

  // entry: stage V^T and P^T (raw ushort copies; both already bf16)
  for (int l = tid; l < 4096; l += 256) {
    const int s = l >> 6, e = l & 63;
    Vt[e][s] = vu[rowbase + (size_t)s * QS + e];
    Pt[e][s] = Pg[l];  // l = d*64+e with d=l>>6 -> Pt[e][d]
  }
  // --- stage 1: QK^T via MFMA, fragments direct from global ---
  {
    const int w4 = tid >> 6, ln = tid & 63;
    const int fr = ln & 15;
    const int kh = ln >> 4;
    const unsigned short* kr = ku + rowbase + (size_t)(w4 * 16 + fr) * QS + kh * 8;
    const bf16x8 a0 = *(const bf16x8*)&kr[0];
    const bf16x8 a1 = *(const bf16x8*)&kr[32];
    f32x4 accQK[4] = {};
#pragma unroll
    for (int tt = 0; tt < 4; ++tt) {
      const unsigned short* qr = qu + rowbase + (size_t)(tt * 16 + fr) * QS + kh * 8;
      const bf16x8 b0 = *(const bf16x8*)&qr[0];
      const bf16x8 b1 = *(const bf16x8*)&qr[32];
      accQK[tt] = __builtin_amdgcn_mfma_f32_16x16x32_bf16(a0, b0, accQK[tt], 0, 0, 0);
      accQK[tt] = __builtin_amdgcn_mfma_f32_16x16x32_bf16(a1, b1, accQK[tt], 0, 0, 0);
    }
    // mask (keep s <= t), write hi/lo At[t][s], per-wave den partials
#pragma unroll
    for (int tt = 0; tt < 4; ++tt) {
      const int t = tt * 16 + fr;
      float dp = 0.f;
#pragma unroll
      for (int r = 0; r < 4; ++r) {
        const int s = w4 * 16 + kh * 4 + r;
        const float val = (s <= t) ? accQK[tt][r] : 0.f;
        const unsigned short hv = f2bf(val);
        Atb[t][s] = hv;
        Atl[t][s] = f2bf(val - bf2f(hv));
        dp += val;
      }
      dp += __shfl_xor(dp, 16);
      dp += __shfl_xor(dp, 32);
      if (ln < 16) denp[w4][t] = dp;
    }
  }
  __syncthreads();
  // --- den: qpk (q direct from global, sg-split) + denp sums ---
  {
    const int t = tid >> 2, sg = tid & 3;
    const float* pk = Ksum + (size_t)g * 64;
    const unsigned short* qr = qu + rowbase + (size_t)t * QS + sg * 16;
    float qpk = 0.f;
#pragma unroll
    for (int i = 0; i < 16; ++i) qpk = fmaf(bf2f(qr[i]), pk[sg * 16 + i], qpk);
    qpk += __shfl_xor(qpk, 1);
    qpk += __shfl_xor(qpk, 2);
    if (sg == 0)
      dens[t] = denp[0][t] + denp[1][t] + denp[2][t] + denp[3][t] + qpk + 1e-6f;
  }
  __syncthreads();
  // --- stage 2: num = At @ V + Q @ P via MFMA (hi + lo passes for At) ---
  const int w = tid >> 6, ln = tid & 63;
  const int fr = ln & 15;
  const int kh = ln >> 4;
  const bf16x8 sa0 = *(const bf16x8*)&Atb[w * 16 + fr][kh * 8];
  const bf16x8 sa1 = *(const bf16x8*)&Atb[w * 16 + fr][kh * 8 + 32];
  const bf16x8 la0 = *(const bf16x8*)&Atl[w * 16 + fr][kh * 8];
  const bf16x8 la1 = *(const bf16x8*)&Atl[w * 16 + fr][kh * 8 + 32];
  const unsigned short* q2 = qu + rowbase + (size_t)(w * 16 + fr) * QS + kh * 8;
  const bf16x8 qa0 = *(const bf16x8*)&q2[0];
  const bf16x8 qa1 = *(const bf16x8*)&q2[32];
  f32x4 acc2[4] = {};
#pragma unroll
  for (int ct = 0; ct < 4; ++ct) {
    const bf16x8 vb0 = *(const bf16x8*)&Vt[ct * 16 + fr][kh * 8];
    const bf16x8 vb1 = *(const bf16x8*)&Vt[ct * 16 + fr][kh * 8 + 32];
    const bf16x8 pb0 = *(const bf16x8*)&Pt[ct * 16 + fr][kh * 8];
    const bf16x8 pb1 = *(const bf16x8*)&Pt[ct * 16 + fr][kh * 8 + 32];
    acc2[ct] = __builtin_amdgcn_mfma_f32_16x16x32_bf16(sa0, vb0, acc2[ct], 0, 0, 0);
    acc2[ct] = __builtin_amdgcn_mfma_f32_16x16x32_bf16(sa1, vb1, acc2[ct], 0, 0, 0);
    acc2[ct] = __builtin_amdgcn_mfma_f32_16x16x32_bf16(la0, vb0, acc2[ct], 0, 0, 0);
    acc2[ct] = __builtin_amdgcn_mfma_f32_16x16x32_bf16(la1, vb1, acc2[ct], 0, 0, 0);
    acc2[ct] = __builtin_amdgcn_mfma_f32_16x16x32_bf16(qa0, pb0, acc2[ct], 0, 0, 0);
    acc2[ct] = __builtin_amdgcn_mfma_f32_16x16x32_bf16(qa1, pb1, acc2[ct], 0, 0, 0);
  }
  // --- epilogue: divide by den, per-head LN (row t in 16 consecutive lanes) ---
  unsigned short* yb = (unsigned short*)yhb;
#pragma unroll
  for (int r = 0; r < 4; ++r) {
    const int t = w * 16 + kh * 4 + r;
    const float inv = 1.f / dens[t];
    float o[4];
    float s1 = 0.f, s2 = 0.f;
#pragma unroll
    for (int ct = 0; ct < 4; ++ct) {
      o[ct] = acc2[ct][r] * inv;
      s1 += o[ct];
      s2 += o[ct] * o[ct];
    }
#pragma unroll
    for (int m = 1; m < 16; m <<= 1) {
      s1 += __shfl_xor(s1, m);
      s2 += __shfl_xor(s2, m);
    }
    const float mean = s1 * (1.f / 64.f);
    const float var = s2 * (1.f / 64.f) - mean * mean;
    const float rsv = rsqrtf(var + 1e-5f);
    unsigned short* yg = yb + (size_t)(b * Tt + j * CHK + t) * Dd + h * DHh;
#pragma unroll
    for (int ct = 0; ct < 4; ++ct) {
      const int e = ct * 16 + fr;
      const float rr = (o[ct] - mean) * rsv * lnw[h * DHh + e] + lnb[h * DHh + e];
      yg[e] = f2bf(rr);
    }
  }
}

// ---------------------------------------------------------------------------
// Fused FFN2-reduce (4 bf16 split-K partials) + bias + relu + residual +
// final layernorm over D=1024.
// ---------------------------------------------------------------------------
__global__ __launch_bounds__(256) void final_ln(const float* __restrict__ x,
                                                const __hip_bfloat16* __restrict__ part,
                                                const float* __restrict__ b2,
                                                const float* __restrict__ w,
                                                const float* __restrict__ bb,
                                                float* __restrict__ out) {
  __shared__ float r1[4], r2[4];
  const int row = blockIdx.x;
  const int tid = threadIdx.x;
  const size_t off = (size_t)row * Dd + tid * 4;
  const size_t MN = (size_t)Mm * Dd;
  float acc4[4] = {0.f, 0.f, 0.f, 0.f};
#pragma unroll
  for (int z = 0; z < 4; ++z) {
    const ushort4 u = *(const ushort4*)&part[off + (size_t)z * MN];
    acc4[0] += bf2f(u.x);
    acc4[1] += bf2f(u.y);
    acc4[2] += bf2f(u.z);
    acc4[3] += bf2f(u.w);
  }
  const float4 bv = *(const float4*)&b2[tid * 4];
  const float4 xa = *(const float4*)&x[off];
  float z[4];
  z[0] = xa.x + fmaxf(acc4[0] + bv.x, 0.f);
  z[1] = xa.y + fmaxf(acc4[1] + bv.y, 0.f);
  z[2] = xa.z + fmaxf(acc4[2] + bv.z, 0.f);
  z[3] = xa.w + fmaxf(acc4[3] + bv.w, 0.f);
  float s1 = z[0] + z[1] + z[2] + z[3];
  float s2 = z[0] * z[0] + z[1] * z[1] + z[2] * z[2] + z[3] * z[3];
#pragma unroll
  for (int o = 1; o < 64; o <<= 1) {
    s1 += __shfl_xor(s1, o);
    s2 += __shfl_xor(s2, o);
  }
  const int wid = tid >> 6;
  if ((tid & 63) == 0) {
    r1[wid] = s1;
    r2[wid] = s2;
  }
  __syncthreads();
  const float t1 = r1[0] + r1[1] + r1[2] + r1[3];
  const float t2 = r2[0] + r2[1] + r2[2] + r2[3];
  const float mu = t1 * (1.f / Dd);
  const float var = t2 * (1.f / Dd) - mu * mu;
  const float rsv = rsqrtf(var + 1e-5f);
  float4 o4;
  float* op = &o4.x;
#pragma unroll
  for (int jj = 0; jj < 4; ++jj) op[jj] = (z[jj] - mu) * rsv * w[tid * 4 + jj] + bb[tid * 4 + jj];
  *(float4*)&out[off] = o4;
}

// ---------------------------------------------------------------------------
extern "C" void kernel_launch(void* const* d_in, const int* in_sizes, int n_in,
                              void* d_out, int out_size, void* d_ws, size_t ws_size,
                              hipStream_t stream) {
  const float* x = (const float*)d_in[0];
  const float* W_amp = (const float*)d_in[1];
  const float* b_amp = (const float*)d_in[2];
  const float* W_phi = (const float*)d_in[3];
  const float* b_phi = (const float*)d_in[4];
  const float* omega = (const float*)d_in[5];
  const float* ret_logit = (const float*)d_in[6];
  const float* theta = (const float*)d_in[7];
  const float* W_feat = (const float*)d_in[8];
  const float* b_feat = (const float*)d_in[9];
  const float* Wq = (const float*)d_in[10];
  const float* Wk = (const float*)d_in[11];
  const float* Wv = (const float*)d_in[12];
  const float* lnh_w = (const float*)d_in[13];
  const float* lnh_b = (const float*)d_in[14];
  const float* W1 = (const float*)d_in[15];
  const float* b1 = (const float*)d_in[16];
  const float* W2 = (const float*)d_in[17];
  const float* b2 = (const float*)d_in[18];
  const float* ln_w = (const float*)d_in[19];
  const float* ln_b = (const float*)d_in[20];

  // ---- workspace bump allocator (256B aligned); dedicated buffers ----
  char* p = (char*)d_ws;
  auto alloc = [&](size_t bytes) {
    char* r = p;
    p += (bytes + 255) & ~(size_t)255;
    return r;
  };
  __hip_bfloat16* xb = (__hip_bfloat16*)alloc((size_t)Mm * Dd * 2);   // later: featb
  __hip_bfloat16* urh = (__hip_bfloat16*)alloc((size_t)Mm * NFf * 2);
  __hip_bfloat16* uih = (__hip_bfloat16*)alloc((size_t)Mm * NFf * 2);
  __hip_bfloat16* WTamp = (__hip_bfloat16*)alloc((size_t)NFf * Dd * 2);  // +WTphi contiguous
  __hip_bfloat16* WTphi = (__hip_bfloat16*)alloc((size_t)NFf * Dd * 2);
  __hip_bfloat16* WTfeat = (__hip_bfloat16*)alloc((size_t)Dd * 3 * NFf * 2);
  __hip_bfloat16* WTq = (__hip_bfloat16*)alloc((size_t)Dd * Dd * 2);  // +k+v contiguous
  __hip_bfloat16* WTk = (__hip_bfloat16*)alloc((size_t)Dd * Dd * 2);
  __hip_bfloat16* WTv = (__hip_bfloat16*)alloc((size_t)Dd * Dd * 2);
  __hip_bfloat16* WT1 = (__hip_bfloat16*)alloc((size_t)Rr * Dd * 2);
  __hip_bfloat16* WT2 = (__hip_bfloat16*)alloc((size_t)Dd * Rr * 2);
  __hip_bfloat16* hb = (__hip_bfloat16*)alloc((size_t)Mm * Dd * 2);
  __hip_bfloat16* qkvb = (__hip_bfloat16*)alloc((size_t)Mm * QS * 2);  // 12 MB
  __hip_bfloat16* yhb = (__hip_bfloat16*)alloc((size_t)Mm * Dd * 2);   // 4 MB
  __hip_bfloat16* S = (__hip_bfloat16*)alloc((size_t)Bb * Hh * NCHK * 4096 * 2);  // 4 MB bf16
  float* Ksum = (float*)alloc((size_t)Bb * Hh * NCHK * 64 * 4);
  __hip_bfloat16* f1b = (__hip_bfloat16*)alloc((size_t)Mm * Rr * 2);   // 16 MB
  __hip_bfloat16* pamp = (__hip_bfloat16*)alloc((size_t)4 * Mm * 512 * 2);   // 8 MB dedicated
  __hip_bfloat16* pffn2 = (__hip_bfloat16*)alloc((size_t)4 * Mm * Dd * 2);   // 16 MB dedicated

  __hip_bfloat16* featb = xb;  // xb dead after ampphi GEMM (stream-ordered)
  const __hip_bfloat16* q = qkvb;
  const __hip_bfloat16* k = qkvb + 1024;
  const __hip_bfloat16* v = qkvb + 2048;
  float* out = (float*)d_out;

  const dim3 blk(256);

  // 0: amp/phi weight transposes + x cast (what the first GEMM needs)
  tc_first<<<dim3(2560), blk, 0, stream>>>(W_amp, W_phi, WTamp, WTphi, x, xb);

  // 1: fused amp/phi projection, split-K=4 (256 blocks, bf16 partials), then
  //    fused reduce + softplus/tanh + polar -> bf16 u
  gemm_mfma<EPI_NONE, 1, 4><<<dim3(512 / 128, Mm / 128, 4), blk, 0, stream>>>(
      (const short*)xb, (const short*)WTamp, nullptr, nullptr, pamp, Mm, 512, Dd);
  reduce_polar<<<dim3(Mm * NFf / 256), blk, 0, stream>>>(pamp, b_amp, b_phi, urh, uih);

  // 2: FUSED resonator scan (64 blocks) || remaining weight transposes
  STDesc st;
  st.src[0] = W_feat; st.dst[0] = WTfeat;
  st.src[1] = Wq; st.dst[1] = WTq;
  st.src[2] = Wk; st.dst[2] = WTk;
  st.src[3] = Wv; st.dst[3] = WTv;
  st.src[4] = W1; st.dst[4] = WT1;
  st.src[5] = W2; st.dst[5] = WT2;
  st.ur = urh; st.ui = uih;
  st.omega = omega; st.ret_logit = ret_logit; st.theta = theta;
  st.featb = featb;
  scan_and_tc<<<dim3(64 + 12032), blk, 0, stream>>>(st);

  // 3: feat projection -> h (bf16)
  gemm_mfma<EPI_RELU, 1, 0><<<dim3(Dd / 128, Mm / 128), blk, 0, stream>>>(
      (const short*)featb, (const short*)WTfeat, b_feat, nullptr, hb, Mm, Dd, 3 * NFf);

  // 4: fused q,k,v projection -> bf16 qkvb (384 blocks, 1.5 blocks/CU)
  gemm_mfma<EPI_QKV, 1, 0><<<dim3(QS / 128, Mm / 128), blk, 0, stream>>>(
      (const short*)hb, (const short*)WTq, nullptr, nullptr, qkvb, Mm, QS, Dd);

  // 5: chunked causal linear attention (+ fused per-head LN in attn_out)
  attn_chunk_kv<<<dim3(Bb * Hh * NCHK), blk, 0, stream>>>(k, v, S, Ksum);
  attn_prefix<<<dim3(520), blk, 0, stream>>>(S, Ksum);
  attn_out<<<dim3(Bb * Hh * NCHK), blk, 0, stream>>>(q, k, v, S, Ksum, lnh_w, lnh_b, yhb);

  // 6: FFN1 -> f1b (bf16); 512 blocks = 2 blocks/CU (LDS-capped max)
  gemm_mfma<EPI_RELU, 1, 0><<<dim3(Rr / 128, Mm / 128), blk, 0, stream>>>(
      (const short*)yhb, (const short*)WT1, b1, nullptr, f1b, Mm, Rr, Dd);

  // 7: FFN2 split-K=4, bf16 partials -> pffn2; 512 blocks = 2 blocks/CU
  gemm_mfma<EPI_NONE, 1, 4><<<dim3(Dd / 128, Mm / 128, 4), blk, 0, stream>>>(
      (const short*)f1b, (const short*)WT2, nullptr, nullptr, pffn2, Mm, Dd, Rr);

  // 8: fused reduce(4x bf16) + bias + relu + residual + final layernorm
  final_ln<<<dim3(Mm), blk, 0, stream>>>(x, pffn2, b2, ln_w, ln_b, out);
}